// Round 6
// baseline (429.097 us; speedup 1.0000x reference)
//
#include <hip/hip_runtime.h>
#include <hip/hip_fp16.h>
#include <math.h>

#define N_NODES 50000
#define E_EDGES 400000
#define NEG_SLOPE 0.2f

static inline int cdiv(long a, int b) { return (int)((a + b - 1) / b); }

__device__ __forceinline__ float lrelu(float v) {
    return v > 0.f ? v : NEG_SLOPE * v;
}

__device__ __forceinline__ float wave_red_sum64(float v) {
    #pragma unroll
    for (int off = 32; off; off >>= 1) v += __shfl_xor(v, off, 64);
    return v;
}

__device__ __forceinline__ void h4_to_f4(uint2 u, float o[4]) {
    union { uint2 u2; __half h[4]; } cv;
    cv.u2 = u;
    #pragma unroll
    for (int i = 0; i < 4; ++i) o[i] = __half2float(cv.h[i]);
}

// ---------------- CSR build ----------------
__global__ void k_count(const int* __restrict__ ei, int* __restrict__ deg) {
    int e = blockIdx.x * blockDim.x + threadIdx.x;
    if (e >= E_EDGES) return;
    atomicAdd(&deg[ei[E_EDGES + e]], 1);
}

__global__ void k_scan(const int* __restrict__ deg, int* __restrict__ row_ptr, int n) {
    __shared__ int part[1024];
    int t = threadIdx.x;
    int chunk = (n + 1023) / 1024;
    int lo = t * chunk, hi = min(lo + chunk, n);
    int s = 0;
    for (int i = lo; i < hi; ++i) s += deg[i];
    part[t] = s;
    __syncthreads();
    for (int off = 1; off < 1024; off <<= 1) {
        int v = (t >= off) ? part[t - off] : 0;
        __syncthreads();
        part[t] += v;
        __syncthreads();
    }
    int base = (t == 0) ? 0 : part[t - 1];
    for (int i = lo; i < hi; ++i) {
        row_ptr[i] = base;
        base += deg[i];
    }
    if (t == 1023) row_ptr[n] = part[1023];
}

__global__ void k_scatter(const int* __restrict__ ei, const int* __restrict__ row_ptr,
                          int* __restrict__ pos, int* __restrict__ csr_src) {
    int e = blockIdx.x * blockDim.x + threadIdx.x;
    if (e >= E_EDGES) return;
    int src = ei[e], dst = ei[E_EDGES + e];
    int p = atomicAdd(&pos[dst], 1);
    csr_src[row_ptr[dst] + p] = src;
}

// ---------------- fold attention vectors through W1: w_es[k*4+h] = sum_c W1[k,h*128+c]*a_src[h,c] ----------------
__global__ void k_fold(const float* __restrict__ W1, const float* __restrict__ a_src,
                       const float* __restrict__ a_dst, float* __restrict__ wes,
                       float* __restrict__ wed) {
    int t = threadIdx.x;
    if (t >= 168) return;
    int which = t / 84;
    int idx = t % 84;
    int k = idx >> 2, h = idx & 3;
    const float* a = which ? a_dst : a_src;
    float s = 0.f;
    for (int c = 0; c < 128; ++c)
        s += W1[k * 512 + h * 128 + c] * a[h * 128 + c];
    (which ? wed : wes)[idx] = s;
}

// ---------------- layer-1 coefficients: es/ed = x @ w_es / w_ed ----------------
__global__ void k_l1_coef(const float* __restrict__ x, const float* __restrict__ wes,
                          const float* __restrict__ wed, float* __restrict__ es,
                          float* __restrict__ ed) {
    int node = blockIdx.x * blockDim.x + threadIdx.x;
    if (node >= N_NODES) return;
    const float* xr = x + (size_t)node * 21;
    float e1[4] = {0.f, 0.f, 0.f, 0.f}, e2[4] = {0.f, 0.f, 0.f, 0.f};
    #pragma unroll
    for (int k = 0; k < 21; ++k) {
        float xv = xr[k];
        float4 a = *(const float4*)&wes[k * 4];
        float4 b = *(const float4*)&wed[k * 4];
        e1[0] += xv * a.x; e1[1] += xv * a.y; e1[2] += xv * a.z; e1[3] += xv * a.w;
        e2[0] += xv * b.x; e2[1] += xv * b.y; e2[2] += xv * b.z; e2[3] += xv * b.w;
    }
    *(float4*)&es[node * 4] = make_float4(e1[0], e1[1], e1[2], e1[3]);
    *(float4*)&ed[node * 4] = make_float4(e2[0], e2[1], e2[2], e2[3]);
}

// ---------------- layer-1 edge phase on RAW x: wave per dst ----------------
// softmax stats per head in 16-lane groups; aggregation:
//   lane l<63 owns y-slot o=l (h=l/21, c=l%21); lane l<21 also owns o=63+l (h=3,c=l)
__global__ void k_edge_l1x(const int* __restrict__ row_ptr, const int* __restrict__ csr_src,
                           const float* __restrict__ x, const float* __restrict__ es,
                           const float* __restrict__ ed, float* __restrict__ y) {
    int wid = (blockIdx.x * blockDim.x + threadIdx.x) >> 6;
    int l = threadIdx.x & 63;
    if (wid >= N_NODES) return;
    const int dst = wid;
    const int hh = l >> 4, sub = l & 15;
    const int beg = row_ptr[dst], end = row_ptr[dst + 1];
    const float eddg = ed[dst * 4 + hh];
    const float self_v = lrelu(es[dst * 4 + hh] + eddg);

    // pass 1: per-head max
    float m = self_v;
    for (int k = beg + sub; k < end; k += 16)
        m = fmaxf(m, lrelu(es[csr_src[k] * 4 + hh] + eddg));
    #pragma unroll
    for (int off = 1; off < 16; off <<= 1) m = fmaxf(m, __shfl_xor(m, off, 64));

    // pass 2: per-head sum of exp
    float s = 0.f;
    for (int k = beg + sub; k < end; k += 16)
        s += expf(lrelu(es[csr_src[k] * 4 + hh] + eddg) - m);
    #pragma unroll
    for (int off = 1; off < 16; off <<= 1) s += __shfl_xor(s, off, 64);
    float p_self = expf(self_v - m);
    s += p_self;
    float inv_s = 1.f / s;

    // redistribute stats to aggregation layout
    const bool act0 = (l < 63);
    const int h0 = act0 ? (l / 21) : 0;
    const int c0 = l - h0 * 21;
    float m0 = __shfl(m, h0 * 16, 64);
    float i0 = __shfl(inv_s, h0 * 16, 64);
    float e0d = __shfl(eddg, h0 * 16, 64);
    float ps0 = __shfl(p_self, h0 * 16, 64);
    const bool act1 = (l < 21);
    float m1 = __shfl(m, 48, 64);
    float i1 = __shfl(inv_s, 48, 64);
    float e1d = __shfl(eddg, 48, 64);
    float ps1 = __shfl(p_self, 48, 64);

    const float* xd = x + (size_t)dst * 21;
    float acc0 = act0 ? ps0 * i0 * xd[c0] : 0.f;
    float acc1 = act1 ? ps1 * i1 * xd[l] : 0.f;

    for (int k = beg; k < end; ++k) {
        int src = csr_src[k];
        const float* xs = x + (size_t)src * 21;
        float a0 = expf(lrelu(es[src * 4 + h0] + e0d) - m0) * i0;
        acc0 += a0 * xs[c0];
        if (act1) {
            float a1 = expf(lrelu(es[src * 4 + 3] + e1d) - m1) * i1;
            acc1 += a1 * xs[l];
        }
    }

    if (act0) y[(size_t)dst * 84 + l] = acc0;
    if (act1) y[(size_t)dst * 84 + 63 + l] = acc1;
}

// ---------------- layer-1 post: out1 = ELU(y @ W1_blocked + b1), fp16 ----------------
// 2 waves per dst; lane covers 4 channels c4 = half*256 + l*4; W1 slice in registers.
__global__ void k_post(const float* __restrict__ y, const float* __restrict__ W1,
                       const float* __restrict__ b1, __half* __restrict__ out1) {
    const int l = threadIdx.x & 63;
    const int wv0 = (blockIdx.x * blockDim.x + threadIdx.x) >> 6;
    const int nw = (gridDim.x * blockDim.x) >> 6;

    const int half_ = wv0 & 1;               // which 256-channel half (constant per wave-stride)
    const int c4 = half_ * 256 + l * 4;
    const int hsel = c4 >> 7;

    float wreg[21][4];
    #pragma unroll
    for (int k = 0; k < 21; ++k) {
        float4 w = *(const float4*)&W1[k * 512 + c4];
        wreg[k][0] = w.x; wreg[k][1] = w.y; wreg[k][2] = w.z; wreg[k][3] = w.w;
    }
    float4 bv = *(const float4*)&b1[c4];
    float bo[4] = {bv.x, bv.y, bv.z, bv.w};

    for (int wv = wv0; wv < 2 * N_NODES; wv += nw) {
        int dst = wv >> 1;
        if ((wv & 1) != half_) continue;      // keep channel assignment consistent
        const float* yr = y + (size_t)dst * 84 + hsel * 21;
        float o[4] = {0.f, 0.f, 0.f, 0.f};
        #pragma unroll
        for (int k = 0; k < 21; ++k) {
            float yv = yr[k];
            o[0] += yv * wreg[k][0];
            o[1] += yv * wreg[k][1];
            o[2] += yv * wreg[k][2];
            o[3] += yv * wreg[k][3];
        }
        union { uint2 u2; __half h[4]; } pk;
        #pragma unroll
        for (int j = 0; j < 4; ++j) {
            float v = o[j] + bo[j];
            v = v > 0.f ? v : expm1f(v);
            pk.h[j] = __float2half_rn(v);
        }
        *(uint2*)&out1[(size_t)dst * 512 + c4] = pk.u2;
    }
}

// ---------------- Layer 2: tiled GEMM (fp16 A @ f32 W2) + es/ed; h2 stored fp16 ----------------
__global__ void k_l2_gemm_coef(const __half* __restrict__ A16, const float* __restrict__ B,
                               const float* __restrict__ a_src, const float* __restrict__ a_dst,
                               __half* __restrict__ C16, float* __restrict__ es, float* __restrict__ ed) {
    __shared__ float AT[64][65];
    __shared__ float Bs[64][64];

    const int t = threadIdx.x;
    const int tr = t >> 4, tc = t & 15;
    const int row0 = blockIdx.x * 64;

    float acc[4][4];
    #pragma unroll
    for (int r = 0; r < 4; ++r)
        #pragma unroll
        for (int cc = 0; cc < 4; ++cc) acc[r][cc] = 0.f;

    for (int k0 = 0; k0 < 512; k0 += 64) {
        // stage A tile (fp16 -> f32 transposed)
        #pragma unroll
        for (int i = 0; i < 2; ++i) {
            int f = i * 256 + t;          // 512 slots of 8 halves
            int row = f >> 3, c8 = f & 7;
            int grow = row0 + row;
            union { uint4 u4; __half h[8]; } v;
            v.u4 = make_uint4(0, 0, 0, 0);
            if (grow < N_NODES)
                v.u4 = *(const uint4*)&A16[(size_t)grow * 512 + k0 + c8 * 8];
            #pragma unroll
            for (int j = 0; j < 8; ++j)
                AT[c8 * 8 + j][row] = __half2float(v.h[j]);
        }
        // stage B
        #pragma unroll
        for (int i = 0; i < 4; ++i) {
            int f = i * 256 + t;
            int row = f >> 4, c4 = f & 15;
            *(float4*)&Bs[row][c4 * 4] = *(const float4*)&B[(size_t)(k0 + row) * 64 + c4 * 4];
        }
        __syncthreads();
        #pragma unroll 8
        for (int kk = 0; kk < 64; ++kk) {
            float4 a4 = *(const float4*)&AT[kk][tr * 4];
            float4 b4 = *(const float4*)&Bs[kk][tc * 4];
            const float av[4] = {a4.x, a4.y, a4.z, a4.w};
            const float bv[4] = {b4.x, b4.y, b4.z, b4.w};
            #pragma unroll
            for (int r = 0; r < 4; ++r)
                #pragma unroll
                for (int cc = 0; cc < 4; ++cc)
                    acc[r][cc] += av[r] * bv[cc];
        }
        __syncthreads();
    }

    float4 as4 = *(const float4*)&a_src[tc * 4];
    float4 ad4 = *(const float4*)&a_dst[tc * 4];
    #pragma unroll
    for (int r = 0; r < 4; ++r) {
        int grow = row0 + tr * 4 + r;
        float4 cv = {acc[r][0], acc[r][1], acc[r][2], acc[r][3]};
        float p1 = cv.x * as4.x + cv.y * as4.y + cv.z * as4.z + cv.w * as4.w;
        float p2 = cv.x * ad4.x + cv.y * ad4.y + cv.z * ad4.z + cv.w * ad4.w;
        #pragma unroll
        for (int off = 8; off; off >>= 1) {
            p1 += __shfl_xor(p1, off, 64);
            p2 += __shfl_xor(p2, off, 64);
        }
        if (grow < N_NODES) {
            union { uint2 u2; __half h[4]; } o;
            o.h[0] = __float2half_rn(cv.x);
            o.h[1] = __float2half_rn(cv.y);
            o.h[2] = __float2half_rn(cv.z);
            o.h[3] = __float2half_rn(cv.w);
            *(uint2*)&C16[(size_t)grow * 64 + tc * 4] = o.u2;
            if (tc == 0) { es[grow] = p1; ed[grow] = p2; }
        }
    }
}

// ---------------- Layer 3: wave-per-node dot + es/ed ----------------
__global__ void k_l3_gemm_coef(const float* __restrict__ A, const float* __restrict__ W3,
                               const float* __restrict__ a_src, const float* __restrict__ a_dst,
                               float* __restrict__ h3, float* __restrict__ es, float* __restrict__ ed) {
    int gid = blockIdx.x * blockDim.x + threadIdx.x;
    int node = gid >> 6, lane = gid & 63;
    if (node >= N_NODES) return;
    float v = A[(size_t)node * 64 + lane] * W3[lane];
    v = wave_red_sum64(v);
    if (lane == 0) {
        h3[node] = v;
        es[node] = v * a_src[0];
        ed[node] = v * a_dst[0];
    }
}

// ---------------- Layer 2 edge phase: wave per dst, 4 edge-groups, fp16 gather ----------------
__global__ void k_gat_edge_l2(const int* __restrict__ row_ptr, const int* __restrict__ csr_src,
                              const __half* __restrict__ h16, const float* __restrict__ es,
                              const float* __restrict__ ed, const float* __restrict__ b,
                              float* __restrict__ out) {
    int wid = (blockIdx.x * blockDim.x + threadIdx.x) >> 6;
    int lane = threadIdx.x & 63;
    if (wid >= N_NODES) return;
    const int dst = wid;
    const int g = lane >> 4, sub = lane & 15;
    const int beg = row_ptr[dst], end = row_ptr[dst + 1];
    const float edd = ed[dst];
    const float self_v = lrelu(es[dst] + edd);

    float m = self_v;
    for (int k = beg + lane; k < end; k += 64)
        m = fmaxf(m, lrelu(es[csr_src[k]] + edd));
    #pragma unroll
    for (int off = 32; off; off >>= 1) m = fmaxf(m, __shfl_xor(m, off, 64));

    float s = 0.f;
    for (int k = beg + lane; k < end; k += 64)
        s += expf(lrelu(es[csr_src[k]] + edd) - m);
    #pragma unroll
    for (int off = 32; off; off >>= 1) s += __shfl_xor(s, off, 64);
    float p_self = expf(self_v - m);
    s += p_self;
    const float inv_s = 1.f / s;

    float acc[4] = {0.f, 0.f, 0.f, 0.f};
    if (g == 0) {
        uint2 r = *(const uint2*)(h16 + (size_t)dst * 64 + sub * 4);
        float hv[4]; h4_to_f4(r, hv);
        float a_self = p_self * inv_s;
        #pragma unroll
        for (int j = 0; j < 4; ++j) acc[j] = a_self * hv[j];
    }
    for (int k0 = beg; k0 < end; k0 += 4) {
        int k = k0 + g;
        if (k < end) {
            int src = csr_src[k];
            float alpha = expf(lrelu(es[src] + edd) - m) * inv_s;
            uint2 r = *(const uint2*)(h16 + (size_t)src * 64 + sub * 4);
            float hv[4]; h4_to_f4(r, hv);
            #pragma unroll
            for (int j = 0; j < 4; ++j) acc[j] += alpha * hv[j];
        }
    }
    #pragma unroll
    for (int off = 16; off < 64; off <<= 1) {
        #pragma unroll
        for (int j = 0; j < 4; ++j) acc[j] += __shfl_xor(acc[j], off, 64);
    }
    if (g == 0) {
        float4 bv = *(const float4*)&b[sub * 4];
        float o[4] = {acc[0] + bv.x, acc[1] + bv.y, acc[2] + bv.z, acc[3] + bv.w};
        #pragma unroll
        for (int j = 0; j < 4; ++j) o[j] = o[j] > 0.f ? o[j] : expm1f(o[j]);
        *(float4*)&out[(size_t)dst * 64 + sub * 4] = make_float4(o[0], o[1], o[2], o[3]);
    }
}

// ---------------- layer 3 edge phase (H=1, C=1) ----------------
__global__ void k_gat_edge_c1(const int* __restrict__ row_ptr, const int* __restrict__ csr_src,
                              const float* __restrict__ h, const float* __restrict__ es,
                              const float* __restrict__ ed, float* __restrict__ out) {
    int dst = blockIdx.x * blockDim.x + threadIdx.x;
    if (dst >= N_NODES) return;
    int beg = row_ptr[dst], end = row_ptr[dst + 1];
    float edd = ed[dst];
    float self_v = lrelu(es[dst] + edd);
    float m = self_v;
    for (int k = beg; k < end; ++k) m = fmaxf(m, lrelu(es[csr_src[k]] + edd));
    float p = expf(self_v - m);
    float s = p;
    float acc = p * h[dst];
    for (int k = beg; k < end; ++k) {
        int src = csr_src[k];
        float pv = expf(lrelu(es[src] + edd) - m);
        s += pv;
        acc += pv * h[src];
    }
    out[dst] = acc / s;
}

// ---------------- final mean + b3 ----------------
__global__ void k_mean(const float* __restrict__ v, const float* __restrict__ b3,
                       float* __restrict__ out, int n) {
    __shared__ float sdata[256];
    float local = 0.f;
    for (int i = blockIdx.x * blockDim.x + threadIdx.x; i < n; i += gridDim.x * blockDim.x)
        local += v[i];
    sdata[threadIdx.x] = local;
    __syncthreads();
    for (int sft = 128; sft > 0; sft >>= 1) {
        if (threadIdx.x < sft) sdata[threadIdx.x] += sdata[threadIdx.x + sft];
        __syncthreads();
    }
    if (threadIdx.x == 0) {
        float add = sdata[0] / (float)n;
        if (blockIdx.x == 0) add += b3[0];
        atomicAdd(out, add);
    }
}

extern "C" void kernel_launch(void* const* d_in, const int* in_sizes, int n_in,
                              void* d_out, int out_size, void* d_ws, size_t ws_size,
                              hipStream_t stream) {
    const float* x      = (const float*)d_in[0];
    const float* W1     = (const float*)d_in[1];
    const float* a_src1 = (const float*)d_in[2];
    const float* a_dst1 = (const float*)d_in[3];
    const float* b1     = (const float*)d_in[4];
    const float* W2     = (const float*)d_in[5];
    const float* a_src2 = (const float*)d_in[6];
    const float* a_dst2 = (const float*)d_in[7];
    const float* b2     = (const float*)d_in[8];
    const float* W3     = (const float*)d_in[9];
    const float* a_src3 = (const float*)d_in[10];
    const float* a_dst3 = (const float*)d_in[11];
    const float* b3     = (const float*)d_in[12];
    const int*   ei     = (const int*)d_in[13];
    float* out = (float*)d_out;

    const int BS = 256;
    const size_t N = N_NODES;

    // workspace layout (float units)
    float*  ws      = (float*)d_ws;
    __half* out1h   = (__half*)ws;                 // N*512 halves = N*256 floats
    float*  y_buf   = ws + N * 256;                // N*84
    __half* h2_16   = (__half*)(y_buf + N * 84);   // N*64 halves = N*32 floats
    float*  out2    = y_buf + N * 84 + N * 32;     // N*64
    float*  h3raw   = out2 + N * 64;               // N
    float*  out3    = h3raw + N;                   // N
    float*  es_buf  = out3 + N;                    // N*4
    float*  ed_buf  = es_buf + N * 4;              // N*4
    float*  wes     = ed_buf + N * 4;              // 88 (padded)
    float*  wed     = wes + 88;                    // 88
    int*    deg     = (int*)(wed + 88);            // N
    int*    row_ptr = deg + N;                     // N+1
    int*    csr_src = row_ptr + N + 1;             // E_EDGES

    // CSR build (shared by all 3 layers)
    hipMemsetAsync(deg, 0, N * sizeof(int), stream);
    k_count<<<cdiv(E_EDGES, BS), BS, 0, stream>>>(ei, deg);
    k_scan<<<1, 1024, 0, stream>>>(deg, row_ptr, N_NODES);
    hipMemsetAsync(deg, 0, N * sizeof(int), stream);
    k_scatter<<<cdiv(E_EDGES, BS), BS, 0, stream>>>(ei, row_ptr, deg, csr_src);

    // Layer 1: H=4, C=128 — aggregate raw x, then per-node GEMM
    k_fold<<<1, 256, 0, stream>>>(W1, a_src1, a_dst1, wes, wed);
    k_l1_coef<<<cdiv((long)N, BS), BS, 0, stream>>>(x, wes, wed, es_buf, ed_buf);
    k_edge_l1x<<<cdiv((long)N * 64, BS), BS, 0, stream>>>(row_ptr, csr_src, x, es_buf, ed_buf, y_buf);
    k_post<<<2048, 256, 0, stream>>>(y_buf, W1, b1, out1h);

    // Layer 2: H=1, C=64
    k_l2_gemm_coef<<<cdiv(N_NODES, 64), 256, 0, stream>>>(out1h, W2, a_src2, a_dst2, h2_16, es_buf, ed_buf);
    k_gat_edge_l2<<<cdiv((long)N * 64, BS), BS, 0, stream>>>(row_ptr, csr_src, h2_16, es_buf, ed_buf, b2, out2);

    // Layer 3: H=1, C=1
    k_l3_gemm_coef<<<cdiv((long)N * 64, BS), BS, 0, stream>>>(out2, W3, a_src3, a_dst3, h3raw, es_buf, ed_buf);
    k_gat_edge_c1<<<cdiv((long)N, BS), BS, 0, stream>>>(row_ptr, csr_src, h3raw, es_buf, ed_buf, out3);

    hipMemsetAsync(out, 0, sizeof(float), stream);
    k_mean<<<256, 256, 0, stream>>>(out3, b3, out, N_NODES);
}

// Round 7
// 420.842 us; speedup vs baseline: 1.0196x; 1.0196x over previous
//
#include <hip/hip_runtime.h>
#include <hip/hip_fp16.h>
#include <math.h>

#define N_NODES 50000
#define E_EDGES 400000
#define NEG_SLOPE 0.2f

static inline int cdiv(long a, int b) { return (int)((a + b - 1) / b); }

__device__ __forceinline__ float lrelu(float v) {
    return v > 0.f ? v : NEG_SLOPE * v;
}

__device__ __forceinline__ float wave_red_sum64(float v) {
    #pragma unroll
    for (int off = 32; off; off >>= 1) v += __shfl_xor(v, off, 64);
    return v;
}

__device__ __forceinline__ void h4_to_f4(uint2 u, float o[4]) {
    union { uint2 u2; __half h[4]; } cv;
    cv.u2 = u;
    #pragma unroll
    for (int i = 0; i < 4; ++i) o[i] = __half2float(cv.h[i]);
}

// ---------------- CSR build ----------------
__global__ void k_count(const int* __restrict__ ei, int* __restrict__ deg) {
    int e = blockIdx.x * blockDim.x + threadIdx.x;
    if (e >= E_EDGES) return;
    atomicAdd(&deg[ei[E_EDGES + e]], 1);
}

__global__ void k_scan(const int* __restrict__ deg, int* __restrict__ row_ptr, int n) {
    __shared__ int part[1024];
    int t = threadIdx.x;
    int chunk = (n + 1023) / 1024;
    int lo = t * chunk, hi = min(lo + chunk, n);
    int s = 0;
    for (int i = lo; i < hi; ++i) s += deg[i];
    part[t] = s;
    __syncthreads();
    for (int off = 1; off < 1024; off <<= 1) {
        int v = (t >= off) ? part[t - off] : 0;
        __syncthreads();
        part[t] += v;
        __syncthreads();
    }
    int base = (t == 0) ? 0 : part[t - 1];
    for (int i = lo; i < hi; ++i) {
        row_ptr[i] = base;
        base += deg[i];
    }
    if (t == 1023) row_ptr[n] = part[1023];
}

__global__ void k_scatter(const int* __restrict__ ei, const int* __restrict__ row_ptr,
                          int* __restrict__ pos, int* __restrict__ csr_src) {
    int e = blockIdx.x * blockDim.x + threadIdx.x;
    if (e >= E_EDGES) return;
    int src = ei[e], dst = ei[E_EDGES + e];
    int p = atomicAdd(&pos[dst], 1);
    csr_src[row_ptr[dst] + p] = src;
}

// ---------------- fold attention vectors through W1 ----------------
__global__ void k_fold(const float* __restrict__ W1, const float* __restrict__ a_src,
                       const float* __restrict__ a_dst, float* __restrict__ wes,
                       float* __restrict__ wed) {
    int t = threadIdx.x;
    if (t >= 168) return;
    int which = t / 84;
    int idx = t % 84;
    int k = idx >> 2, h = idx & 3;
    const float* a = which ? a_dst : a_src;
    float s = 0.f;
    for (int c = 0; c < 128; ++c)
        s += W1[k * 512 + h * 128 + c] * a[h * 128 + c];
    (which ? wed : wes)[idx] = s;
}

// ---------------- layer-1 coefficients: es/ed = x @ w_es / w_ed ----------------
__global__ void k_l1_coef(const float* __restrict__ x, const float* __restrict__ wes,
                          const float* __restrict__ wed, float* __restrict__ es,
                          float* __restrict__ ed) {
    int node = blockIdx.x * blockDim.x + threadIdx.x;
    if (node >= N_NODES) return;
    const float* xr = x + (size_t)node * 21;
    float e1[4] = {0.f, 0.f, 0.f, 0.f}, e2[4] = {0.f, 0.f, 0.f, 0.f};
    #pragma unroll
    for (int k = 0; k < 21; ++k) {
        float xv = xr[k];
        float4 a = *(const float4*)&wes[k * 4];
        float4 b = *(const float4*)&wed[k * 4];
        e1[0] += xv * a.x; e1[1] += xv * a.y; e1[2] += xv * a.z; e1[3] += xv * a.w;
        e2[0] += xv * b.x; e2[1] += xv * b.y; e2[2] += xv * b.z; e2[3] += xv * b.w;
    }
    *(float4*)&es[node * 4] = make_float4(e1[0], e1[1], e1[2], e1[3]);
    *(float4*)&ed[node * 4] = make_float4(e2[0], e2[1], e2[2], e2[3]);
}

// ---------------- layer-1 edge phase on RAW x: wave per dst ----------------
__global__ void k_edge_l1x(const int* __restrict__ row_ptr, const int* __restrict__ csr_src,
                           const float* __restrict__ x, const float* __restrict__ es,
                           const float* __restrict__ ed, float* __restrict__ y) {
    int wid = (blockIdx.x * blockDim.x + threadIdx.x) >> 6;
    int l = threadIdx.x & 63;
    if (wid >= N_NODES) return;
    const int dst = wid;
    const int hh = l >> 4, sub = l & 15;
    const int beg = row_ptr[dst], end = row_ptr[dst + 1];
    const float eddg = ed[dst * 4 + hh];
    const float self_v = lrelu(es[dst * 4 + hh] + eddg);

    float m = self_v;
    for (int k = beg + sub; k < end; k += 16)
        m = fmaxf(m, lrelu(es[csr_src[k] * 4 + hh] + eddg));
    #pragma unroll
    for (int off = 1; off < 16; off <<= 1) m = fmaxf(m, __shfl_xor(m, off, 64));

    float s = 0.f;
    for (int k = beg + sub; k < end; k += 16)
        s += expf(lrelu(es[csr_src[k] * 4 + hh] + eddg) - m);
    #pragma unroll
    for (int off = 1; off < 16; off <<= 1) s += __shfl_xor(s, off, 64);
    float p_self = expf(self_v - m);
    s += p_self;
    float inv_s = 1.f / s;

    const bool act0 = (l < 63);
    const int h0 = act0 ? (l / 21) : 0;
    const int c0 = l - h0 * 21;
    float m0 = __shfl(m, h0 * 16, 64);
    float i0 = __shfl(inv_s, h0 * 16, 64);
    float e0d = __shfl(eddg, h0 * 16, 64);
    float ps0 = __shfl(p_self, h0 * 16, 64);
    const bool act1 = (l < 21);
    float m1 = __shfl(m, 48, 64);
    float i1 = __shfl(inv_s, 48, 64);
    float e1d = __shfl(eddg, 48, 64);
    float ps1 = __shfl(p_self, 48, 64);

    const float* xd = x + (size_t)dst * 21;
    float acc0 = act0 ? ps0 * i0 * xd[c0] : 0.f;
    float acc1 = act1 ? ps1 * i1 * xd[l] : 0.f;

    for (int k = beg; k < end; ++k) {
        int src = csr_src[k];
        const float* xs = x + (size_t)src * 21;
        float a0 = expf(lrelu(es[src * 4 + h0] + e0d) - m0) * i0;
        acc0 += a0 * xs[c0];
        if (act1) {
            float a1 = expf(lrelu(es[src * 4 + 3] + e1d) - m1) * i1;
            acc1 += a1 * xs[l];
        }
    }

    if (act0) y[(size_t)dst * 84 + l] = acc0;
    if (act1) y[(size_t)dst * 84 + 63 + l] = acc1;
}

// ---------------- Layer 2 fused: A = ELU(y@W1+b1) built in LDS, then A@W2 + es/ed ----------------
// block = 64 rows; per K-step (64 cols, one head): mini-GEMM 64x21x64 -> AT, then 64x64x64 main GEMM.
__global__ void k_l2_fused(const float* __restrict__ y, const float* __restrict__ W1,
                           const float* __restrict__ b1, const float* __restrict__ W2,
                           const float* __restrict__ a_src, const float* __restrict__ a_dst,
                           __half* __restrict__ C16, float* __restrict__ es, float* __restrict__ ed) {
    __shared__ float Ys[64][84];
    __shared__ float AT[64][65];   // AT[kk][r]
    __shared__ float Bs[64][64];

    const int t = threadIdx.x;
    const int tr = t >> 4, tc = t & 15;
    const int row0 = blockIdx.x * 64;

    // stage y tile once (read each y element exactly once from HBM)
    for (int f = t; f < 64 * 84; f += 256) {
        int row = f / 84, c = f % 84;
        int grow = row0 + row;
        Ys[row][c] = (grow < N_NODES) ? y[(size_t)grow * 84 + c] : 0.f;
    }

    float acc[4][4];
    #pragma unroll
    for (int r = 0; r < 4; ++r)
        #pragma unroll
        for (int cc = 0; cc < 4; ++cc) acc[r][cc] = 0.f;

    const int colA = t & 63;   // mini-GEMM column
    const int rg = t >> 6;     // row group 0..3

    __syncthreads();

    for (int k0 = 0; k0 < 512; k0 += 64) {
        // mini-GEMM: AT[colA][r] = ELU(b1 + sum_j Ys[r][h0*21+j] * W1[j][k0+colA])
        const int h0 = k0 >> 7;
        float w[21];
        #pragma unroll
        for (int j = 0; j < 21; ++j) w[j] = W1[j * 512 + k0 + colA];
        const float bb = b1[k0 + colA];
        #pragma unroll
        for (int rr = 0; rr < 16; ++rr) {
            int r = rg * 16 + rr;
            float a = bb;
            #pragma unroll
            for (int j = 0; j < 21; ++j) a += Ys[r][h0 * 21 + j] * w[j];
            a = a > 0.f ? a : expm1f(a);
            AT[colA][r] = a;
        }
        // stage W2 K-slice
        #pragma unroll
        for (int i = 0; i < 4; ++i) {
            int f = i * 256 + t;
            int brow = f >> 4, c4 = f & 15;
            *(float4*)&Bs[brow][c4 * 4] = *(const float4*)&W2[(size_t)(k0 + brow) * 64 + c4 * 4];
        }
        __syncthreads();
        #pragma unroll 8
        for (int kk = 0; kk < 64; ++kk) {
            float4 a4 = *(const float4*)&AT[kk][tr * 4];
            float4 b4 = *(const float4*)&Bs[kk][tc * 4];
            const float av[4] = {a4.x, a4.y, a4.z, a4.w};
            const float bv[4] = {b4.x, b4.y, b4.z, b4.w};
            #pragma unroll
            for (int r = 0; r < 4; ++r)
                #pragma unroll
                for (int cc = 0; cc < 4; ++cc)
                    acc[r][cc] += av[r] * bv[cc];
        }
        __syncthreads();
    }

    float4 as4 = *(const float4*)&a_src[tc * 4];
    float4 ad4 = *(const float4*)&a_dst[tc * 4];
    #pragma unroll
    for (int r = 0; r < 4; ++r) {
        int grow = row0 + tr * 4 + r;
        float4 cv = {acc[r][0], acc[r][1], acc[r][2], acc[r][3]};
        float p1 = cv.x * as4.x + cv.y * as4.y + cv.z * as4.z + cv.w * as4.w;
        float p2 = cv.x * ad4.x + cv.y * ad4.y + cv.z * ad4.z + cv.w * ad4.w;
        #pragma unroll
        for (int off = 8; off; off >>= 1) {
            p1 += __shfl_xor(p1, off, 64);
            p2 += __shfl_xor(p2, off, 64);
        }
        if (grow < N_NODES) {
            union { uint2 u2; __half h[4]; } o;
            o.h[0] = __float2half_rn(cv.x);
            o.h[1] = __float2half_rn(cv.y);
            o.h[2] = __float2half_rn(cv.z);
            o.h[3] = __float2half_rn(cv.w);
            *(uint2*)&C16[(size_t)grow * 64 + tc * 4] = o.u2;
            if (tc == 0) { es[grow] = p1; ed[grow] = p2; }
        }
    }
}

// ---------------- Layer 3: wave-per-node dot + es/ed ----------------
__global__ void k_l3_gemm_coef(const float* __restrict__ A, const float* __restrict__ W3,
                               const float* __restrict__ a_src, const float* __restrict__ a_dst,
                               float* __restrict__ h3, float* __restrict__ es, float* __restrict__ ed) {
    int gid = blockIdx.x * blockDim.x + threadIdx.x;
    int node = gid >> 6, lane = gid & 63;
    if (node >= N_NODES) return;
    float v = A[(size_t)node * 64 + lane] * W3[lane];
    v = wave_red_sum64(v);
    if (lane == 0) {
        h3[node] = v;
        es[node] = v * a_src[0];
        ed[node] = v * a_dst[0];
    }
}

// ---------------- Layer 2 edge phase: wave per dst, 4 edge-groups, fp16 gather ----------------
__global__ void k_gat_edge_l2(const int* __restrict__ row_ptr, const int* __restrict__ csr_src,
                              const __half* __restrict__ h16, const float* __restrict__ es,
                              const float* __restrict__ ed, const float* __restrict__ b,
                              float* __restrict__ out) {
    int wid = (blockIdx.x * blockDim.x + threadIdx.x) >> 6;
    int lane = threadIdx.x & 63;
    if (wid >= N_NODES) return;
    const int dst = wid;
    const int g = lane >> 4, sub = lane & 15;
    const int beg = row_ptr[dst], end = row_ptr[dst + 1];
    const float edd = ed[dst];
    const float self_v = lrelu(es[dst] + edd);

    float m = self_v;
    for (int k = beg + lane; k < end; k += 64)
        m = fmaxf(m, lrelu(es[csr_src[k]] + edd));
    #pragma unroll
    for (int off = 32; off; off >>= 1) m = fmaxf(m, __shfl_xor(m, off, 64));

    float s = 0.f;
    for (int k = beg + lane; k < end; k += 64)
        s += expf(lrelu(es[csr_src[k]] + edd) - m);
    #pragma unroll
    for (int off = 32; off; off >>= 1) s += __shfl_xor(s, off, 64);
    float p_self = expf(self_v - m);
    s += p_self;
    const float inv_s = 1.f / s;

    float acc[4] = {0.f, 0.f, 0.f, 0.f};
    if (g == 0) {
        uint2 r = *(const uint2*)(h16 + (size_t)dst * 64 + sub * 4);
        float hv[4]; h4_to_f4(r, hv);
        float a_self = p_self * inv_s;
        #pragma unroll
        for (int j = 0; j < 4; ++j) acc[j] = a_self * hv[j];
    }
    for (int k0 = beg; k0 < end; k0 += 4) {
        int k = k0 + g;
        if (k < end) {
            int src = csr_src[k];
            float alpha = expf(lrelu(es[src] + edd) - m) * inv_s;
            uint2 r = *(const uint2*)(h16 + (size_t)src * 64 + sub * 4);
            float hv[4]; h4_to_f4(r, hv);
            #pragma unroll
            for (int j = 0; j < 4; ++j) acc[j] += alpha * hv[j];
        }
    }
    #pragma unroll
    for (int off = 16; off < 64; off <<= 1) {
        #pragma unroll
        for (int j = 0; j < 4; ++j) acc[j] += __shfl_xor(acc[j], off, 64);
    }
    if (g == 0) {
        float4 bv = *(const float4*)&b[sub * 4];
        float o[4] = {acc[0] + bv.x, acc[1] + bv.y, acc[2] + bv.z, acc[3] + bv.w};
        #pragma unroll
        for (int j = 0; j < 4; ++j) o[j] = o[j] > 0.f ? o[j] : expm1f(o[j]);
        *(float4*)&out[(size_t)dst * 64 + sub * 4] = make_float4(o[0], o[1], o[2], o[3]);
    }
}

// ---------------- layer 3 edge phase (H=1, C=1) ----------------
__global__ void k_gat_edge_c1(const int* __restrict__ row_ptr, const int* __restrict__ csr_src,
                              const float* __restrict__ h, const float* __restrict__ es,
                              const float* __restrict__ ed, float* __restrict__ out) {
    int dst = blockIdx.x * blockDim.x + threadIdx.x;
    if (dst >= N_NODES) return;
    int beg = row_ptr[dst], end = row_ptr[dst + 1];
    float edd = ed[dst];
    float self_v = lrelu(es[dst] + edd);
    float m = self_v;
    for (int k = beg; k < end; ++k) m = fmaxf(m, lrelu(es[csr_src[k]] + edd));
    float p = expf(self_v - m);
    float s = p;
    float acc = p * h[dst];
    for (int k = beg; k < end; ++k) {
        int src = csr_src[k];
        float pv = expf(lrelu(es[src] + edd) - m);
        s += pv;
        acc += pv * h[src];
    }
    out[dst] = acc / s;
}

// ---------------- final mean + b3 ----------------
__global__ void k_mean(const float* __restrict__ v, const float* __restrict__ b3,
                       float* __restrict__ out, int n) {
    __shared__ float sdata[256];
    float local = 0.f;
    for (int i = blockIdx.x * blockDim.x + threadIdx.x; i < n; i += gridDim.x * blockDim.x)
        local += v[i];
    sdata[threadIdx.x] = local;
    __syncthreads();
    for (int sft = 128; sft > 0; sft >>= 1) {
        if (threadIdx.x < sft) sdata[threadIdx.x] += sdata[threadIdx.x + sft];
        __syncthreads();
    }
    if (threadIdx.x == 0) {
        float add = sdata[0] / (float)n;
        if (blockIdx.x == 0) add += b3[0];
        atomicAdd(out, add);
    }
}

extern "C" void kernel_launch(void* const* d_in, const int* in_sizes, int n_in,
                              void* d_out, int out_size, void* d_ws, size_t ws_size,
                              hipStream_t stream) {
    const float* x      = (const float*)d_in[0];
    const float* W1     = (const float*)d_in[1];
    const float* a_src1 = (const float*)d_in[2];
    const float* a_dst1 = (const float*)d_in[3];
    const float* b1     = (const float*)d_in[4];
    const float* W2     = (const float*)d_in[5];
    const float* a_src2 = (const float*)d_in[6];
    const float* a_dst2 = (const float*)d_in[7];
    const float* b2     = (const float*)d_in[8];
    const float* W3     = (const float*)d_in[9];
    const float* a_src3 = (const float*)d_in[10];
    const float* a_dst3 = (const float*)d_in[11];
    const float* b3     = (const float*)d_in[12];
    const int*   ei     = (const int*)d_in[13];
    float* out = (float*)d_out;

    const int BS = 256;
    const size_t N = N_NODES;

    // workspace layout (float units)
    float*  ws      = (float*)d_ws;
    float*  y_buf   = ws;                          // N*84
    __half* h2_16   = (__half*)(y_buf + N * 84);   // N*64 halves = N*32 floats
    float*  out2    = y_buf + N * 84 + N * 32;     // N*64
    float*  h3raw   = out2 + N * 64;               // N
    float*  out3    = h3raw + N;                   // N
    float*  es_buf  = out3 + N;                    // N*4
    float*  ed_buf  = es_buf + N * 4;              // N*4
    float*  wes     = ed_buf + N * 4;              // 88 (padded)
    float*  wed     = wes + 88;                    // 88
    int*    deg     = (int*)(wed + 88);            // N
    int*    row_ptr = deg + N;                     // N+1
    int*    csr_src = row_ptr + N + 1;             // E_EDGES

    // CSR build (shared by all 3 layers)
    hipMemsetAsync(deg, 0, N * sizeof(int), stream);
    k_count<<<cdiv(E_EDGES, BS), BS, 0, stream>>>(ei, deg);
    k_scan<<<1, 1024, 0, stream>>>(deg, row_ptr, N_NODES);
    hipMemsetAsync(deg, 0, N * sizeof(int), stream);
    k_scatter<<<cdiv(E_EDGES, BS), BS, 0, stream>>>(ei, row_ptr, deg, csr_src);

    // Layer 1: H=4, C=128 — aggregate raw x; out1 is never materialized
    k_fold<<<1, 256, 0, stream>>>(W1, a_src1, a_dst1, wes, wed);
    k_l1_coef<<<cdiv((long)N, BS), BS, 0, stream>>>(x, wes, wed, es_buf, ed_buf);
    k_edge_l1x<<<cdiv((long)N * 64, BS), BS, 0, stream>>>(row_ptr, csr_src, x, es_buf, ed_buf, y_buf);

    // Layer 2: H=1, C=64 — fused ELU(y@W1+b1) @ W2 + coefficients
    k_l2_fused<<<cdiv(N_NODES, 64), 256, 0, stream>>>(y_buf, W1, b1, W2, a_src2, a_dst2, h2_16, es_buf, ed_buf);
    k_gat_edge_l2<<<cdiv((long)N * 64, BS), BS, 0, stream>>>(row_ptr, csr_src, h2_16, es_buf, ed_buf, b2, out2);

    // Layer 3: H=1, C=1
    k_l3_gemm_coef<<<cdiv((long)N * 64, BS), BS, 0, stream>>>(out2, W3, a_src3, a_dst3, h3raw, es_buf, ed_buf);
    k_gat_edge_c1<<<cdiv((long)N, BS), BS, 0, stream>>>(row_ptr, csr_src, h3raw, es_buf, ed_buf, out3);

    hipMemsetAsync(out, 0, sizeof(float), stream);
    k_mean<<<256, 256, 0, stream>>>(out3, b3, out, N_NODES);
}

// Round 8
// 397.411 us; speedup vs baseline: 1.0797x; 1.0590x over previous
//
#include <hip/hip_runtime.h>
#include <hip/hip_fp16.h>
#include <math.h>

#define N_NODES 50000
#define E_EDGES 400000
#define NEG_SLOPE 0.2f

static inline int cdiv(long a, int b) { return (int)((a + b - 1) / b); }

__device__ __forceinline__ float lrelu(float v) {
    return v > 0.f ? v : NEG_SLOPE * v;
}

__device__ __forceinline__ float wave_red_sum64(float v) {
    #pragma unroll
    for (int off = 32; off; off >>= 1) v += __shfl_xor(v, off, 64);
    return v;
}

__device__ __forceinline__ void h4_to_f4(uint2 u, float o[4]) {
    union { uint2 u2; __half h[4]; } cv;
    cv.u2 = u;
    #pragma unroll
    for (int i = 0; i < 4; ++i) o[i] = __half2float(cv.h[i]);
}

// ---------------- CSR build ----------------
__global__ void k_count(const int* __restrict__ ei, int* __restrict__ deg) {
    int e = blockIdx.x * blockDim.x + threadIdx.x;
    if (e >= E_EDGES) return;
    atomicAdd(&deg[ei[E_EDGES + e]], 1);
}

__global__ void k_scan(const int* __restrict__ deg, int* __restrict__ row_ptr, int n) {
    __shared__ int part[1024];
    int t = threadIdx.x;
    int chunk = (n + 1023) / 1024;
    int lo = t * chunk, hi = min(lo + chunk, n);
    int s = 0;
    for (int i = lo; i < hi; ++i) s += deg[i];
    part[t] = s;
    __syncthreads();
    for (int off = 1; off < 1024; off <<= 1) {
        int v = (t >= off) ? part[t - off] : 0;
        __syncthreads();
        part[t] += v;
        __syncthreads();
    }
    int base = (t == 0) ? 0 : part[t - 1];
    for (int i = lo; i < hi; ++i) {
        row_ptr[i] = base;
        base += deg[i];
    }
    if (t == 1023) row_ptr[n] = part[1023];
}

__global__ void k_scatter(const int* __restrict__ ei, const int* __restrict__ row_ptr,
                          int* __restrict__ pos, int* __restrict__ csr_src) {
    int e = blockIdx.x * blockDim.x + threadIdx.x;
    if (e >= E_EDGES) return;
    int src = ei[e], dst = ei[E_EDGES + e];
    int p = atomicAdd(&pos[dst], 1);
    csr_src[row_ptr[dst] + p] = src;
}

// ---------------- fold attention vectors through W1 ----------------
__global__ void k_fold(const float* __restrict__ W1, const float* __restrict__ a_src,
                       const float* __restrict__ a_dst, float* __restrict__ wes,
                       float* __restrict__ wed) {
    int t = threadIdx.x;
    if (t >= 168) return;
    int which = t / 84;
    int idx = t % 84;
    int k = idx >> 2, h = idx & 3;
    const float* a = which ? a_dst : a_src;
    float s = 0.f;
    for (int c = 0; c < 128; ++c)
        s += W1[k * 512 + h * 128 + c] * a[h * 128 + c];
    (which ? wed : wes)[idx] = s;
}

// ---------------- layer-1 coefficients: es/ed = x @ w_es / w_ed ----------------
__global__ void k_l1_coef(const float* __restrict__ x, const float* __restrict__ wes,
                          const float* __restrict__ wed, float* __restrict__ es,
                          float* __restrict__ ed) {
    int node = blockIdx.x * blockDim.x + threadIdx.x;
    if (node >= N_NODES) return;
    const float* xr = x + (size_t)node * 21;
    float e1[4] = {0.f, 0.f, 0.f, 0.f}, e2[4] = {0.f, 0.f, 0.f, 0.f};
    #pragma unroll
    for (int k = 0; k < 21; ++k) {
        float xv = xr[k];
        float4 a = *(const float4*)&wes[k * 4];
        float4 b = *(const float4*)&wed[k * 4];
        e1[0] += xv * a.x; e1[1] += xv * a.y; e1[2] += xv * a.z; e1[3] += xv * a.w;
        e2[0] += xv * b.x; e2[1] += xv * b.y; e2[2] += xv * b.z; e2[3] += xv * b.w;
    }
    *(float4*)&es[node * 4] = make_float4(e1[0], e1[1], e1[2], e1[3]);
    *(float4*)&ed[node * 4] = make_float4(e2[0], e2[1], e2[2], e2[3]);
}

// ---------------- layer-1 edge phase on RAW x: wave per dst ----------------
__global__ void k_edge_l1x(const int* __restrict__ row_ptr, const int* __restrict__ csr_src,
                           const float* __restrict__ x, const float* __restrict__ es,
                           const float* __restrict__ ed, float* __restrict__ y) {
    int wid = (blockIdx.x * blockDim.x + threadIdx.x) >> 6;
    int l = threadIdx.x & 63;
    if (wid >= N_NODES) return;
    const int dst = wid;
    const int hh = l >> 4, sub = l & 15;
    const int beg = row_ptr[dst], end = row_ptr[dst + 1];
    const float eddg = ed[dst * 4 + hh];
    const float self_v = lrelu(es[dst * 4 + hh] + eddg);

    float m = self_v;
    for (int k = beg + sub; k < end; k += 16)
        m = fmaxf(m, lrelu(es[csr_src[k] * 4 + hh] + eddg));
    #pragma unroll
    for (int off = 1; off < 16; off <<= 1) m = fmaxf(m, __shfl_xor(m, off, 64));

    float s = 0.f;
    for (int k = beg + sub; k < end; k += 16)
        s += expf(lrelu(es[csr_src[k] * 4 + hh] + eddg) - m);
    #pragma unroll
    for (int off = 1; off < 16; off <<= 1) s += __shfl_xor(s, off, 64);
    float p_self = expf(self_v - m);
    s += p_self;
    float inv_s = 1.f / s;

    const bool act0 = (l < 63);
    const int h0 = act0 ? (l / 21) : 0;
    const int c0 = l - h0 * 21;
    float m0 = __shfl(m, h0 * 16, 64);
    float i0 = __shfl(inv_s, h0 * 16, 64);
    float e0d = __shfl(eddg, h0 * 16, 64);
    float ps0 = __shfl(p_self, h0 * 16, 64);
    const bool act1 = (l < 21);
    float m1 = __shfl(m, 48, 64);
    float i1 = __shfl(inv_s, 48, 64);
    float e1d = __shfl(eddg, 48, 64);
    float ps1 = __shfl(p_self, 48, 64);

    const float* xd = x + (size_t)dst * 21;
    float acc0 = act0 ? ps0 * i0 * xd[c0] : 0.f;
    float acc1 = act1 ? ps1 * i1 * xd[l] : 0.f;

    for (int k = beg; k < end; ++k) {
        int src = csr_src[k];
        const float* xs = x + (size_t)src * 21;
        float a0 = expf(lrelu(es[src * 4 + h0] + e0d) - m0) * i0;
        acc0 += a0 * xs[c0];
        if (act1) {
            float a1 = expf(lrelu(es[src * 4 + 3] + e1d) - m1) * i1;
            acc1 += a1 * xs[l];
        }
    }

    if (act0) y[(size_t)dst * 84 + l] = acc0;
    if (act1) y[(size_t)dst * 84 + 63 + l] = acc1;
}

// ---------------- layer-1 post v2: out1 = ELU(y@W1+b1) -> fp16 ----------------
// block=256 (4 waves); wave w handles head w of each node; thread owns cols (2t, 2t+1)
// W1 slice in registers (float2 x 21 = 42 VGPR); y row broadcast via shuffles.
__global__ void __launch_bounds__(256, 2) k_post2(const float* __restrict__ y,
                                                  const float* __restrict__ W1,
                                                  const float* __restrict__ b1,
                                                  __half* __restrict__ out1) {
    const int t = threadIdx.x;
    const int lane = t & 63;
    const int whead = t >> 6;          // wave index == head
    const int c2 = 2 * t;              // column pair (both in head `whead`)

    float2 wreg[21];
    #pragma unroll
    for (int j = 0; j < 21; ++j)
        wreg[j] = *(const float2*)&W1[j * 512 + c2];
    const float2 bb = *(const float2*)&b1[c2];

    for (int node = blockIdx.x; node < N_NODES; node += gridDim.x) {
        // y row into registers (lanes 0..63 hold y[0..63]; lanes 0..19 hold y[64..83])
        float yv0 = y[(size_t)node * 84 + lane];
        float yv1 = (lane < 20) ? y[(size_t)node * 84 + 64 + lane] : 0.f;

        float o0 = bb.x, o1 = bb.y;
        #pragma unroll
        for (int j = 0; j < 21; ++j) {
            int s = whead * 21 + j;
            float yv = (s < 64) ? __shfl(yv0, s, 64) : __shfl(yv1, s - 64, 64);
            o0 += yv * wreg[j].x;
            o1 += yv * wreg[j].y;
        }
        o0 = o0 > 0.f ? o0 : expm1f(o0);
        o1 = o1 > 0.f ? o1 : expm1f(o1);
        __half2 hv;
        hv.x = __float2half_rn(o0);
        hv.y = __float2half_rn(o1);
        *(__half2*)&out1[(size_t)node * 512 + c2] = hv;
    }
}

// ---------------- Layer 2: tiled GEMM (fp16 A @ f32 W2) + es/ed; h2 stored fp16 ----------------
__global__ void k_l2_gemm_coef(const __half* __restrict__ A16, const float* __restrict__ B,
                               const float* __restrict__ a_src, const float* __restrict__ a_dst,
                               __half* __restrict__ C16, float* __restrict__ es, float* __restrict__ ed) {
    __shared__ float AT[64][65];
    __shared__ float Bs[64][64];

    const int t = threadIdx.x;
    const int tr = t >> 4, tc = t & 15;
    const int row0 = blockIdx.x * 64;

    float acc[4][4];
    #pragma unroll
    for (int r = 0; r < 4; ++r)
        #pragma unroll
        for (int cc = 0; cc < 4; ++cc) acc[r][cc] = 0.f;

    for (int k0 = 0; k0 < 512; k0 += 64) {
        // stage A tile (fp16 -> f32 transposed)
        #pragma unroll
        for (int i = 0; i < 2; ++i) {
            int f = i * 256 + t;          // 512 slots of 8 halves
            int row = f >> 3, c8 = f & 7;
            int grow = row0 + row;
            union { uint4 u4; __half h[8]; } v;
            v.u4 = make_uint4(0, 0, 0, 0);
            if (grow < N_NODES)
                v.u4 = *(const uint4*)&A16[(size_t)grow * 512 + k0 + c8 * 8];
            #pragma unroll
            for (int j = 0; j < 8; ++j)
                AT[c8 * 8 + j][row] = __half2float(v.h[j]);
        }
        // stage B
        #pragma unroll
        for (int i = 0; i < 4; ++i) {
            int f = i * 256 + t;
            int row = f >> 4, c4 = f & 15;
            *(float4*)&Bs[row][c4 * 4] = *(const float4*)&B[(size_t)(k0 + row) * 64 + c4 * 4];
        }
        __syncthreads();
        #pragma unroll 8
        for (int kk = 0; kk < 64; ++kk) {
            float4 a4 = *(const float4*)&AT[kk][tr * 4];
            float4 b4 = *(const float4*)&Bs[kk][tc * 4];
            const float av[4] = {a4.x, a4.y, a4.z, a4.w};
            const float bv[4] = {b4.x, b4.y, b4.z, b4.w};
            #pragma unroll
            for (int r = 0; r < 4; ++r)
                #pragma unroll
                for (int cc = 0; cc < 4; ++cc)
                    acc[r][cc] += av[r] * bv[cc];
        }
        __syncthreads();
    }

    float4 as4 = *(const float4*)&a_src[tc * 4];
    float4 ad4 = *(const float4*)&a_dst[tc * 4];
    #pragma unroll
    for (int r = 0; r < 4; ++r) {
        int grow = row0 + tr * 4 + r;
        float4 cv = {acc[r][0], acc[r][1], acc[r][2], acc[r][3]};
        float p1 = cv.x * as4.x + cv.y * as4.y + cv.z * as4.z + cv.w * as4.w;
        float p2 = cv.x * ad4.x + cv.y * ad4.y + cv.z * ad4.z + cv.w * ad4.w;
        #pragma unroll
        for (int off = 8; off; off >>= 1) {
            p1 += __shfl_xor(p1, off, 64);
            p2 += __shfl_xor(p2, off, 64);
        }
        if (grow < N_NODES) {
            union { uint2 u2; __half h[4]; } o;
            o.h[0] = __float2half_rn(cv.x);
            o.h[1] = __float2half_rn(cv.y);
            o.h[2] = __float2half_rn(cv.z);
            o.h[3] = __float2half_rn(cv.w);
            *(uint2*)&C16[(size_t)grow * 64 + tc * 4] = o.u2;
            if (tc == 0) { es[grow] = p1; ed[grow] = p2; }
        }
    }
}

// ---------------- Layer 3: wave-per-node dot + es/ed ----------------
__global__ void k_l3_gemm_coef(const float* __restrict__ A, const float* __restrict__ W3,
                               const float* __restrict__ a_src, const float* __restrict__ a_dst,
                               float* __restrict__ h3, float* __restrict__ es, float* __restrict__ ed) {
    int gid = blockIdx.x * blockDim.x + threadIdx.x;
    int node = gid >> 6, lane = gid & 63;
    if (node >= N_NODES) return;
    float v = A[(size_t)node * 64 + lane] * W3[lane];
    v = wave_red_sum64(v);
    if (lane == 0) {
        h3[node] = v;
        es[node] = v * a_src[0];
        ed[node] = v * a_dst[0];
    }
}

// ---------------- Layer 2 edge phase: wave per dst, 4 edge-groups, fp16 gather ----------------
__global__ void k_gat_edge_l2(const int* __restrict__ row_ptr, const int* __restrict__ csr_src,
                              const __half* __restrict__ h16, const float* __restrict__ es,
                              const float* __restrict__ ed, const float* __restrict__ b,
                              float* __restrict__ out) {
    int wid = (blockIdx.x * blockDim.x + threadIdx.x) >> 6;
    int lane = threadIdx.x & 63;
    if (wid >= N_NODES) return;
    const int dst = wid;
    const int g = lane >> 4, sub = lane & 15;
    const int beg = row_ptr[dst], end = row_ptr[dst + 1];
    const float edd = ed[dst];
    const float self_v = lrelu(es[dst] + edd);

    float m = self_v;
    for (int k = beg + lane; k < end; k += 64)
        m = fmaxf(m, lrelu(es[csr_src[k]] + edd));
    #pragma unroll
    for (int off = 32; off; off >>= 1) m = fmaxf(m, __shfl_xor(m, off, 64));

    float s = 0.f;
    for (int k = beg + lane; k < end; k += 64)
        s += expf(lrelu(es[csr_src[k]] + edd) - m);
    #pragma unroll
    for (int off = 32; off; off >>= 1) s += __shfl_xor(s, off, 64);
    float p_self = expf(self_v - m);
    s += p_self;
    const float inv_s = 1.f / s;

    float acc[4] = {0.f, 0.f, 0.f, 0.f};
    if (g == 0) {
        uint2 r = *(const uint2*)(h16 + (size_t)dst * 64 + sub * 4);
        float hv[4]; h4_to_f4(r, hv);
        float a_self = p_self * inv_s;
        #pragma unroll
        for (int j = 0; j < 4; ++j) acc[j] = a_self * hv[j];
    }
    for (int k0 = beg; k0 < end; k0 += 4) {
        int k = k0 + g;
        if (k < end) {
            int src = csr_src[k];
            float alpha = expf(lrelu(es[src] + edd) - m) * inv_s;
            uint2 r = *(const uint2*)(h16 + (size_t)src * 64 + sub * 4);
            float hv[4]; h4_to_f4(r, hv);
            #pragma unroll
            for (int j = 0; j < 4; ++j) acc[j] += alpha * hv[j];
        }
    }
    #pragma unroll
    for (int off = 16; off < 64; off <<= 1) {
        #pragma unroll
        for (int j = 0; j < 4; ++j) acc[j] += __shfl_xor(acc[j], off, 64);
    }
    if (g == 0) {
        float4 bv = *(const float4*)&b[sub * 4];
        float o[4] = {acc[0] + bv.x, acc[1] + bv.y, acc[2] + bv.z, acc[3] + bv.w};
        #pragma unroll
        for (int j = 0; j < 4; ++j) o[j] = o[j] > 0.f ? o[j] : expm1f(o[j]);
        *(float4*)&out[(size_t)dst * 64 + sub * 4] = make_float4(o[0], o[1], o[2], o[3]);
    }
}

// ---------------- layer 3 edge phase (H=1, C=1) ----------------
__global__ void k_gat_edge_c1(const int* __restrict__ row_ptr, const int* __restrict__ csr_src,
                              const float* __restrict__ h, const float* __restrict__ es,
                              const float* __restrict__ ed, float* __restrict__ out) {
    int dst = blockIdx.x * blockDim.x + threadIdx.x;
    if (dst >= N_NODES) return;
    int beg = row_ptr[dst], end = row_ptr[dst + 1];
    float edd = ed[dst];
    float self_v = lrelu(es[dst] + edd);
    float m = self_v;
    for (int k = beg; k < end; ++k) m = fmaxf(m, lrelu(es[csr_src[k]] + edd));
    float p = expf(self_v - m);
    float s = p;
    float acc = p * h[dst];
    for (int k = beg; k < end; ++k) {
        int src = csr_src[k];
        float pv = expf(lrelu(es[src] + edd) - m);
        s += pv;
        acc += pv * h[src];
    }
    out[dst] = acc / s;
}

// ---------------- final mean + b3 ----------------
__global__ void k_mean(const float* __restrict__ v, const float* __restrict__ b3,
                       float* __restrict__ out, int n) {
    __shared__ float sdata[256];
    float local = 0.f;
    for (int i = blockIdx.x * blockDim.x + threadIdx.x; i < n; i += gridDim.x * blockDim.x)
        local += v[i];
    sdata[threadIdx.x] = local;
    __syncthreads();
    for (int sft = 128; sft > 0; sft >>= 1) {
        if (threadIdx.x < sft) sdata[threadIdx.x] += sdata[threadIdx.x + sft];
        __syncthreads();
    }
    if (threadIdx.x == 0) {
        float add = sdata[0] / (float)n;
        if (blockIdx.x == 0) add += b3[0];
        atomicAdd(out, add);
    }
}

extern "C" void kernel_launch(void* const* d_in, const int* in_sizes, int n_in,
                              void* d_out, int out_size, void* d_ws, size_t ws_size,
                              hipStream_t stream) {
    const float* x      = (const float*)d_in[0];
    const float* W1     = (const float*)d_in[1];
    const float* a_src1 = (const float*)d_in[2];
    const float* a_dst1 = (const float*)d_in[3];
    const float* b1     = (const float*)d_in[4];
    const float* W2     = (const float*)d_in[5];
    const float* a_src2 = (const float*)d_in[6];
    const float* a_dst2 = (const float*)d_in[7];
    const float* b2     = (const float*)d_in[8];
    const float* W3     = (const float*)d_in[9];
    const float* a_src3 = (const float*)d_in[10];
    const float* a_dst3 = (const float*)d_in[11];
    const float* b3     = (const float*)d_in[12];
    const int*   ei     = (const int*)d_in[13];
    float* out = (float*)d_out;

    const int BS = 256;
    const size_t N = N_NODES;

    // workspace layout (float units)
    float*  ws      = (float*)d_ws;
    __half* out1h   = (__half*)ws;                 // N*512 halves = N*256 floats
    float*  y_buf   = ws + N * 256;                // N*84
    __half* h2_16   = (__half*)(y_buf + N * 84);   // N*64 halves = N*32 floats
    float*  out2    = y_buf + N * 84 + N * 32;     // N*64
    float*  h3raw   = out2 + N * 64;               // N
    float*  out3    = h3raw + N;                   // N
    float*  es_buf  = out3 + N;                    // N*4
    float*  ed_buf  = es_buf + N * 4;              // N*4
    float*  wes     = ed_buf + N * 4;              // 88 (padded)
    float*  wed     = wes + 88;                    // 88
    int*    deg     = (int*)(wed + 88);            // N
    int*    row_ptr = deg + N;                     // N+1
    int*    csr_src = row_ptr + N + 1;             // E_EDGES

    // CSR build (shared by all 3 layers)
    hipMemsetAsync(deg, 0, N * sizeof(int), stream);
    k_count<<<cdiv(E_EDGES, BS), BS, 0, stream>>>(ei, deg);
    k_scan<<<1, 1024, 0, stream>>>(deg, row_ptr, N_NODES);
    hipMemsetAsync(deg, 0, N * sizeof(int), stream);
    k_scatter<<<cdiv(E_EDGES, BS), BS, 0, stream>>>(ei, row_ptr, deg, csr_src);

    // Layer 1: H=4, C=128 — aggregate raw x, then per-node GEMM (y -> out1 fp16)
    k_fold<<<1, 256, 0, stream>>>(W1, a_src1, a_dst1, wes, wed);
    k_l1_coef<<<cdiv((long)N, BS), BS, 0, stream>>>(x, wes, wed, es_buf, ed_buf);
    k_edge_l1x<<<cdiv((long)N * 64, BS), BS, 0, stream>>>(row_ptr, csr_src, x, es_buf, ed_buf, y_buf);
    k_post2<<<2048, 256, 0, stream>>>(y_buf, W1, b1, out1h);

    // Layer 2: H=1, C=64
    k_l2_gemm_coef<<<cdiv(N_NODES, 64), 256, 0, stream>>>(out1h, W2, a_src2, a_dst2, h2_16, es_buf, ed_buf);
    k_gat_edge_l2<<<cdiv((long)N * 64, BS), BS, 0, stream>>>(row_ptr, csr_src, h2_16, es_buf, ed_buf, b2, out2);

    // Layer 3: H=1, C=1
    k_l3_gemm_coef<<<cdiv((long)N * 64, BS), BS, 0, stream>>>(out2, W3, a_src3, a_dst3, h3raw, es_buf, ed_buf);
    k_gat_edge_c1<<<cdiv((long)N, BS), BS, 0, stream>>>(row_ptr, csr_src, h3raw, es_buf, ed_buf, out3);

    hipMemsetAsync(out, 0, sizeof(float), stream);
    k_mean<<<256, 256, 0, stream>>>(out3, b3, out, N_NODES);
}

// Round 10
// 292.172 us; speedup vs baseline: 1.4686x; 1.3602x over previous
//
#include <hip/hip_runtime.h>
#include <hip/hip_fp16.h>
#include <math.h>

#define N_NODES 50000
#define E_EDGES 400000
#define NEG_SLOPE 0.2f
#define SCAN_BLOCKS 250
#define SCAN_CHUNK 200

static inline int cdiv(long a, int b) { return (int)((a + b - 1) / b); }

__device__ __forceinline__ float lrelu(float v) {
    return v > 0.f ? v : NEG_SLOPE * v;
}

__device__ __forceinline__ float wave_red_sum64(float v) {
    #pragma unroll
    for (int off = 32; off; off >>= 1) v += __shfl_xor(v, off, 64);
    return v;
}

__device__ __forceinline__ void h4_to_f4(uint2 u, float o[4]) {
    union { uint2 u2; __half h[4]; } cv;
    cv.u2 = u;
    #pragma unroll
    for (int i = 0; i < 4; ++i) o[i] = __half2float(cv.h[i]);
}

// ---------------- CSR build ----------------
__global__ void k_count(const int* __restrict__ ei, int* __restrict__ deg) {
    int e = blockIdx.x * blockDim.x + threadIdx.x;
    if (e >= E_EDGES) return;
    atomicAdd(&deg[ei[E_EDGES + e]], 1);
}

// 3-phase parallel exclusive scan of deg[50000] -> row_ptr[50001]
__global__ void k_scan1(const int* __restrict__ deg, int* __restrict__ bsum) {
    __shared__ int sd[256];
    int b = blockIdx.x, t = threadIdx.x;
    int lo = b * SCAN_CHUNK;
    int s = 0;
    for (int i = t; i < SCAN_CHUNK; i += 256) s += deg[lo + i];
    sd[t] = s;
    __syncthreads();
    for (int off = 128; off; off >>= 1) {
        if (t < off) sd[t] += sd[t + off];
        __syncthreads();
    }
    if (t == 0) bsum[b] = sd[0];
}

__global__ void k_scan2(int* __restrict__ bsum) {
    __shared__ int sd[256];
    int t = threadIdx.x;
    int v = (t < SCAN_BLOCKS) ? bsum[t] : 0;
    sd[t] = v;
    __syncthreads();
    for (int off = 1; off < 256; off <<= 1) {
        int u = (t >= off) ? sd[t - off] : 0;
        __syncthreads();
        sd[t] += u;
        __syncthreads();
    }
    if (t < SCAN_BLOCKS) bsum[t] = sd[t] - v;   // exclusive
}

__global__ void k_scan3(const int* __restrict__ deg, const int* __restrict__ bsum,
                        int* __restrict__ row_ptr) {
    __shared__ int sd[256];
    int b = blockIdx.x, t = threadIdx.x;
    int lo = b * SCAN_CHUNK;
    int v = (t < SCAN_CHUNK) ? deg[lo + t] : 0;
    sd[t] = v;
    __syncthreads();
    for (int off = 1; off < 256; off <<= 1) {
        int u = (t >= off) ? sd[t - off] : 0;
        __syncthreads();
        sd[t] += u;
        __syncthreads();
    }
    if (t < SCAN_CHUNK) row_ptr[lo + t] = bsum[b] + sd[t] - v;
    if (b == 0 && t == 0) row_ptr[N_NODES] = E_EDGES;
}

__global__ void k_scatter(const int* __restrict__ ei, const int* __restrict__ row_ptr,
                          int* __restrict__ pos, int* __restrict__ csr_src) {
    int e = blockIdx.x * blockDim.x + threadIdx.x;
    if (e >= E_EDGES) return;
    int src = ei[e], dst = ei[E_EDGES + e];
    int p = atomicAdd(&pos[dst], 1);
    csr_src[row_ptr[dst] + p] = src;
}

// ---------------- fold attention vectors through W1 ----------------
__global__ void k_fold(const float* __restrict__ W1, const float* __restrict__ a_src,
                       const float* __restrict__ a_dst, float* __restrict__ wes,
                       float* __restrict__ wed) {
    int t = threadIdx.x;
    if (t >= 168) return;
    int which = t / 84;
    int idx = t % 84;
    int k = idx >> 2, h = idx & 3;
    const float* a = which ? a_dst : a_src;
    float s = 0.f;
    for (int c = 0; c < 128; ++c)
        s += W1[k * 512 + h * 128 + c] * a[h * 128 + c];
    (which ? wed : wes)[idx] = s;
}

// ---------------- layer-1 coefficients: es/ed = x @ w_es / w_ed ----------------
__global__ void k_l1_coef(const float* __restrict__ x, const float* __restrict__ wes,
                          const float* __restrict__ wed, float* __restrict__ es,
                          float* __restrict__ ed) {
    int node = blockIdx.x * blockDim.x + threadIdx.x;
    if (node >= N_NODES) return;
    const float* xr = x + (size_t)node * 21;
    float e1[4] = {0.f, 0.f, 0.f, 0.f}, e2[4] = {0.f, 0.f, 0.f, 0.f};
    #pragma unroll
    for (int k = 0; k < 21; ++k) {
        float xv = xr[k];
        float4 a = *(const float4*)&wes[k * 4];
        float4 b = *(const float4*)&wed[k * 4];
        e1[0] += xv * a.x; e1[1] += xv * a.y; e1[2] += xv * a.z; e1[3] += xv * a.w;
        e2[0] += xv * b.x; e2[1] += xv * b.y; e2[2] += xv * b.z; e2[3] += xv * b.w;
    }
    *(float4*)&es[node * 4] = make_float4(e1[0], e1[1], e1[2], e1[3]);
    *(float4*)&ed[node * 4] = make_float4(e2[0], e2[1], e2[2], e2[3]);
}

// ---------------- layer-1 edge phase on RAW x ----------------
// softmax stats: 16 lanes per head. aggregation: 3 edge-groups x 21 channels,
// each lane accumulates ALL 4 heads for its channel (x value shared across heads).
// Self-loop contribution added ONLY in group 0 (groups are reduced at the end).
__global__ void k_edge_l1x(const int* __restrict__ row_ptr, const int* __restrict__ csr_src,
                           const float* __restrict__ x, const float* __restrict__ es,
                           const float* __restrict__ ed, float* __restrict__ y) {
    int wid = (blockIdx.x * blockDim.x + threadIdx.x) >> 6;
    int l = threadIdx.x & 63;
    if (wid >= N_NODES) return;
    const int dst = wid;
    const int hh = l >> 4, sub = l & 15;
    const int beg = row_ptr[dst], end = row_ptr[dst + 1];
    const float eddg = ed[dst * 4 + hh];
    const float self_v = lrelu(es[dst * 4 + hh] + eddg);

    // pass 1: per-head max
    float m = self_v;
    for (int k = beg + sub; k < end; k += 16)
        m = fmaxf(m, lrelu(es[csr_src[k] * 4 + hh] + eddg));
    #pragma unroll
    for (int off = 1; off < 16; off <<= 1) m = fmaxf(m, __shfl_xor(m, off, 64));

    // pass 2: per-head sum of exp
    float s = 0.f;
    for (int k = beg + sub; k < end; k += 16)
        s += __expf(lrelu(es[csr_src[k] * 4 + hh] + eddg) - m);
    #pragma unroll
    for (int off = 1; off < 16; off <<= 1) s += __shfl_xor(s, off, 64);
    float p_self = __expf(self_v - m);
    s += p_self;
    float inv_s = 1.f / s;

    // broadcast per-head stats to all lanes
    float mh[4], ih[4], eh[4], ph[4];
    #pragma unroll
    for (int h = 0; h < 4; ++h) {
        mh[h] = __shfl(m, h * 16, 64);
        ih[h] = __shfl(inv_s, h * 16, 64);
        eh[h] = __shfl(eddg, h * 16, 64);
        ph[h] = __shfl(p_self, h * 16, 64);
    }

    // aggregation: lane l<63: group g=l/21 walks edges beg+g, beg+g+3, ...
    const int g = l / 21;            // lane 63 -> g=3 (inactive)
    const int c = l - g * 21;
    const bool act = (l < 63);

    // self term only once (group 0); groups are summed in the final reduce
    float xdv = (act && g == 0) ? x[(size_t)dst * 21 + c] : 0.f;
    float acc[4];
    #pragma unroll
    for (int h = 0; h < 4; ++h) acc[h] = ph[h] * ih[h] * xdv;

    if (act) {
        int k = beg + g;
        for (; k + 3 < end; k += 6) {
            int s0 = csr_src[k], s1 = csr_src[k + 3];
            float4 e0 = *(const float4*)&es[s0 * 4];
            float4 e1 = *(const float4*)&es[s1 * 4];
            float x0 = x[(size_t)s0 * 21 + c];
            float x1 = x[(size_t)s1 * 21 + c];
            #pragma unroll
            for (int h = 0; h < 4; ++h) {
                float a0 = __expf(lrelu((&e0.x)[h] + eh[h]) - mh[h]) * ih[h];
                float a1 = __expf(lrelu((&e1.x)[h] + eh[h]) - mh[h]) * ih[h];
                acc[h] += a0 * x0 + a1 * x1;
            }
        }
        if (k < end) {
            int s0 = csr_src[k];
            float4 e0 = *(const float4*)&es[s0 * 4];
            float x0 = x[(size_t)s0 * 21 + c];
            #pragma unroll
            for (int h = 0; h < 4; ++h) {
                float a0 = __expf(lrelu((&e0.x)[h] + eh[h]) - mh[h]) * ih[h];
                acc[h] += a0 * x0;
            }
        }
    }

    // 3-way reduce across edge-groups, then lanes 0..20 write all 4 heads
    #pragma unroll
    for (int h = 0; h < 4; ++h) {
        float a1 = __shfl(acc[h], (l + 21) & 63, 64);
        float a2 = __shfl(acc[h], (l + 42) & 63, 64);
        acc[h] += a1 + a2;
    }
    if (l < 21) {
        #pragma unroll
        for (int h = 0; h < 4; ++h)
            y[(size_t)dst * 84 + h * 21 + l] = acc[h];
    }
}

// ---------------- layer-1 post: out1 = ELU(y@W1+b1) -> fp16 ----------------
__global__ void __launch_bounds__(256, 2) k_post2(const float* __restrict__ y,
                                                  const float* __restrict__ W1,
                                                  const float* __restrict__ b1,
                                                  __half* __restrict__ out1) {
    const int t = threadIdx.x;
    const int lane = t & 63;
    const int whead = t >> 6;
    const int c2 = 2 * t;

    float2 wreg[21];
    #pragma unroll
    for (int j = 0; j < 21; ++j)
        wreg[j] = *(const float2*)&W1[j * 512 + c2];
    const float2 bb = *(const float2*)&b1[c2];

    for (int node = blockIdx.x; node < N_NODES; node += gridDim.x) {
        float yv0 = y[(size_t)node * 84 + lane];
        float yv1 = (lane < 20) ? y[(size_t)node * 84 + 64 + lane] : 0.f;

        float o0 = bb.x, o1 = bb.y;
        #pragma unroll
        for (int j = 0; j < 21; ++j) {
            int s = whead * 21 + j;
            float yv = (s < 64) ? __shfl(yv0, s, 64) : __shfl(yv1, s - 64, 64);
            o0 += yv * wreg[j].x;
            o1 += yv * wreg[j].y;
        }
        o0 = o0 > 0.f ? o0 : expm1f(o0);
        o1 = o1 > 0.f ? o1 : expm1f(o1);
        __half2 hv;
        hv.x = __float2half_rn(o0);
        hv.y = __float2half_rn(o1);
        *(__half2*)&out1[(size_t)node * 512 + c2] = hv;
    }
}

// ---------------- Layer 2: tiled GEMM (fp16 A @ f32 W2) + es/ed; h2 stored fp16 ----------------
__global__ void k_l2_gemm_coef(const __half* __restrict__ A16, const float* __restrict__ B,
                               const float* __restrict__ a_src, const float* __restrict__ a_dst,
                               __half* __restrict__ C16, float* __restrict__ es, float* __restrict__ ed) {
    __shared__ float AT[64][65];
    __shared__ float Bs[64][64];

    const int t = threadIdx.x;
    const int tr = t >> 4, tc = t & 15;
    const int row0 = blockIdx.x * 64;

    float acc[4][4];
    #pragma unroll
    for (int r = 0; r < 4; ++r)
        #pragma unroll
        for (int cc = 0; cc < 4; ++cc) acc[r][cc] = 0.f;

    for (int k0 = 0; k0 < 512; k0 += 64) {
        #pragma unroll
        for (int i = 0; i < 2; ++i) {
            int f = i * 256 + t;
            int row = f >> 3, c8 = f & 7;
            int grow = row0 + row;
            union { uint4 u4; __half h[8]; } v;
            v.u4 = make_uint4(0, 0, 0, 0);
            if (grow < N_NODES)
                v.u4 = *(const uint4*)&A16[(size_t)grow * 512 + k0 + c8 * 8];
            #pragma unroll
            for (int j = 0; j < 8; ++j)
                AT[c8 * 8 + j][row] = __half2float(v.h[j]);
        }
        #pragma unroll
        for (int i = 0; i < 4; ++i) {
            int f = i * 256 + t;
            int row = f >> 4, c4 = f & 15;
            *(float4*)&Bs[row][c4 * 4] = *(const float4*)&B[(size_t)(k0 + row) * 64 + c4 * 4];
        }
        __syncthreads();
        #pragma unroll 8
        for (int kk = 0; kk < 64; ++kk) {
            float4 a4 = *(const float4*)&AT[kk][tr * 4];
            float4 b4 = *(const float4*)&Bs[kk][tc * 4];
            const float av[4] = {a4.x, a4.y, a4.z, a4.w};
            const float bv[4] = {b4.x, b4.y, b4.z, b4.w};
            #pragma unroll
            for (int r = 0; r < 4; ++r)
                #pragma unroll
                for (int cc = 0; cc < 4; ++cc)
                    acc[r][cc] += av[r] * bv[cc];
        }
        __syncthreads();
    }

    float4 as4 = *(const float4*)&a_src[tc * 4];
    float4 ad4 = *(const float4*)&a_dst[tc * 4];
    #pragma unroll
    for (int r = 0; r < 4; ++r) {
        int grow = row0 + tr * 4 + r;
        float4 cv = {acc[r][0], acc[r][1], acc[r][2], acc[r][3]};
        float p1 = cv.x * as4.x + cv.y * as4.y + cv.z * as4.z + cv.w * as4.w;
        float p2 = cv.x * ad4.x + cv.y * ad4.y + cv.z * ad4.z + cv.w * ad4.w;
        #pragma unroll
        for (int off = 8; off; off >>= 1) {
            p1 += __shfl_xor(p1, off, 64);
            p2 += __shfl_xor(p2, off, 64);
        }
        if (grow < N_NODES) {
            union { uint2 u2; __half h[4]; } o;
            o.h[0] = __float2half_rn(cv.x);
            o.h[1] = __float2half_rn(cv.y);
            o.h[2] = __float2half_rn(cv.z);
            o.h[3] = __float2half_rn(cv.w);
            *(uint2*)&C16[(size_t)grow * 64 + tc * 4] = o.u2;
            if (tc == 0) { es[grow] = p1; ed[grow] = p2; }
        }
    }
}

// ---------------- Layer 3: wave-per-node dot + es/ed ----------------
__global__ void k_l3_gemm_coef(const float* __restrict__ A, const float* __restrict__ W3,
                               const float* __restrict__ a_src, const float* __restrict__ a_dst,
                               float* __restrict__ h3, float* __restrict__ es, float* __restrict__ ed) {
    int gid = blockIdx.x * blockDim.x + threadIdx.x;
    int node = gid >> 6, lane = gid & 63;
    if (node >= N_NODES) return;
    float v = A[(size_t)node * 64 + lane] * W3[lane];
    v = wave_red_sum64(v);
    if (lane == 0) {
        h3[node] = v;
        es[node] = v * a_src[0];
        ed[node] = v * a_dst[0];
    }
}

// ---------------- Layer 2 edge phase: wave per dst, 4 edge-groups, fp16 gather ----------------
__global__ void k_gat_edge_l2(const int* __restrict__ row_ptr, const int* __restrict__ csr_src,
                              const __half* __restrict__ h16, const float* __restrict__ es,
                              const float* __restrict__ ed, const float* __restrict__ b,
                              float* __restrict__ out) {
    int wid = (blockIdx.x * blockDim.x + threadIdx.x) >> 6;
    int lane = threadIdx.x & 63;
    if (wid >= N_NODES) return;
    const int dst = wid;
    const int g = lane >> 4, sub = lane & 15;
    const int beg = row_ptr[dst], end = row_ptr[dst + 1];
    const float edd = ed[dst];
    const float self_v = lrelu(es[dst] + edd);

    float m = self_v;
    for (int k = beg + lane; k < end; k += 64)
        m = fmaxf(m, lrelu(es[csr_src[k]] + edd));
    #pragma unroll
    for (int off = 32; off; off >>= 1) m = fmaxf(m, __shfl_xor(m, off, 64));

    float s = 0.f;
    for (int k = beg + lane; k < end; k += 64)
        s += __expf(lrelu(es[csr_src[k]] + edd) - m);
    #pragma unroll
    for (int off = 32; off; off >>= 1) s += __shfl_xor(s, off, 64);
    float p_self = __expf(self_v - m);
    s += p_self;
    const float inv_s = 1.f / s;

    float acc[4] = {0.f, 0.f, 0.f, 0.f};
    if (g == 0) {
        uint2 r = *(const uint2*)(h16 + (size_t)dst * 64 + sub * 4);
        float hv[4]; h4_to_f4(r, hv);
        float a_self = p_self * inv_s;
        #pragma unroll
        for (int j = 0; j < 4; ++j) acc[j] = a_self * hv[j];
    }
    for (int k0 = beg; k0 < end; k0 += 4) {
        int k = k0 + g;
        if (k < end) {
            int src = csr_src[k];
            float alpha = __expf(lrelu(es[src] + edd) - m) * inv_s;
            uint2 r = *(const uint2*)(h16 + (size_t)src * 64 + sub * 4);
            float hv[4]; h4_to_f4(r, hv);
            #pragma unroll
            for (int j = 0; j < 4; ++j) acc[j] += alpha * hv[j];
        }
    }
    #pragma unroll
    for (int off = 16; off < 64; off <<= 1) {
        #pragma unroll
        for (int j = 0; j < 4; ++j) acc[j] += __shfl_xor(acc[j], off, 64);
    }
    if (g == 0) {
        float4 bv = *(const float4*)&b[sub * 4];
        float o[4] = {acc[0] + bv.x, acc[1] + bv.y, acc[2] + bv.z, acc[3] + bv.w};
        #pragma unroll
        for (int j = 0; j < 4; ++j) o[j] = o[j] > 0.f ? o[j] : expm1f(o[j]);
        *(float4*)&out[(size_t)dst * 64 + sub * 4] = make_float4(o[0], o[1], o[2], o[3]);
    }
}

// ---------------- layer 3 edge phase (H=1, C=1) ----------------
__global__ void k_gat_edge_c1(const int* __restrict__ row_ptr, const int* __restrict__ csr_src,
                              const float* __restrict__ h, const float* __restrict__ es,
                              const float* __restrict__ ed, float* __restrict__ out) {
    int dst = blockIdx.x * blockDim.x + threadIdx.x;
    if (dst >= N_NODES) return;
    int beg = row_ptr[dst], end = row_ptr[dst + 1];
    float edd = ed[dst];
    float self_v = lrelu(es[dst] + edd);
    float m = self_v;
    for (int k = beg; k < end; ++k) m = fmaxf(m, lrelu(es[csr_src[k]] + edd));
    float p = __expf(self_v - m);
    float s = p;
    float acc = p * h[dst];
    for (int k = beg; k < end; ++k) {
        int src = csr_src[k];
        float pv = __expf(lrelu(es[src] + edd) - m);
        s += pv;
        acc += pv * h[src];
    }
    out[dst] = acc / s;
}

// ---------------- final mean + b3 ----------------
__global__ void k_mean(const float* __restrict__ v, const float* __restrict__ b3,
                       float* __restrict__ out, int n) {
    __shared__ float sdata[256];
    float local = 0.f;
    for (int i = blockIdx.x * blockDim.x + threadIdx.x; i < n; i += gridDim.x * blockDim.x)
        local += v[i];
    sdata[threadIdx.x] = local;
    __syncthreads();
    for (int sft = 128; sft > 0; sft >>= 1) {
        if (threadIdx.x < sft) sdata[threadIdx.x] += sdata[threadIdx.x + sft];
        __syncthreads();
    }
    if (threadIdx.x == 0) {
        float add = sdata[0] / (float)n;
        if (blockIdx.x == 0) add += b3[0];
        atomicAdd(out, add);
    }
}

extern "C" void kernel_launch(void* const* d_in, const int* in_sizes, int n_in,
                              void* d_out, int out_size, void* d_ws, size_t ws_size,
                              hipStream_t stream) {
    const float* x      = (const float*)d_in[0];
    const float* W1     = (const float*)d_in[1];
    const float* a_src1 = (const float*)d_in[2];
    const float* a_dst1 = (const float*)d_in[3];
    const float* b1     = (const float*)d_in[4];
    const float* W2     = (const float*)d_in[5];
    const float* a_src2 = (const float*)d_in[6];
    const float* a_dst2 = (const float*)d_in[7];
    const float* b2     = (const float*)d_in[8];
    const float* W3     = (const float*)d_in[9];
    const float* a_src3 = (const float*)d_in[10];
    const float* a_dst3 = (const float*)d_in[11];
    const float* b3     = (const float*)d_in[12];
    const int*   ei     = (const int*)d_in[13];
    float* out = (float*)d_out;

    const int BS = 256;
    const size_t N = N_NODES;

    // workspace layout (float units)
    float*  ws      = (float*)d_ws;
    __half* out1h   = (__half*)ws;                 // N*512 halves = N*256 floats
    float*  y_buf   = ws + N * 256;                // N*84
    __half* h2_16   = (__half*)(y_buf + N * 84);   // N*64 halves = N*32 floats
    float*  out2    = y_buf + N * 84 + N * 32;     // N*64
    float*  h3raw   = out2 + N * 64;               // N
    float*  out3    = h3raw + N;                   // N
    float*  es_buf  = out3 + N;                    // N*4 (16B aligned)
    float*  ed_buf  = es_buf + N * 4;              // N*4
    float*  wes     = ed_buf + N * 4;              // 88 (padded)
    float*  wed     = wes + 88;                    // 88
    int*    deg     = (int*)(wed + 88);            // N
    int*    row_ptr = deg + N;                     // N+1
    int*    csr_src = row_ptr + N + 1;             // E_EDGES
    int*    bsum    = csr_src + E_EDGES;           // 256

    // CSR build (shared by all 3 layers)
    hipMemsetAsync(deg, 0, N * sizeof(int), stream);
    k_count<<<cdiv(E_EDGES, BS), BS, 0, stream>>>(ei, deg);
    k_scan1<<<SCAN_BLOCKS, 256, 0, stream>>>(deg, bsum);
    k_scan2<<<1, 256, 0, stream>>>(bsum);
    k_scan3<<<SCAN_BLOCKS, 256, 0, stream>>>(deg, bsum, row_ptr);
    hipMemsetAsync(deg, 0, N * sizeof(int), stream);
    k_scatter<<<cdiv(E_EDGES, BS), BS, 0, stream>>>(ei, row_ptr, deg, csr_src);

    // Layer 1: H=4, C=128 — aggregate raw x, then per-node GEMM (y -> out1 fp16)
    k_fold<<<1, 256, 0, stream>>>(W1, a_src1, a_dst1, wes, wed);
    k_l1_coef<<<cdiv((long)N, BS), BS, 0, stream>>>(x, wes, wed, es_buf, ed_buf);
    k_edge_l1x<<<cdiv((long)N * 64, BS), BS, 0, stream>>>(row_ptr, csr_src, x, es_buf, ed_buf, y_buf);
    k_post2<<<2048, 256, 0, stream>>>(y_buf, W1, b1, out1h);

    // Layer 2: H=1, C=64
    k_l2_gemm_coef<<<cdiv(N_NODES, 64), 256, 0, stream>>>(out1h, W2, a_src2, a_dst2, h2_16, es_buf, ed_buf);
    k_gat_edge_l2<<<cdiv((long)N * 64, BS), BS, 0, stream>>>(row_ptr, csr_src, h2_16, es_buf, ed_buf, b2, out2);

    // Layer 3: H=1, C=1
    k_l3_gemm_coef<<<cdiv((long)N * 64, BS), BS, 0, stream>>>(out2, W3, a_src3, a_dst3, h3raw, es_buf, ed_buf);
    k_gat_edge_c1<<<cdiv((long)N, BS), BS, 0, stream>>>(row_ptr, csr_src, h3raw, es_buf, ed_buf, out3);

    hipMemsetAsync(out, 0, sizeof(float), stream);
    k_mean<<<256, 256, 0, stream>>>(out3, b3, out, N_NODES);
}

// Round 11
// 265.668 us; speedup vs baseline: 1.6152x; 1.0998x over previous
//
#include <hip/hip_runtime.h>
#include <hip/hip_fp16.h>
#include <math.h>

#define N_NODES 50000
#define E_EDGES 400000
#define NEG_SLOPE 0.2f
#define SCAN_BLOCKS 250
#define SCAN_CHUNK 200

static inline int cdiv(long a, int b) { return (int)((a + b - 1) / b); }

__device__ __forceinline__ float lrelu(float v) {
    return v > 0.f ? v : NEG_SLOPE * v;
}

__device__ __forceinline__ float wave_red_sum64(float v) {
    #pragma unroll
    for (int off = 32; off; off >>= 1) v += __shfl_xor(v, off, 64);
    return v;
}

__device__ __forceinline__ void h4_to_f4(uint2 u, float o[4]) {
    union { uint2 u2; __half h[4]; } cv;
    cv.u2 = u;
    #pragma unroll
    for (int i = 0; i < 4; ++i) o[i] = __half2float(cv.h[i]);
}

// ---------------- CSR build ----------------
__global__ void k_count(const int* __restrict__ ei, int* __restrict__ deg) {
    int e = blockIdx.x * blockDim.x + threadIdx.x;
    if (e >= E_EDGES) return;
    atomicAdd(&deg[ei[E_EDGES + e]], 1);
}

// 3-phase parallel exclusive scan of deg[50000] -> row_ptr[50001]
__global__ void k_scan1(const int* __restrict__ deg, int* __restrict__ bsum) {
    __shared__ int sd[256];
    int b = blockIdx.x, t = threadIdx.x;
    int lo = b * SCAN_CHUNK;
    int s = 0;
    for (int i = t; i < SCAN_CHUNK; i += 256) s += deg[lo + i];
    sd[t] = s;
    __syncthreads();
    for (int off = 128; off; off >>= 1) {
        if (t < off) sd[t] += sd[t + off];
        __syncthreads();
    }
    if (t == 0) bsum[b] = sd[0];
}

__global__ void k_scan2(int* __restrict__ bsum) {
    __shared__ int sd[256];
    int t = threadIdx.x;
    int v = (t < SCAN_BLOCKS) ? bsum[t] : 0;
    sd[t] = v;
    __syncthreads();
    for (int off = 1; off < 256; off <<= 1) {
        int u = (t >= off) ? sd[t - off] : 0;
        __syncthreads();
        sd[t] += u;
        __syncthreads();
    }
    if (t < SCAN_BLOCKS) bsum[t] = sd[t] - v;   // exclusive
}

__global__ void k_scan3(const int* __restrict__ deg, const int* __restrict__ bsum,
                        int* __restrict__ row_ptr) {
    __shared__ int sd[256];
    int b = blockIdx.x, t = threadIdx.x;
    int lo = b * SCAN_CHUNK;
    int v = (t < SCAN_CHUNK) ? deg[lo + t] : 0;
    sd[t] = v;
    __syncthreads();
    for (int off = 1; off < 256; off <<= 1) {
        int u = (t >= off) ? sd[t - off] : 0;
        __syncthreads();
        sd[t] += u;
        __syncthreads();
    }
    if (t < SCAN_CHUNK) row_ptr[lo + t] = bsum[b] + sd[t] - v;
    if (b == 0 && t == 0) row_ptr[N_NODES] = E_EDGES;
}

__global__ void k_scatter(const int* __restrict__ ei, const int* __restrict__ row_ptr,
                          int* __restrict__ pos, int* __restrict__ csr_src) {
    int e = blockIdx.x * blockDim.x + threadIdx.x;
    if (e >= E_EDGES) return;
    int src = ei[e], dst = ei[E_EDGES + e];
    int p = atomicAdd(&pos[dst], 1);
    csr_src[row_ptr[dst] + p] = src;
}

// ---------------- fold attention vectors through W1 ----------------
__global__ void k_fold(const float* __restrict__ W1, const float* __restrict__ a_src,
                       const float* __restrict__ a_dst, float* __restrict__ wes,
                       float* __restrict__ wed) {
    int t = threadIdx.x;
    if (t >= 168) return;
    int which = t / 84;
    int idx = t % 84;
    int k = idx >> 2, h = idx & 3;
    const float* a = which ? a_dst : a_src;
    float s = 0.f;
    for (int c = 0; c < 128; ++c)
        s += W1[k * 512 + h * 128 + c] * a[h * 128 + c];
    (which ? wed : wes)[idx] = s;
}

// ---------------- layer-1 coefficients: es/ed = x @ w_es / w_ed ----------------
__global__ void k_l1_coef(const float* __restrict__ x, const float* __restrict__ wes,
                          const float* __restrict__ wed, float* __restrict__ es,
                          float* __restrict__ ed) {
    int node = blockIdx.x * blockDim.x + threadIdx.x;
    if (node >= N_NODES) return;
    const float* xr = x + (size_t)node * 21;
    float e1[4] = {0.f, 0.f, 0.f, 0.f}, e2[4] = {0.f, 0.f, 0.f, 0.f};
    #pragma unroll
    for (int k = 0; k < 21; ++k) {
        float xv = xr[k];
        float4 a = *(const float4*)&wes[k * 4];
        float4 b = *(const float4*)&wed[k * 4];
        e1[0] += xv * a.x; e1[1] += xv * a.y; e1[2] += xv * a.z; e1[3] += xv * a.w;
        e2[0] += xv * b.x; e2[1] += xv * b.y; e2[2] += xv * b.z; e2[3] += xv * b.w;
    }
    *(float4*)&es[node * 4] = make_float4(e1[0], e1[1], e1[2], e1[3]);
    *(float4*)&ed[node * 4] = make_float4(e2[0], e2[1], e2[2], e2[3]);
}

// ---------------- layer-1 edge phase on RAW x ----------------
__global__ void k_edge_l1x(const int* __restrict__ row_ptr, const int* __restrict__ csr_src,
                           const float* __restrict__ x, const float* __restrict__ es,
                           const float* __restrict__ ed, float* __restrict__ y) {
    int wid = (blockIdx.x * blockDim.x + threadIdx.x) >> 6;
    int l = threadIdx.x & 63;
    if (wid >= N_NODES) return;
    const int dst = wid;
    const int hh = l >> 4, sub = l & 15;
    const int beg = row_ptr[dst], end = row_ptr[dst + 1];
    const float eddg = ed[dst * 4 + hh];
    const float self_v = lrelu(es[dst * 4 + hh] + eddg);

    // pass 1: per-head max
    float m = self_v;
    for (int k = beg + sub; k < end; k += 16)
        m = fmaxf(m, lrelu(es[csr_src[k] * 4 + hh] + eddg));
    #pragma unroll
    for (int off = 1; off < 16; off <<= 1) m = fmaxf(m, __shfl_xor(m, off, 64));

    // pass 2: per-head sum of exp
    float s = 0.f;
    for (int k = beg + sub; k < end; k += 16)
        s += __expf(lrelu(es[csr_src[k] * 4 + hh] + eddg) - m);
    #pragma unroll
    for (int off = 1; off < 16; off <<= 1) s += __shfl_xor(s, off, 64);
    float p_self = __expf(self_v - m);
    s += p_self;
    float inv_s = 1.f / s;

    // broadcast per-head stats to all lanes
    float mh[4], ih[4], eh[4], ph[4];
    #pragma unroll
    for (int h = 0; h < 4; ++h) {
        mh[h] = __shfl(m, h * 16, 64);
        ih[h] = __shfl(inv_s, h * 16, 64);
        eh[h] = __shfl(eddg, h * 16, 64);
        ph[h] = __shfl(p_self, h * 16, 64);
    }

    // aggregation: lane l<63: group g=l/21 walks edges beg+g, beg+g+3, ...
    const int g = l / 21;            // lane 63 -> g=3 (inactive)
    const int c = l - g * 21;
    const bool act = (l < 63);

    // self term only once (group 0); groups are summed in the final reduce
    float xdv = (act && g == 0) ? x[(size_t)dst * 21 + c] : 0.f;
    float acc[4];
    #pragma unroll
    for (int h = 0; h < 4; ++h) acc[h] = ph[h] * ih[h] * xdv;

    if (act) {
        int k = beg + g;
        for (; k + 3 < end; k += 6) {
            int s0 = csr_src[k], s1 = csr_src[k + 3];
            float4 e0 = *(const float4*)&es[s0 * 4];
            float4 e1 = *(const float4*)&es[s1 * 4];
            float x0 = x[(size_t)s0 * 21 + c];
            float x1 = x[(size_t)s1 * 21 + c];
            #pragma unroll
            for (int h = 0; h < 4; ++h) {
                float a0 = __expf(lrelu((&e0.x)[h] + eh[h]) - mh[h]) * ih[h];
                float a1 = __expf(lrelu((&e1.x)[h] + eh[h]) - mh[h]) * ih[h];
                acc[h] += a0 * x0 + a1 * x1;
            }
        }
        if (k < end) {
            int s0 = csr_src[k];
            float4 e0 = *(const float4*)&es[s0 * 4];
            float x0 = x[(size_t)s0 * 21 + c];
            #pragma unroll
            for (int h = 0; h < 4; ++h) {
                float a0 = __expf(lrelu((&e0.x)[h] + eh[h]) - mh[h]) * ih[h];
                acc[h] += a0 * x0;
            }
        }
    }

    // 3-way reduce across edge-groups, then lanes 0..20 write all 4 heads
    #pragma unroll
    for (int h = 0; h < 4; ++h) {
        float a1 = __shfl(acc[h], (l + 21) & 63, 64);
        float a2 = __shfl(acc[h], (l + 42) & 63, 64);
        acc[h] += a1 + a2;
    }
    if (l < 21) {
        #pragma unroll
        for (int h = 0; h < 4; ++h)
            y[(size_t)dst * 84 + h * 21 + l] = acc[h];
    }
}

// ---------------- layer-1 post v3: LDS-staged batch, out1 = ELU(y@W1+b1) -> fp16 ----------------
// grid = 3125 blocks x 16 nodes each (exactly 50000). Thread owns col pair c2=2t.
// W1 slice in registers; y rows staged once in LDS; 2 nodes in flight (4 FMA chains).
__global__ void k_post3(const float* __restrict__ y, const float* __restrict__ W1,
                        const float* __restrict__ b1, __half* __restrict__ out1) {
    __shared__ float Ys[16][84];
    const int t = threadIdx.x;
    const int c2 = 2 * t;
    const int whead = c2 >> 7;          // head index (0..3)
    const int base = blockIdx.x * 16;

    float2 wreg[21];
    #pragma unroll
    for (int j = 0; j < 21; ++j)
        wreg[j] = *(const float2*)&W1[j * 512 + c2];
    const float2 bb = *(const float2*)&b1[c2];

    // stage 16 y-rows (1344 floats) coalesced
    for (int f = t; f < 16 * 84; f += 256) {
        int n = f / 84, c = f % 84;
        Ys[n][c] = y[(size_t)(base + n) * 84 + c];
    }
    __syncthreads();

    #pragma unroll 2
    for (int n = 0; n < 16; n += 2) {
        float o0 = bb.x, o1 = bb.y, p0 = bb.x, p1 = bb.y;
        #pragma unroll
        for (int j = 0; j < 21; ++j) {
            float ya = Ys[n][whead * 21 + j];
            float yb = Ys[n + 1][whead * 21 + j];
            o0 += ya * wreg[j].x;
            o1 += ya * wreg[j].y;
            p0 += yb * wreg[j].x;
            p1 += yb * wreg[j].y;
        }
        o0 = o0 > 0.f ? o0 : expm1f(o0);
        o1 = o1 > 0.f ? o1 : expm1f(o1);
        p0 = p0 > 0.f ? p0 : expm1f(p0);
        p1 = p1 > 0.f ? p1 : expm1f(p1);
        __half2 ha, hb;
        ha.x = __float2half_rn(o0); ha.y = __float2half_rn(o1);
        hb.x = __float2half_rn(p0); hb.y = __float2half_rn(p1);
        *(__half2*)&out1[(size_t)(base + n) * 512 + c2] = ha;
        *(__half2*)&out1[(size_t)(base + n + 1) * 512 + c2] = hb;
    }
}

// ---------------- Layer 2: tiled GEMM (fp16 A @ f32 W2) + es/ed; h2 stored fp16 ----------------
__global__ void k_l2_gemm_coef(const __half* __restrict__ A16, const float* __restrict__ B,
                               const float* __restrict__ a_src, const float* __restrict__ a_dst,
                               __half* __restrict__ C16, float* __restrict__ es, float* __restrict__ ed) {
    __shared__ float AT[64][65];
    __shared__ float Bs[64][64];

    const int t = threadIdx.x;
    const int tr = t >> 4, tc = t & 15;
    const int row0 = blockIdx.x * 64;

    float acc[4][4];
    #pragma unroll
    for (int r = 0; r < 4; ++r)
        #pragma unroll
        for (int cc = 0; cc < 4; ++cc) acc[r][cc] = 0.f;

    for (int k0 = 0; k0 < 512; k0 += 64) {
        #pragma unroll
        for (int i = 0; i < 2; ++i) {
            int f = i * 256 + t;
            int row = f >> 3, c8 = f & 7;
            int grow = row0 + row;
            union { uint4 u4; __half h[8]; } v;
            v.u4 = make_uint4(0, 0, 0, 0);
            if (grow < N_NODES)
                v.u4 = *(const uint4*)&A16[(size_t)grow * 512 + k0 + c8 * 8];
            #pragma unroll
            for (int j = 0; j < 8; ++j)
                AT[c8 * 8 + j][row] = __half2float(v.h[j]);
        }
        #pragma unroll
        for (int i = 0; i < 4; ++i) {
            int f = i * 256 + t;
            int row = f >> 4, c4 = f & 15;
            *(float4*)&Bs[row][c4 * 4] = *(const float4*)&B[(size_t)(k0 + row) * 64 + c4 * 4];
        }
        __syncthreads();
        #pragma unroll 8
        for (int kk = 0; kk < 64; ++kk) {
            float4 a4 = *(const float4*)&AT[kk][tr * 4];
            float4 b4 = *(const float4*)&Bs[kk][tc * 4];
            const float av[4] = {a4.x, a4.y, a4.z, a4.w};
            const float bv[4] = {b4.x, b4.y, b4.z, b4.w};
            #pragma unroll
            for (int r = 0; r < 4; ++r)
                #pragma unroll
                for (int cc = 0; cc < 4; ++cc)
                    acc[r][cc] += av[r] * bv[cc];
        }
        __syncthreads();
    }

    float4 as4 = *(const float4*)&a_src[tc * 4];
    float4 ad4 = *(const float4*)&a_dst[tc * 4];
    #pragma unroll
    for (int r = 0; r < 4; ++r) {
        int grow = row0 + tr * 4 + r;
        float4 cv = {acc[r][0], acc[r][1], acc[r][2], acc[r][3]};
        float p1 = cv.x * as4.x + cv.y * as4.y + cv.z * as4.z + cv.w * as4.w;
        float p2 = cv.x * ad4.x + cv.y * ad4.y + cv.z * ad4.z + cv.w * ad4.w;
        #pragma unroll
        for (int off = 8; off; off >>= 1) {
            p1 += __shfl_xor(p1, off, 64);
            p2 += __shfl_xor(p2, off, 64);
        }
        if (grow < N_NODES) {
            union { uint2 u2; __half h[4]; } o;
            o.h[0] = __float2half_rn(cv.x);
            o.h[1] = __float2half_rn(cv.y);
            o.h[2] = __float2half_rn(cv.z);
            o.h[3] = __float2half_rn(cv.w);
            *(uint2*)&C16[(size_t)grow * 64 + tc * 4] = o.u2;
            if (tc == 0) { es[grow] = p1; ed[grow] = p2; }
        }
    }
}

// ---------------- Layer 3: wave-per-node dot + es/ed ----------------
__global__ void k_l3_gemm_coef(const float* __restrict__ A, const float* __restrict__ W3,
                               const float* __restrict__ a_src, const float* __restrict__ a_dst,
                               float* __restrict__ h3, float* __restrict__ es, float* __restrict__ ed) {
    int gid = blockIdx.x * blockDim.x + threadIdx.x;
    int node = gid >> 6, lane = gid & 63;
    if (node >= N_NODES) return;
    float v = A[(size_t)node * 64 + lane] * W3[lane];
    v = wave_red_sum64(v);
    if (lane == 0) {
        h3[node] = v;
        es[node] = v * a_src[0];
        ed[node] = v * a_dst[0];
    }
}

// ---------------- Layer 2 edge phase: wave per dst, 4 edge-groups, fp16 gather ----------------
__global__ void k_gat_edge_l2(const int* __restrict__ row_ptr, const int* __restrict__ csr_src,
                              const __half* __restrict__ h16, const float* __restrict__ es,
                              const float* __restrict__ ed, const float* __restrict__ b,
                              float* __restrict__ out) {
    int wid = (blockIdx.x * blockDim.x + threadIdx.x) >> 6;
    int lane = threadIdx.x & 63;
    if (wid >= N_NODES) return;
    const int dst = wid;
    const int g = lane >> 4, sub = lane & 15;
    const int beg = row_ptr[dst], end = row_ptr[dst + 1];
    const float edd = ed[dst];
    const float self_v = lrelu(es[dst] + edd);

    float m = self_v;
    for (int k = beg + lane; k < end; k += 64)
        m = fmaxf(m, lrelu(es[csr_src[k]] + edd));
    #pragma unroll
    for (int off = 32; off; off >>= 1) m = fmaxf(m, __shfl_xor(m, off, 64));

    float s = 0.f;
    for (int k = beg + lane; k < end; k += 64)
        s += __expf(lrelu(es[csr_src[k]] + edd) - m);
    #pragma unroll
    for (int off = 32; off; off >>= 1) s += __shfl_xor(s, off, 64);
    float p_self = __expf(self_v - m);
    s += p_self;
    const float inv_s = 1.f / s;

    float acc[4] = {0.f, 0.f, 0.f, 0.f};
    if (g == 0) {
        uint2 r = *(const uint2*)(h16 + (size_t)dst * 64 + sub * 4);
        float hv[4]; h4_to_f4(r, hv);
        float a_self = p_self * inv_s;
        #pragma unroll
        for (int j = 0; j < 4; ++j) acc[j] = a_self * hv[j];
    }
    for (int k0 = beg; k0 < end; k0 += 4) {
        int k = k0 + g;
        if (k < end) {
            int src = csr_src[k];
            float alpha = __expf(lrelu(es[src] + edd) - m) * inv_s;
            uint2 r = *(const uint2*)(h16 + (size_t)src * 64 + sub * 4);
            float hv[4]; h4_to_f4(r, hv);
            #pragma unroll
            for (int j = 0; j < 4; ++j) acc[j] += alpha * hv[j];
        }
    }
    #pragma unroll
    for (int off = 16; off < 64; off <<= 1) {
        #pragma unroll
        for (int j = 0; j < 4; ++j) acc[j] += __shfl_xor(acc[j], off, 64);
    }
    if (g == 0) {
        float4 bv = *(const float4*)&b[sub * 4];
        float o[4] = {acc[0] + bv.x, acc[1] + bv.y, acc[2] + bv.z, acc[3] + bv.w};
        #pragma unroll
        for (int j = 0; j < 4; ++j) o[j] = o[j] > 0.f ? o[j] : expm1f(o[j]);
        *(float4*)&out[(size_t)dst * 64 + sub * 4] = make_float4(o[0], o[1], o[2], o[3]);
    }
}

// ---------------- layer 3 edge phase (H=1, C=1) ----------------
__global__ void k_gat_edge_c1(const int* __restrict__ row_ptr, const int* __restrict__ csr_src,
                              const float* __restrict__ h, const float* __restrict__ es,
                              const float* __restrict__ ed, float* __restrict__ out) {
    int dst = blockIdx.x * blockDim.x + threadIdx.x;
    if (dst >= N_NODES) return;
    int beg = row_ptr[dst], end = row_ptr[dst + 1];
    float edd = ed[dst];
    float self_v = lrelu(es[dst] + edd);
    float m = self_v;
    for (int k = beg; k < end; ++k) m = fmaxf(m, lrelu(es[csr_src[k]] + edd));
    float p = __expf(self_v - m);
    float s = p;
    float acc = p * h[dst];
    for (int k = beg; k < end; ++k) {
        int src = csr_src[k];
        float pv = __expf(lrelu(es[src] + edd) - m);
        s += pv;
        acc += pv * h[src];
    }
    out[dst] = acc / s;
}

// ---------------- final mean + b3 ----------------
__global__ void k_mean(const float* __restrict__ v, const float* __restrict__ b3,
                       float* __restrict__ out, int n) {
    __shared__ float sdata[256];
    float local = 0.f;
    for (int i = blockIdx.x * blockDim.x + threadIdx.x; i < n; i += gridDim.x * blockDim.x)
        local += v[i];
    sdata[threadIdx.x] = local;
    __syncthreads();
    for (int sft = 128; sft > 0; sft >>= 1) {
        if (threadIdx.x < sft) sdata[threadIdx.x] += sdata[threadIdx.x + sft];
        __syncthreads();
    }
    if (threadIdx.x == 0) {
        float add = sdata[0] / (float)n;
        if (blockIdx.x == 0) add += b3[0];
        atomicAdd(out, add);
    }
}

extern "C" void kernel_launch(void* const* d_in, const int* in_sizes, int n_in,
                              void* d_out, int out_size, void* d_ws, size_t ws_size,
                              hipStream_t stream) {
    const float* x      = (const float*)d_in[0];
    const float* W1     = (const float*)d_in[1];
    const float* a_src1 = (const float*)d_in[2];
    const float* a_dst1 = (const float*)d_in[3];
    const float* b1     = (const float*)d_in[4];
    const float* W2     = (const float*)d_in[5];
    const float* a_src2 = (const float*)d_in[6];
    const float* a_dst2 = (const float*)d_in[7];
    const float* b2     = (const float*)d_in[8];
    const float* W3     = (const float*)d_in[9];
    const float* a_src3 = (const float*)d_in[10];
    const float* a_dst3 = (const float*)d_in[11];
    const float* b3     = (const float*)d_in[12];
    const int*   ei     = (const int*)d_in[13];
    float* out = (float*)d_out;

    const int BS = 256;
    const size_t N = N_NODES;

    // workspace layout (float units)
    float*  ws      = (float*)d_ws;
    __half* out1h   = (__half*)ws;                 // N*512 halves = N*256 floats
    float*  y_buf   = ws + N * 256;                // N*84
    __half* h2_16   = (__half*)(y_buf + N * 84);   // N*64 halves = N*32 floats
    float*  out2    = y_buf + N * 84 + N * 32;     // N*64
    float*  h3raw   = out2 + N * 64;               // N
    float*  out3    = h3raw + N;                   // N
    float*  es_buf  = out3 + N;                    // N*4 (16B aligned)
    float*  ed_buf  = es_buf + N * 4;              // N*4
    float*  wes     = ed_buf + N * 4;              // 88 (padded)
    float*  wed     = wes + 88;                    // 88
    int*    deg     = (int*)(wed + 88);            // N
    int*    row_ptr = deg + N;                     // N+1
    int*    csr_src = row_ptr + N + 1;             // E_EDGES
    int*    bsum    = csr_src + E_EDGES;           // 256

    // CSR build (shared by all 3 layers)
    hipMemsetAsync(deg, 0, N * sizeof(int), stream);
    k_count<<<cdiv(E_EDGES, BS), BS, 0, stream>>>(ei, deg);
    k_scan1<<<SCAN_BLOCKS, 256, 0, stream>>>(deg, bsum);
    k_scan2<<<1, 256, 0, stream>>>(bsum);
    k_scan3<<<SCAN_BLOCKS, 256, 0, stream>>>(deg, bsum, row_ptr);
    hipMemsetAsync(deg, 0, N * sizeof(int), stream);
    k_scatter<<<cdiv(E_EDGES, BS), BS, 0, stream>>>(ei, row_ptr, deg, csr_src);

    // Layer 1: H=4, C=128 — aggregate raw x, then per-node GEMM (y -> out1 fp16)
    k_fold<<<1, 256, 0, stream>>>(W1, a_src1, a_dst1, wes, wed);
    k_l1_coef<<<cdiv((long)N, BS), BS, 0, stream>>>(x, wes, wed, es_buf, ed_buf);
    k_edge_l1x<<<cdiv((long)N * 64, BS), BS, 0, stream>>>(row_ptr, csr_src, x, es_buf, ed_buf, y_buf);
    k_post3<<<N_NODES / 16, 256, 0, stream>>>(y_buf, W1, b1, out1h);

    // Layer 2: H=1, C=64
    k_l2_gemm_coef<<<cdiv(N_NODES, 64), 256, 0, stream>>>(out1h, W2, a_src2, a_dst2, h2_16, es_buf, ed_buf);
    k_gat_edge_l2<<<cdiv((long)N * 64, BS), BS, 0, stream>>>(row_ptr, csr_src, h2_16, es_buf, ed_buf, b2, out2);

    // Layer 3: H=1, C=1
    k_l3_gemm_coef<<<cdiv((long)N * 64, BS), BS, 0, stream>>>(out2, W3, a_src3, a_dst3, h3raw, es_buf, ed_buf);
    k_gat_edge_c1<<<cdiv((long)N, BS), BS, 0, stream>>>(row_ptr, csr_src, h3raw, es_buf, ed_buf, out3);

    hipMemsetAsync(out, 0, sizeof(float), stream);
    k_mean<<<256, 256, 0, stream>>>(out3, b3, out, N_NODES);
}

// Round 12
// 235.419 us; speedup vs baseline: 1.8227x; 1.1285x over previous
//
#include <hip/hip_runtime.h>
#include <hip/hip_fp16.h>
#include <math.h>

#define N_NODES 50000
#define E_EDGES 400000
#define NEG_SLOPE 0.2f
#define SCAN_BLOCKS 250
#define SCAN_CHUNK 200

typedef _Float16 f16x8 __attribute__((ext_vector_type(8)));
typedef float f32x4 __attribute__((ext_vector_type(4)));

static inline int cdiv(long a, int b) { return (int)((a + b - 1) / b); }

__device__ __forceinline__ float lrelu(float v) {
    return v > 0.f ? v : NEG_SLOPE * v;
}

__device__ __forceinline__ float wave_red_sum64(float v) {
    #pragma unroll
    for (int off = 32; off; off >>= 1) v += __shfl_xor(v, off, 64);
    return v;
}

__device__ __forceinline__ void h4_to_f4(uint2 u, float o[4]) {
    union { uint2 u2; __half h[4]; } cv;
    cv.u2 = u;
    #pragma unroll
    for (int i = 0; i < 4; ++i) o[i] = __half2float(cv.h[i]);
}

// ---------------- CSR build ----------------
__global__ void k_count(const int* __restrict__ ei, int* __restrict__ deg) {
    int e = blockIdx.x * blockDim.x + threadIdx.x;
    if (e >= E_EDGES) return;
    atomicAdd(&deg[ei[E_EDGES + e]], 1);
}

__global__ void k_scan1(const int* __restrict__ deg, int* __restrict__ bsum) {
    __shared__ int sd[256];
    int b = blockIdx.x, t = threadIdx.x;
    int lo = b * SCAN_CHUNK;
    int s = 0;
    for (int i = t; i < SCAN_CHUNK; i += 256) s += deg[lo + i];
    sd[t] = s;
    __syncthreads();
    for (int off = 128; off; off >>= 1) {
        if (t < off) sd[t] += sd[t + off];
        __syncthreads();
    }
    if (t == 0) bsum[b] = sd[0];
}

__global__ void k_scan2(int* __restrict__ bsum) {
    __shared__ int sd[256];
    int t = threadIdx.x;
    int v = (t < SCAN_BLOCKS) ? bsum[t] : 0;
    sd[t] = v;
    __syncthreads();
    for (int off = 1; off < 256; off <<= 1) {
        int u = (t >= off) ? sd[t - off] : 0;
        __syncthreads();
        sd[t] += u;
        __syncthreads();
    }
    if (t < SCAN_BLOCKS) bsum[t] = sd[t] - v;   // exclusive
}

__global__ void k_scan3(const int* __restrict__ deg, const int* __restrict__ bsum,
                        int* __restrict__ row_ptr) {
    __shared__ int sd[256];
    int b = blockIdx.x, t = threadIdx.x;
    int lo = b * SCAN_CHUNK;
    int v = (t < SCAN_CHUNK) ? deg[lo + t] : 0;
    sd[t] = v;
    __syncthreads();
    for (int off = 1; off < 256; off <<= 1) {
        int u = (t >= off) ? sd[t - off] : 0;
        __syncthreads();
        sd[t] += u;
        __syncthreads();
    }
    if (t < SCAN_CHUNK) row_ptr[lo + t] = bsum[b] + sd[t] - v;
    if (b == 0 && t == 0) row_ptr[N_NODES] = E_EDGES;
}

__global__ void k_scatter(const int* __restrict__ ei, const int* __restrict__ row_ptr,
                          int* __restrict__ pos, int* __restrict__ csr_src) {
    int e = blockIdx.x * blockDim.x + threadIdx.x;
    if (e >= E_EDGES) return;
    int src = ei[e], dst = ei[E_EDGES + e];
    int p = atomicAdd(&pos[dst], 1);
    csr_src[row_ptr[dst] + p] = src;
}

// ---------------- fold attention vectors through W1 ----------------
__global__ void k_fold(const float* __restrict__ W1, const float* __restrict__ a_src,
                       const float* __restrict__ a_dst, float* __restrict__ wes,
                       float* __restrict__ wed) {
    int t = threadIdx.x;
    if (t >= 168) return;
    int which = t / 84;
    int idx = t % 84;
    int k = idx >> 2, h = idx & 3;
    const float* a = which ? a_dst : a_src;
    float s = 0.f;
    for (int c = 0; c < 128; ++c)
        s += W1[k * 512 + h * 128 + c] * a[h * 128 + c];
    (which ? wed : wes)[idx] = s;
}

// ---------------- layer-1 coefficients ----------------
__global__ void k_l1_coef(const float* __restrict__ x, const float* __restrict__ wes,
                          const float* __restrict__ wed, float* __restrict__ es,
                          float* __restrict__ ed) {
    int node = blockIdx.x * blockDim.x + threadIdx.x;
    if (node >= N_NODES) return;
    const float* xr = x + (size_t)node * 21;
    float e1[4] = {0.f, 0.f, 0.f, 0.f}, e2[4] = {0.f, 0.f, 0.f, 0.f};
    #pragma unroll
    for (int k = 0; k < 21; ++k) {
        float xv = xr[k];
        float4 a = *(const float4*)&wes[k * 4];
        float4 b = *(const float4*)&wed[k * 4];
        e1[0] += xv * a.x; e1[1] += xv * a.y; e1[2] += xv * a.z; e1[3] += xv * a.w;
        e2[0] += xv * b.x; e2[1] += xv * b.y; e2[2] += xv * b.z; e2[3] += xv * b.w;
    }
    *(float4*)&es[node * 4] = make_float4(e1[0], e1[1], e1[2], e1[3]);
    *(float4*)&ed[node * 4] = make_float4(e2[0], e2[1], e2[2], e2[3]);
}

// ---------------- layer-1 edge phase on RAW x ----------------
__global__ void k_edge_l1x(const int* __restrict__ row_ptr, const int* __restrict__ csr_src,
                           const float* __restrict__ x, const float* __restrict__ es,
                           const float* __restrict__ ed, float* __restrict__ y) {
    int wid = (blockIdx.x * blockDim.x + threadIdx.x) >> 6;
    int l = threadIdx.x & 63;
    if (wid >= N_NODES) return;
    const int dst = wid;
    const int hh = l >> 4, sub = l & 15;
    const int beg = row_ptr[dst], end = row_ptr[dst + 1];
    const float eddg = ed[dst * 4 + hh];
    const float self_v = lrelu(es[dst * 4 + hh] + eddg);

    float m = self_v;
    for (int k = beg + sub; k < end; k += 16)
        m = fmaxf(m, lrelu(es[csr_src[k] * 4 + hh] + eddg));
    #pragma unroll
    for (int off = 1; off < 16; off <<= 1) m = fmaxf(m, __shfl_xor(m, off, 64));

    float s = 0.f;
    for (int k = beg + sub; k < end; k += 16)
        s += __expf(lrelu(es[csr_src[k] * 4 + hh] + eddg) - m);
    #pragma unroll
    for (int off = 1; off < 16; off <<= 1) s += __shfl_xor(s, off, 64);
    float p_self = __expf(self_v - m);
    s += p_self;
    float inv_s = 1.f / s;

    float mh[4], ih[4], eh[4], ph[4];
    #pragma unroll
    for (int h = 0; h < 4; ++h) {
        mh[h] = __shfl(m, h * 16, 64);
        ih[h] = __shfl(inv_s, h * 16, 64);
        eh[h] = __shfl(eddg, h * 16, 64);
        ph[h] = __shfl(p_self, h * 16, 64);
    }

    const int g = l / 21;
    const int c = l - g * 21;
    const bool act = (l < 63);

    float xdv = (act && g == 0) ? x[(size_t)dst * 21 + c] : 0.f;
    float acc[4];
    #pragma unroll
    for (int h = 0; h < 4; ++h) acc[h] = ph[h] * ih[h] * xdv;

    if (act) {
        int k = beg + g;
        for (; k + 3 < end; k += 6) {
            int s0 = csr_src[k], s1 = csr_src[k + 3];
            float4 e0 = *(const float4*)&es[s0 * 4];
            float4 e1 = *(const float4*)&es[s1 * 4];
            float x0 = x[(size_t)s0 * 21 + c];
            float x1 = x[(size_t)s1 * 21 + c];
            #pragma unroll
            for (int h = 0; h < 4; ++h) {
                float a0 = __expf(lrelu((&e0.x)[h] + eh[h]) - mh[h]) * ih[h];
                float a1 = __expf(lrelu((&e1.x)[h] + eh[h]) - mh[h]) * ih[h];
                acc[h] += a0 * x0 + a1 * x1;
            }
        }
        if (k < end) {
            int s0 = csr_src[k];
            float4 e0 = *(const float4*)&es[s0 * 4];
            float x0 = x[(size_t)s0 * 21 + c];
            #pragma unroll
            for (int h = 0; h < 4; ++h) {
                float a0 = __expf(lrelu((&e0.x)[h] + eh[h]) - mh[h]) * ih[h];
                acc[h] += a0 * x0;
            }
        }
    }

    #pragma unroll
    for (int h = 0; h < 4; ++h) {
        float a1 = __shfl(acc[h], (l + 21) & 63, 64);
        float a2 = __shfl(acc[h], (l + 42) & 63, 64);
        acc[h] += a1 + a2;
    }
    if (l < 21) {
        #pragma unroll
        for (int h = 0; h < 4; ++h)
            y[(size_t)dst * 84 + h * 21 + l] = acc[h];
    }
}

// ---------------- layer-1 post v3: LDS-staged batch ----------------
__global__ void k_post3(const float* __restrict__ y, const float* __restrict__ W1,
                        const float* __restrict__ b1, __half* __restrict__ out1) {
    __shared__ float Ys[16][84];
    const int t = threadIdx.x;
    const int c2 = 2 * t;
    const int whead = c2 >> 7;
    const int base = blockIdx.x * 16;

    float2 wreg[21];
    #pragma unroll
    for (int j = 0; j < 21; ++j)
        wreg[j] = *(const float2*)&W1[j * 512 + c2];
    const float2 bb = *(const float2*)&b1[c2];

    for (int f = t; f < 16 * 84; f += 256) {
        int n = f / 84, c = f % 84;
        Ys[n][c] = y[(size_t)(base + n) * 84 + c];
    }
    __syncthreads();

    #pragma unroll 2
    for (int n = 0; n < 16; n += 2) {
        float o0 = bb.x, o1 = bb.y, p0 = bb.x, p1 = bb.y;
        #pragma unroll
        for (int j = 0; j < 21; ++j) {
            float ya = Ys[n][whead * 21 + j];
            float yb = Ys[n + 1][whead * 21 + j];
            o0 += ya * wreg[j].x;
            o1 += ya * wreg[j].y;
            p0 += yb * wreg[j].x;
            p1 += yb * wreg[j].y;
        }
        o0 = o0 > 0.f ? o0 : expm1f(o0);
        o1 = o1 > 0.f ? o1 : expm1f(o1);
        p0 = p0 > 0.f ? p0 : expm1f(p0);
        p1 = p1 > 0.f ? p1 : expm1f(p1);
        __half2 ha, hb;
        ha.x = __float2half_rn(o0); ha.y = __float2half_rn(o1);
        hb.x = __float2half_rn(p0); hb.y = __float2half_rn(p1);
        *(__half2*)&out1[(size_t)(base + n) * 512 + c2] = ha;
        *(__half2*)&out1[(size_t)(base + n + 1) * 512 + c2] = hb;
    }
}

// ---------------- W2 transpose to fp16: W2t[n][k] = W2[k][n] ----------------
__global__ void k_w2t(const float* __restrict__ W2, __half* __restrict__ W2t) {
    int idx = blockIdx.x * blockDim.x + threadIdx.x;
    if (idx >= 512 * 64) return;
    int k = idx >> 6, n = idx & 63;
    W2t[(size_t)n * 512 + k] = __float2half_rn(W2[idx]);
}

// ---------------- Layer 2 GEMM via MFMA + es/ed ----------------
// block = 256 (4 waves); wave = 32 rows (2 mtiles) x 64 cols (4 ntiles); no LDS.
// A frag: A[l&15][(l>>4)*8+j]; B frag: B[(l>>4)*8+j][l&15]; C: col=l&15,row=(l>>4)*4+reg.
__global__ void k_l2_mfma(const __half* __restrict__ A16, const __half* __restrict__ W2t,
                          const float* __restrict__ a_src, const float* __restrict__ a_dst,
                          __half* __restrict__ C16, float* __restrict__ es, float* __restrict__ ed) {
    const int t = threadIdx.x;
    const int l = t & 63;
    const int wv = t >> 6;
    const int row0 = blockIdx.x * 128 + wv * 32;
    const int lr = l & 15;
    const int kg = l >> 4;

    f32x4 acc[2][4];
    #pragma unroll
    for (int m = 0; m < 2; ++m)
        #pragma unroll
        for (int n = 0; n < 4; ++n) acc[m][n] = (f32x4){0.f, 0.f, 0.f, 0.f};

    int ra0 = row0 + lr;       ra0 = ra0 < N_NODES ? ra0 : N_NODES - 1;
    int ra1 = row0 + 16 + lr;  ra1 = ra1 < N_NODES ? ra1 : N_NODES - 1;
    const _Float16* A = (const _Float16*)A16;
    const _Float16* B = (const _Float16*)W2t;

    for (int k0 = 0; k0 < 512; k0 += 32) {
        const int kb = k0 + kg * 8;
        f16x8 a0 = *(const f16x8*)(A + (size_t)ra0 * 512 + kb);
        f16x8 a1 = *(const f16x8*)(A + (size_t)ra1 * 512 + kb);
        #pragma unroll
        for (int nt = 0; nt < 4; ++nt) {
            f16x8 bf = *(const f16x8*)(B + (size_t)(nt * 16 + lr) * 512 + kb);
            acc[0][nt] = __builtin_amdgcn_mfma_f32_16x16x32_f16(a0, bf, acc[0][nt], 0, 0, 0);
            acc[1][nt] = __builtin_amdgcn_mfma_f32_16x16x32_f16(a1, bf, acc[1][nt], 0, 0, 0);
        }
    }

    float asv[4], adv[4];
    #pragma unroll
    for (int nt = 0; nt < 4; ++nt) {
        asv[nt] = a_src[nt * 16 + lr];
        adv[nt] = a_dst[nt * 16 + lr];
    }

    #pragma unroll
    for (int m = 0; m < 2; ++m) {
        #pragma unroll
        for (int r = 0; r < 4; ++r) {
            int row = row0 + m * 16 + kg * 4 + r;
            float cv[4];
            float p1 = 0.f, p2 = 0.f;
            #pragma unroll
            for (int nt = 0; nt < 4; ++nt) {
                cv[nt] = acc[m][nt][r];
                p1 += cv[nt] * asv[nt];
                p2 += cv[nt] * adv[nt];
            }
            #pragma unroll
            for (int off = 1; off < 16; off <<= 1) {
                p1 += __shfl_xor(p1, off, 64);
                p2 += __shfl_xor(p2, off, 64);
            }
            if (row < N_NODES) {
                #pragma unroll
                for (int nt = 0; nt < 4; ++nt)
                    C16[(size_t)row * 64 + nt * 16 + lr] = __float2half_rn(cv[nt]);
                if (lr == 0) { es[row] = p1; ed[row] = p2; }
            }
        }
    }
}

// ---------------- Layer 3: wave-per-node dot + es/ed ----------------
__global__ void k_l3_gemm_coef(const float* __restrict__ A, const float* __restrict__ W3,
                               const float* __restrict__ a_src, const float* __restrict__ a_dst,
                               float* __restrict__ h3, float* __restrict__ es, float* __restrict__ ed) {
    int gid = blockIdx.x * blockDim.x + threadIdx.x;
    int node = gid >> 6, lane = gid & 63;
    if (node >= N_NODES) return;
    float v = A[(size_t)node * 64 + lane] * W3[lane];
    v = wave_red_sum64(v);
    if (lane == 0) {
        h3[node] = v;
        es[node] = v * a_src[0];
        ed[node] = v * a_dst[0];
    }
}

// ---------------- Layer 2 edge phase ----------------
__global__ void k_gat_edge_l2(const int* __restrict__ row_ptr, const int* __restrict__ csr_src,
                              const __half* __restrict__ h16, const float* __restrict__ es,
                              const float* __restrict__ ed, const float* __restrict__ b,
                              float* __restrict__ out) {
    int wid = (blockIdx.x * blockDim.x + threadIdx.x) >> 6;
    int lane = threadIdx.x & 63;
    if (wid >= N_NODES) return;
    const int dst = wid;
    const int g = lane >> 4, sub = lane & 15;
    const int beg = row_ptr[dst], end = row_ptr[dst + 1];
    const float edd = ed[dst];
    const float self_v = lrelu(es[dst] + edd);

    float m = self_v;
    for (int k = beg + lane; k < end; k += 64)
        m = fmaxf(m, lrelu(es[csr_src[k]] + edd));
    #pragma unroll
    for (int off = 32; off; off >>= 1) m = fmaxf(m, __shfl_xor(m, off, 64));

    float s = 0.f;
    for (int k = beg + lane; k < end; k += 64)
        s += __expf(lrelu(es[csr_src[k]] + edd) - m);
    #pragma unroll
    for (int off = 32; off; off >>= 1) s += __shfl_xor(s, off, 64);
    float p_self = __expf(self_v - m);
    s += p_self;
    const float inv_s = 1.f / s;

    float acc[4] = {0.f, 0.f, 0.f, 0.f};
    if (g == 0) {
        uint2 r = *(const uint2*)(h16 + (size_t)dst * 64 + sub * 4);
        float hv[4]; h4_to_f4(r, hv);
        float a_self = p_self * inv_s;
        #pragma unroll
        for (int j = 0; j < 4; ++j) acc[j] = a_self * hv[j];
    }
    for (int k0 = beg; k0 < end; k0 += 4) {
        int k = k0 + g;
        if (k < end) {
            int src = csr_src[k];
            float alpha = __expf(lrelu(es[src] + edd) - m) * inv_s;
            uint2 r = *(const uint2*)(h16 + (size_t)src * 64 + sub * 4);
            float hv[4]; h4_to_f4(r, hv);
            #pragma unroll
            for (int j = 0; j < 4; ++j) acc[j] += alpha * hv[j];
        }
    }
    #pragma unroll
    for (int off = 16; off < 64; off <<= 1) {
        #pragma unroll
        for (int j = 0; j < 4; ++j) acc[j] += __shfl_xor(acc[j], off, 64);
    }
    if (g == 0) {
        float4 bv = *(const float4*)&b[sub * 4];
        float o[4] = {acc[0] + bv.x, acc[1] + bv.y, acc[2] + bv.z, acc[3] + bv.w};
        #pragma unroll
        for (int j = 0; j < 4; ++j) o[j] = o[j] > 0.f ? o[j] : expm1f(o[j]);
        *(float4*)&out[(size_t)dst * 64 + sub * 4] = make_float4(o[0], o[1], o[2], o[3]);
    }
}

// ---------------- layer 3 edge phase (H=1, C=1) ----------------
__global__ void k_gat_edge_c1(const int* __restrict__ row_ptr, const int* __restrict__ csr_src,
                              const float* __restrict__ h, const float* __restrict__ es,
                              const float* __restrict__ ed, float* __restrict__ out) {
    int dst = blockIdx.x * blockDim.x + threadIdx.x;
    if (dst >= N_NODES) return;
    int beg = row_ptr[dst], end = row_ptr[dst + 1];
    float edd = ed[dst];
    float self_v = lrelu(es[dst] + edd);
    float m = self_v;
    for (int k = beg; k < end; ++k) m = fmaxf(m, lrelu(es[csr_src[k]] + edd));
    float p = __expf(self_v - m);
    float s = p;
    float acc = p * h[dst];
    for (int k = beg; k < end; ++k) {
        int src = csr_src[k];
        float pv = __expf(lrelu(es[src] + edd) - m);
        s += pv;
        acc += pv * h[src];
    }
    out[dst] = acc / s;
}

// ---------------- final mean + b3 ----------------
__global__ void k_mean(const float* __restrict__ v, const float* __restrict__ b3,
                       float* __restrict__ out, int n) {
    __shared__ float sdata[256];
    float local = 0.f;
    for (int i = blockIdx.x * blockDim.x + threadIdx.x; i < n; i += gridDim.x * blockDim.x)
        local += v[i];
    sdata[threadIdx.x] = local;
    __syncthreads();
    for (int sft = 128; sft > 0; sft >>= 1) {
        if (threadIdx.x < sft) sdata[threadIdx.x] += sdata[threadIdx.x + sft];
        __syncthreads();
    }
    if (threadIdx.x == 0) {
        float add = sdata[0] / (float)n;
        if (blockIdx.x == 0) add += b3[0];
        atomicAdd(out, add);
    }
}

extern "C" void kernel_launch(void* const* d_in, const int* in_sizes, int n_in,
                              void* d_out, int out_size, void* d_ws, size_t ws_size,
                              hipStream_t stream) {
    const float* x      = (const float*)d_in[0];
    const float* W1     = (const float*)d_in[1];
    const float* a_src1 = (const float*)d_in[2];
    const float* a_dst1 = (const float*)d_in[3];
    const float* b1     = (const float*)d_in[4];
    const float* W2     = (const float*)d_in[5];
    const float* a_src2 = (const float*)d_in[6];
    const float* a_dst2 = (const float*)d_in[7];
    const float* b2     = (const float*)d_in[8];
    const float* W3     = (const float*)d_in[9];
    const float* a_src3 = (const float*)d_in[10];
    const float* a_dst3 = (const float*)d_in[11];
    const float* b3     = (const float*)d_in[12];
    const int*   ei     = (const int*)d_in[13];
    float* out = (float*)d_out;

    const int BS = 256;
    const size_t N = N_NODES;

    // workspace layout (float units)
    float*  ws      = (float*)d_ws;
    __half* out1h   = (__half*)ws;                 // N*512 halves = N*256 floats
    float*  y_buf   = ws + N * 256;                // N*84
    __half* h2_16   = (__half*)(y_buf + N * 84);   // N*64 halves = N*32 floats
    float*  out2    = y_buf + N * 84 + N * 32;     // N*64
    float*  h3raw   = out2 + N * 64;               // N
    float*  out3    = h3raw + N;                   // N
    float*  es_buf  = out3 + N;                    // N*4
    float*  ed_buf  = es_buf + N * 4;              // N*4
    float*  wes     = ed_buf + N * 4;              // 88
    float*  wed     = wes + 88;                    // 88
    __half* W2t     = (__half*)(wed + 88);         // 32768 halves = 16384 floats (16B-aligned)
    int*    deg     = (int*)(wed + 88 + 16384);    // N
    int*    row_ptr = deg + N;                     // N+1
    int*    csr_src = row_ptr + N + 1;             // E_EDGES
    int*    bsum    = csr_src + E_EDGES;           // 256

    // CSR build (shared by all 3 layers)
    hipMemsetAsync(deg, 0, N * sizeof(int), stream);
    k_count<<<cdiv(E_EDGES, BS), BS, 0, stream>>>(ei, deg);
    k_scan1<<<SCAN_BLOCKS, 256, 0, stream>>>(deg, bsum);
    k_scan2<<<1, 256, 0, stream>>>(bsum);
    k_scan3<<<SCAN_BLOCKS, 256, 0, stream>>>(deg, bsum, row_ptr);
    hipMemsetAsync(deg, 0, N * sizeof(int), stream);
    k_scatter<<<cdiv(E_EDGES, BS), BS, 0, stream>>>(ei, row_ptr, deg, csr_src);

    // Layer 1: H=4, C=128 — aggregate raw x, then per-node GEMM (y -> out1 fp16)
    k_fold<<<1, 256, 0, stream>>>(W1, a_src1, a_dst1, wes, wed);
    k_l1_coef<<<cdiv((long)N, BS), BS, 0, stream>>>(x, wes, wed, es_buf, ed_buf);
    k_edge_l1x<<<cdiv((long)N * 64, BS), BS, 0, stream>>>(row_ptr, csr_src, x, es_buf, ed_buf, y_buf);
    k_post3<<<N_NODES / 16, 256, 0, stream>>>(y_buf, W1, b1, out1h);

    // Layer 2: H=1, C=64 — MFMA GEMM
    k_w2t<<<cdiv(512 * 64, BS), BS, 0, stream>>>(W2, W2t);
    k_l2_mfma<<<cdiv(N_NODES, 128), 256, 0, stream>>>(out1h, W2t, a_src2, a_dst2, h2_16, es_buf, ed_buf);
    k_gat_edge_l2<<<cdiv((long)N * 64, BS), BS, 0, stream>>>(row_ptr, csr_src, h2_16, es_buf, ed_buf, b2, out2);

    // Layer 3: H=1, C=1
    k_l3_gemm_coef<<<cdiv((long)N * 64, BS), BS, 0, stream>>>(out2, W3, a_src3, a_dst3, h3raw, es_buf, ed_buf);
    k_gat_edge_c1<<<cdiv((long)N, BS), BS, 0, stream>>>(row_ptr, csr_src, h3raw, es_buf, ed_buf, out3);

    hipMemsetAsync(out, 0, sizeof(float), stream);
    k_mean<<<256, 256, 0, stream>>>(out3, b3, out, N_NODES);
}

// Round 14
// 213.817 us; speedup vs baseline: 2.0068x; 1.1010x over previous
//
#include <hip/hip_runtime.h>
#include <hip/hip_fp16.h>
#include <math.h>

#define N_NODES 50000
#define E_EDGES 400000
#define NEG_SLOPE 0.2f
#define SCAN_BLOCKS 250
#define SCAN_CHUNK 200

typedef _Float16 f16x8 __attribute__((ext_vector_type(8)));
typedef float f32x4 __attribute__((ext_vector_type(4)));

static inline int cdiv(long a, int b) { return (int)((a + b - 1) / b); }

__device__ __forceinline__ float lrelu(float v) {
    return v > 0.f ? v : NEG_SLOPE * v;
}

__device__ __forceinline__ float wave_red_sum64(float v) {
    #pragma unroll
    for (int off = 32; off; off >>= 1) v += __shfl_xor(v, off, 64);
    return v;
}

__device__ __forceinline__ void h4_to_f4(uint2 u, float o[4]) {
    union { uint2 u2; __half h[4]; } cv;
    cv.u2 = u;
    #pragma unroll
    for (int i = 0; i < 4; ++i) o[i] = __half2float(cv.h[i]);
}

// ---------------- CSR build ----------------
__global__ void k_count(const int* __restrict__ ei, int* __restrict__ deg) {
    int e = blockIdx.x * blockDim.x + threadIdx.x;
    if (e >= E_EDGES) return;
    atomicAdd(&deg[ei[E_EDGES + e]], 1);
}

__global__ void k_scan1(const int* __restrict__ deg, int* __restrict__ bsum) {
    __shared__ int sd[256];
    int b = blockIdx.x, t = threadIdx.x;
    int lo = b * SCAN_CHUNK;
    int s = 0;
    for (int i = t; i < SCAN_CHUNK; i += 256) s += deg[lo + i];
    sd[t] = s;
    __syncthreads();
    for (int off = 128; off; off >>= 1) {
        if (t < off) sd[t] += sd[t + off];
        __syncthreads();
    }
    if (t == 0) bsum[b] = sd[0];
}

__global__ void k_scan2(int* __restrict__ bsum) {
    __shared__ int sd[256];
    int t = threadIdx.x;
    int v = (t < SCAN_BLOCKS) ? bsum[t] : 0;
    sd[t] = v;
    __syncthreads();
    for (int off = 1; off < 256; off <<= 1) {
        int u = (t >= off) ? sd[t - off] : 0;
        __syncthreads();
        sd[t] += u;
        __syncthreads();
    }
    if (t < SCAN_BLOCKS) bsum[t] = sd[t] - v;   // exclusive
}

__global__ void k_scan3(const int* __restrict__ deg, const int* __restrict__ bsum,
                        int* __restrict__ row_ptr) {
    __shared__ int sd[256];
    int b = blockIdx.x, t = threadIdx.x;
    int lo = b * SCAN_CHUNK;
    int v = (t < SCAN_CHUNK) ? deg[lo + t] : 0;
    sd[t] = v;
    __syncthreads();
    for (int off = 1; off < 256; off <<= 1) {
        int u = (t >= off) ? sd[t - off] : 0;
        __syncthreads();
        sd[t] += u;
        __syncthreads();
    }
    if (t < SCAN_CHUNK) row_ptr[lo + t] = bsum[b] + sd[t] - v;
    if (b == 0 && t == 0) row_ptr[N_NODES] = E_EDGES;
}

__global__ void k_scatter(const int* __restrict__ ei, const int* __restrict__ row_ptr,
                          int* __restrict__ pos, int* __restrict__ csr_src) {
    int e = blockIdx.x * blockDim.x + threadIdx.x;
    if (e >= E_EDGES) return;
    int src = ei[e], dst = ei[E_EDGES + e];
    int p = atomicAdd(&pos[dst], 1);
    csr_src[row_ptr[dst] + p] = src;
}

// ---------------- fold attention vectors through W1 ----------------
__global__ void k_fold(const float* __restrict__ W1, const float* __restrict__ a_src,
                       const float* __restrict__ a_dst, float* __restrict__ wes,
                       float* __restrict__ wed) {
    int t = threadIdx.x;
    if (t >= 168) return;
    int which = t / 84;
    int idx = t % 84;
    int k = idx >> 2, h = idx & 3;
    const float* a = which ? a_dst : a_src;
    float s = 0.f;
    for (int c = 0; c < 128; ++c)
        s += W1[k * 512 + h * 128 + c] * a[h * 128 + c];
    (which ? wed : wes)[idx] = s;
}

// ---------------- layer-1 coefficients ----------------
__global__ void k_l1_coef(const float* __restrict__ x, const float* __restrict__ wes,
                          const float* __restrict__ wed, float* __restrict__ es,
                          float* __restrict__ ed) {
    int node = blockIdx.x * blockDim.x + threadIdx.x;
    if (node >= N_NODES) return;
    const float* xr = x + (size_t)node * 21;
    float e1[4] = {0.f, 0.f, 0.f, 0.f}, e2[4] = {0.f, 0.f, 0.f, 0.f};
    #pragma unroll
    for (int k = 0; k < 21; ++k) {
        float xv = xr[k];
        float4 a = *(const float4*)&wes[k * 4];
        float4 b = *(const float4*)&wed[k * 4];
        e1[0] += xv * a.x; e1[1] += xv * a.y; e1[2] += xv * a.z; e1[3] += xv * a.w;
        e2[0] += xv * b.x; e2[1] += xv * b.y; e2[2] += xv * b.z; e2[3] += xv * b.w;
    }
    *(float4*)&es[node * 4] = make_float4(e1[0], e1[1], e1[2], e1[3]);
    *(float4*)&ed[node * 4] = make_float4(e2[0], e2[1], e2[2], e2[3]);
}

// ---------------- layer-1 edge phase on RAW x -> y16 (fp16, K-padded) ----------------
// y16 layout: [node][head*32 + k], k in 0..31 (21..31 zero)
__global__ void k_edge_l1x(const int* __restrict__ row_ptr, const int* __restrict__ csr_src,
                           const float* __restrict__ x, const float* __restrict__ es,
                           const float* __restrict__ ed, __half* __restrict__ y16) {
    int wid = (blockIdx.x * blockDim.x + threadIdx.x) >> 6;
    int l = threadIdx.x & 63;
    if (wid >= N_NODES) return;
    const int dst = wid;
    const int hh = l >> 4, sub = l & 15;
    const int beg = row_ptr[dst], end = row_ptr[dst + 1];
    const float eddg = ed[dst * 4 + hh];
    const float self_v = lrelu(es[dst * 4 + hh] + eddg);

    // pass 1: per-head max
    float m = self_v;
    for (int k = beg + sub; k < end; k += 16)
        m = fmaxf(m, lrelu(es[csr_src[k] * 4 + hh] + eddg));
    #pragma unroll
    for (int off = 1; off < 16; off <<= 1) m = fmaxf(m, __shfl_xor(m, off, 64));

    // pass 2: per-head sum of exp
    float s = 0.f;
    for (int k = beg + sub; k < end; k += 16)
        s += __expf(lrelu(es[csr_src[k] * 4 + hh] + eddg) - m);
    #pragma unroll
    for (int off = 1; off < 16; off <<= 1) s += __shfl_xor(s, off, 64);
    float p_self = __expf(self_v - m);
    s += p_self;
    float inv_s = 1.f / s;

    // broadcast per-head stats to all lanes
    float mh[4], ih[4], eh[4], ph[4];
    #pragma unroll
    for (int h = 0; h < 4; ++h) {
        mh[h] = __shfl(m, h * 16, 64);
        ih[h] = __shfl(inv_s, h * 16, 64);
        eh[h] = __shfl(eddg, h * 16, 64);
        ph[h] = __shfl(p_self, h * 16, 64);
    }

    // aggregation: lane l<63: group g=l/21 walks edges beg+g, beg+g+3, ...
    const int g = l / 21;
    const int c = l - g * 21;
    const bool act = (l < 63);

    float xdv = (act && g == 0) ? x[(size_t)dst * 21 + c] : 0.f;
    float acc[4];
    #pragma unroll
    for (int h = 0; h < 4; ++h) acc[h] = ph[h] * ih[h] * xdv;

    if (act) {
        int k = beg + g;
        for (; k + 3 < end; k += 6) {
            int s0 = csr_src[k], s1 = csr_src[k + 3];
            float4 e0 = *(const float4*)&es[s0 * 4];
            float4 e1 = *(const float4*)&es[s1 * 4];
            float x0 = x[(size_t)s0 * 21 + c];
            float x1 = x[(size_t)s1 * 21 + c];
            #pragma unroll
            for (int h = 0; h < 4; ++h) {
                float a0 = __expf(lrelu((&e0.x)[h] + eh[h]) - mh[h]) * ih[h];
                float a1 = __expf(lrelu((&e1.x)[h] + eh[h]) - mh[h]) * ih[h];
                acc[h] += a0 * x0 + a1 * x1;
            }
        }
        if (k < end) {
            int s0 = csr_src[k];
            float4 e0 = *(const float4*)&es[s0 * 4];
            float x0 = x[(size_t)s0 * 21 + c];
            #pragma unroll
            for (int h = 0; h < 4; ++h) {
                float a0 = __expf(lrelu((&e0.x)[h] + eh[h]) - mh[h]) * ih[h];
                acc[h] += a0 * x0;
            }
        }
    }

    // 3-way reduce across edge-groups; lanes 0..20 hold the result, 21..31 write pad
    #pragma unroll
    for (int h = 0; h < 4; ++h) {
        float a1 = __shfl(acc[h], (l + 21) & 63, 64);
        float a2 = __shfl(acc[h], (l + 42) & 63, 64);
        acc[h] += a1 + a2;
    }
    if (l < 32) {
        #pragma unroll
        for (int h = 0; h < 4; ++h) {
            float v = (l < 21) ? acc[h] : 0.f;
            y16[(size_t)dst * 128 + h * 32 + l] = __float2half_rn(v);
        }
    }
}

// ---------------- W1 transpose to fp16, K-padded: W1t[n][k] = W1[k][n] ----------------
__global__ void k_w1t(const float* __restrict__ W1, __half* __restrict__ W1t) {
    int idx = blockIdx.x * blockDim.x + threadIdx.x;
    if (idx >= 512 * 32) return;
    int n = idx >> 5, k = idx & 31;
    W1t[idx] = (k < 21) ? __float2half_rn(W1[k * 512 + n]) : __half(0.f);
}

// ---------------- layer-1 post via MFMA: out1 = ELU(y16 @ W1 + b1) -> fp16 ----------------
// block = 4 waves x 32 rows; wave wv owns head wv: rows [row0,row0+32) x cols [wv*128, wv*128+128).
// 2 M-tiles x 8 N-tiles per wave; K=32 single step.
__global__ void k_post_mfma(const __half* __restrict__ y16, const __half* __restrict__ W1t,
                            const float* __restrict__ b1, __half* __restrict__ out1) {
    const int t = threadIdx.x;
    const int l = t & 63;
    const int head = t >> 6;              // wave index == head
    const int row0 = blockIdx.x * 32;
    const int lr = l & 15;
    const int kg = l >> 4;

    const _Float16* Y = (const _Float16*)y16;
    const _Float16* B = (const _Float16*)W1t;

    int ra0 = row0 + lr;       ra0 = ra0 < N_NODES ? ra0 : N_NODES - 1;
    int ra1 = row0 + 16 + lr;  ra1 = ra1 < N_NODES ? ra1 : N_NODES - 1;

    f32x4 acc[2][8];
    #pragma unroll
    for (int m = 0; m < 2; ++m)
        #pragma unroll
        for (int n = 0; n < 8; ++n) acc[m][n] = (f32x4){0.f, 0.f, 0.f, 0.f};

    // A-frags for this head (K=32, one step)
    f16x8 a0 = *(const f16x8*)(Y + (size_t)ra0 * 128 + head * 32 + kg * 8);
    f16x8 a1 = *(const f16x8*)(Y + (size_t)ra1 * 128 + head * 32 + kg * 8);

    #pragma unroll
    for (int nt = 0; nt < 8; ++nt) {
        // B column n_global = head*128 + nt*16 + lr; W1t row-major [n][32]
        f16x8 bf = *(const f16x8*)(B + (size_t)(head * 128 + nt * 16 + lr) * 32 + kg * 8);
        acc[0][nt] = __builtin_amdgcn_mfma_f32_16x16x32_f16(a0, bf, acc[0][nt], 0, 0, 0);
        acc[1][nt] = __builtin_amdgcn_mfma_f32_16x16x32_f16(a1, bf, acc[1][nt], 0, 0, 0);
    }

    float bb[8];
    #pragma unroll
    for (int nt = 0; nt < 8; ++nt) bb[nt] = b1[head * 128 + nt * 16 + lr];

    #pragma unroll
    for (int m = 0; m < 2; ++m) {
        #pragma unroll
        for (int r = 0; r < 4; ++r) {
            int row = row0 + m * 16 + kg * 4 + r;
            if (row < N_NODES) {
                #pragma unroll
                for (int nt = 0; nt < 8; ++nt) {
                    float v = acc[m][nt][r] + bb[nt];
                    v = v > 0.f ? v : __expf(v) - 1.f;
                    out1[(size_t)row * 512 + head * 128 + nt * 16 + lr] = __float2half_rn(v);
                }
            }
        }
    }
}

// ---------------- W2 transpose to fp16: W2t[n][k] = W2[k][n] ----------------
__global__ void k_w2t(const float* __restrict__ W2, __half* __restrict__ W2t) {
    int idx = blockIdx.x * blockDim.x + threadIdx.x;
    if (idx >= 512 * 64) return;
    int k = idx >> 6, n = idx & 63;
    W2t[(size_t)n * 512 + k] = __float2half_rn(W2[idx]);
}

// ---------------- Layer 2 GEMM via MFMA + es/ed ----------------
__global__ void k_l2_mfma(const __half* __restrict__ A16, const __half* __restrict__ W2t,
                          const float* __restrict__ a_src, const float* __restrict__ a_dst,
                          __half* __restrict__ C16, float* __restrict__ es, float* __restrict__ ed) {
    const int t = threadIdx.x;
    const int l = t & 63;
    const int wv = t >> 6;
    const int row0 = blockIdx.x * 128 + wv * 32;
    const int lr = l & 15;
    const int kg = l >> 4;

    f32x4 acc[2][4];
    #pragma unroll
    for (int m = 0; m < 2; ++m)
        #pragma unroll
        for (int n = 0; n < 4; ++n) acc[m][n] = (f32x4){0.f, 0.f, 0.f, 0.f};

    int ra0 = row0 + lr;       ra0 = ra0 < N_NODES ? ra0 : N_NODES - 1;
    int ra1 = row0 + 16 + lr;  ra1 = ra1 < N_NODES ? ra1 : N_NODES - 1;
    const _Float16* A = (const _Float16*)A16;
    const _Float16* B = (const _Float16*)W2t;

    for (int k0 = 0; k0 < 512; k0 += 32) {
        const int kb = k0 + kg * 8;
        f16x8 a0 = *(const f16x8*)(A + (size_t)ra0 * 512 + kb);
        f16x8 a1 = *(const f16x8*)(A + (size_t)ra1 * 512 + kb);
        #pragma unroll
        for (int nt = 0; nt < 4; ++nt) {
            f16x8 bf = *(const f16x8*)(B + (size_t)(nt * 16 + lr) * 512 + kb);
            acc[0][nt] = __builtin_amdgcn_mfma_f32_16x16x32_f16(a0, bf, acc[0][nt], 0, 0, 0);
            acc[1][nt] = __builtin_amdgcn_mfma_f32_16x16x32_f16(a1, bf, acc[1][nt], 0, 0, 0);
        }
    }

    float asv[4], adv[4];
    #pragma unroll
    for (int nt = 0; nt < 4; ++nt) {
        asv[nt] = a_src[nt * 16 + lr];
        adv[nt] = a_dst[nt * 16 + lr];
    }

    #pragma unroll
    for (int m = 0; m < 2; ++m) {
        #pragma unroll
        for (int r = 0; r < 4; ++r) {
            int row = row0 + m * 16 + kg * 4 + r;
            float cv[4];
            float p1 = 0.f, p2 = 0.f;
            #pragma unroll
            for (int nt = 0; nt < 4; ++nt) {
                cv[nt] = acc[m][nt][r];
                p1 += cv[nt] * asv[nt];
                p2 += cv[nt] * adv[nt];
            }
            #pragma unroll
            for (int off = 1; off < 16; off <<= 1) {
                p1 += __shfl_xor(p1, off, 64);
                p2 += __shfl_xor(p2, off, 64);
            }
            if (row < N_NODES) {
                #pragma unroll
                for (int nt = 0; nt < 4; ++nt)
                    C16[(size_t)row * 64 + nt * 16 + lr] = __float2half_rn(cv[nt]);
                if (lr == 0) { es[row] = p1; ed[row] = p2; }
            }
        }
    }
}

// ---------------- Layer 3: wave-per-node dot + es/ed ----------------
__global__ void k_l3_gemm_coef(const float* __restrict__ A, const float* __restrict__ W3,
                               const float* __restrict__ a_src, const float* __restrict__ a_dst,
                               float* __restrict__ h3, float* __restrict__ es, float* __restrict__ ed) {
    int gid = blockIdx.x * blockDim.x + threadIdx.x;
    int node = gid >> 6, lane = gid & 63;
    if (node >= N_NODES) return;
    float v = A[(size_t)node * 64 + lane] * W3[lane];
    v = wave_red_sum64(v);
    if (lane == 0) {
        h3[node] = v;
        es[node] = v * a_src[0];
        ed[node] = v * a_dst[0];
    }
}

// ---------------- Layer 2 edge phase ----------------
__global__ void k_gat_edge_l2(const int* __restrict__ row_ptr, const int* __restrict__ csr_src,
                              const __half* __restrict__ h16, const float* __restrict__ es,
                              const float* __restrict__ ed, const float* __restrict__ b,
                              float* __restrict__ out) {
    int wid = (blockIdx.x * blockDim.x + threadIdx.x) >> 6;
    int lane = threadIdx.x & 63;
    if (wid >= N_NODES) return;
    const int dst = wid;
    const int g = lane >> 4, sub = lane & 15;
    const int beg = row_ptr[dst], end = row_ptr[dst + 1];
    const float edd = ed[dst];
    const float self_v = lrelu(es[dst] + edd);

    float m = self_v;
    for (int k = beg + lane; k < end; k += 64)
        m = fmaxf(m, lrelu(es[csr_src[k]] + edd));
    #pragma unroll
    for (int off = 32; off; off >>= 1) m = fmaxf(m, __shfl_xor(m, off, 64));

    float s = 0.f;
    for (int k = beg + lane; k < end; k += 64)
        s += __expf(lrelu(es[csr_src[k]] + edd) - m);
    #pragma unroll
    for (int off = 32; off; off >>= 1) s += __shfl_xor(s, off, 64);
    float p_self = __expf(self_v - m);
    s += p_self;
    const float inv_s = 1.f / s;

    float acc[4] = {0.f, 0.f, 0.f, 0.f};
    if (g == 0) {
        uint2 r = *(const uint2*)(h16 + (size_t)dst * 64 + sub * 4);
        float hv[4]; h4_to_f4(r, hv);
        float a_self = p_self * inv_s;
        #pragma unroll
        for (int j = 0; j < 4; ++j) acc[j] = a_self * hv[j];
    }
    for (int k0 = beg; k0 < end; k0 += 4) {
        int k = k0 + g;
        if (k < end) {
            int src = csr_src[k];
            float alpha = __expf(lrelu(es[src] + edd) - m) * inv_s;
            uint2 r = *(const uint2*)(h16 + (size_t)src * 64 + sub * 4);
            float hv[4]; h4_to_f4(r, hv);
            #pragma unroll
            for (int j = 0; j < 4; ++j) acc[j] += alpha * hv[j];
        }
    }
    #pragma unroll
    for (int off = 16; off < 64; off <<= 1) {
        #pragma unroll
        for (int j = 0; j < 4; ++j) acc[j] += __shfl_xor(acc[j], off, 64);
    }
    if (g == 0) {
        float4 bv = *(const float4*)&b[sub * 4];
        float o[4] = {acc[0] + bv.x, acc[1] + bv.y, acc[2] + bv.z, acc[3] + bv.w};
        #pragma unroll
        for (int j = 0; j < 4; ++j) o[j] = o[j] > 0.f ? o[j] : expm1f(o[j]);
        *(float4*)&out[(size_t)dst * 64 + sub * 4] = make_float4(o[0], o[1], o[2], o[3]);
    }
}

// ---------------- layer 3 edge phase (H=1, C=1) ----------------
__global__ void k_gat_edge_c1(const int* __restrict__ row_ptr, const int* __restrict__ csr_src,
                              const float* __restrict__ h, const float* __restrict__ es,
                              const float* __restrict__ ed, float* __restrict__ out) {
    int dst = blockIdx.x * blockDim.x + threadIdx.x;
    if (dst >= N_NODES) return;
    int beg = row_ptr[dst], end = row_ptr[dst + 1];
    float edd = ed[dst];
    float self_v = lrelu(es[dst] + edd);
    float m = self_v;
    for (int k = beg; k < end; ++k) m = fmaxf(m, lrelu(es[csr_src[k]] + edd));
    float p = __expf(self_v - m);
    float s = p;
    float acc = p * h[dst];
    for (int k = beg; k < end; ++k) {
        int src = csr_src[k];
        float pv = __expf(lrelu(es[src] + edd) - m);
        s += pv;
        acc += pv * h[src];
    }
    out[dst] = acc / s;
}

// ---------------- final mean + b3 ----------------
__global__ void k_mean(const float* __restrict__ v, const float* __restrict__ b3,
                       float* __restrict__ out, int n) {
    __shared__ float sdata[256];
    float local = 0.f;
    for (int i = blockIdx.x * blockDim.x + threadIdx.x; i < n; i += gridDim.x * blockDim.x)
        local += v[i];
    sdata[threadIdx.x] = local;
    __syncthreads();
    for (int sft = 128; sft > 0; sft >>= 1) {
        if (threadIdx.x < sft) sdata[threadIdx.x] += sdata[threadIdx.x + sft];
        __syncthreads();
    }
    if (threadIdx.x == 0) {
        float add = sdata[0] / (float)n;
        if (blockIdx.x == 0) add += b3[0];
        atomicAdd(out, add);
    }
}

extern "C" void kernel_launch(void* const* d_in, const int* in_sizes, int n_in,
                              void* d_out, int out_size, void* d_ws, size_t ws_size,
                              hipStream_t stream) {
    const float* x      = (const float*)d_in[0];
    const float* W1     = (const float*)d_in[1];
    const float* a_src1 = (const float*)d_in[2];
    const float* a_dst1 = (const float*)d_in[3];
    const float* b1     = (const float*)d_in[4];
    const float* W2     = (const float*)d_in[5];
    const float* a_src2 = (const float*)d_in[6];
    const float* a_dst2 = (const float*)d_in[7];
    const float* b2     = (const float*)d_in[8];
    const float* W3     = (const float*)d_in[9];
    const float* a_src3 = (const float*)d_in[10];
    const float* a_dst3 = (const float*)d_in[11];
    const float* b3     = (const float*)d_in[12];
    const int*   ei     = (const int*)d_in[13];
    float* out = (float*)d_out;

    const int BS = 256;
    const size_t N = N_NODES;

    // workspace layout (float units)
    float*  ws      = (float*)d_ws;
    __half* out1h   = (__half*)ws;                 // N*512 halves = N*256 floats
    __half* y16     = (__half*)(ws + N * 256);     // N*128 halves = N*64 floats
    __half* h2_16   = (__half*)(ws + N * 320);     // N*64 halves = N*32 floats
    float*  out2    = ws + N * 352;                // N*64
    float*  h3raw   = out2 + N * 64;               // N
    float*  out3    = h3raw + N;                   // N
    float*  es_buf  = out3 + N;                    // N*4
    float*  ed_buf  = es_buf + N * 4;              // N*4
    float*  wes     = ed_buf + N * 4;              // 88
    float*  wed     = wes + 88;                    // 88
    __half* W1t     = (__half*)(wed + 88);         // 512*32 halves = 8192 floats
    __half* W2t     = (__half*)(wed + 88 + 8192);  // 64*512 halves = 16384 floats
    int*    deg     = (int*)(wed + 88 + 8192 + 16384); // N
    int*    row_ptr = deg + N;                     // N+1
    int*    csr_src = row_ptr + N + 1;             // E_EDGES
    int*    bsum    = csr_src + E_EDGES;           // 256

    // CSR build (shared by all 3 layers)
    hipMemsetAsync(deg, 0, N * sizeof(int), stream);
    k_count<<<cdiv(E_EDGES, BS), BS, 0, stream>>>(ei, deg);
    k_scan1<<<SCAN_BLOCKS, 256, 0, stream>>>(deg, bsum);
    k_scan2<<<1, 256, 0, stream>>>(bsum);
    k_scan3<<<SCAN_BLOCKS, 256, 0, stream>>>(deg, bsum, row_ptr);
    hipMemsetAsync(deg, 0, N * sizeof(int), stream);
    k_scatter<<<cdiv(E_EDGES, BS), BS, 0, stream>>>(ei, row_ptr, deg, csr_src);

    // Layer 1: H=4, C=128 — aggregate raw x (y16 fp16), MFMA post GEMM
    k_fold<<<1, 256, 0, stream>>>(W1, a_src1, a_dst1, wes, wed);
    k_l1_coef<<<cdiv((long)N, BS), BS, 0, stream>>>(x, wes, wed, es_buf, ed_buf);
    k_edge_l1x<<<cdiv((long)N * 64, BS), BS, 0, stream>>>(row_ptr, csr_src, x, es_buf, ed_buf, y16);
    k_w1t<<<cdiv(512 * 32, BS), BS, 0, stream>>>(W1, W1t);
    k_post_mfma<<<cdiv(N_NODES, 32), 256, 0, stream>>>(y16, W1t, b1, out1h);

    // Layer 2: H=1, C=64 — MFMA GEMM
    k_w2t<<<cdiv(512 * 64, BS), BS, 0, stream>>>(W2, W2t);
    k_l2_mfma<<<cdiv(N_NODES, 128), 256, 0, stream>>>(out1h, W2t, a_src2, a_dst2, h2_16, es_buf, ed_buf);
    k_gat_edge_l2<<<cdiv((long)N * 64, BS), BS, 0, stream>>>(row_ptr, csr_src, h2_16, es_buf, ed_buf, b2, out2);

    // Layer 3: H=1, C=1
    k_l3_gemm_coef<<<cdiv((long)N * 64, BS), BS, 0, stream>>>(out2, W3, a_src3, a_dst3, h3raw, es_buf, ed_buf);
    k_gat_edge_c1<<<cdiv((long)N, BS), BS, 0, stream>>>(row_ptr, csr_src, h3raw, es_buf, ed_buf, out3);

    hipMemsetAsync(out, 0, sizeof(float), stream);
    k_mean<<<256, 256, 0, stream>>>(out3, b3, out, N_NODES);
}

// Round 15
// 192.500 us; speedup vs baseline: 2.2291x; 1.1107x over previous
//
#include <hip/hip_runtime.h>
#include <hip/hip_fp16.h>
#include <math.h>

#define N_NODES 50000
#define E_EDGES 400000
#define NEG_SLOPE 0.2f
#define SCAN_BLOCKS 250
#define SCAN_CHUNK 200

typedef _Float16 f16x8 __attribute__((ext_vector_type(8)));
typedef float f32x4 __attribute__((ext_vector_type(4)));

static inline int cdiv(long a, int b) { return (int)((a + b - 1) / b); }

__device__ __forceinline__ float lrelu(float v) {
    return v > 0.f ? v : NEG_SLOPE * v;
}

__device__ __forceinline__ float wave_red_sum64(float v) {
    #pragma unroll
    for (int off = 32; off; off >>= 1) v += __shfl_xor(v, off, 64);
    return v;
}

__device__ __forceinline__ void h4_to_f4(uint2 u, float o[4]) {
    union { uint2 u2; __half h[4]; } cv;
    cv.u2 = u;
    #pragma unroll
    for (int i = 0; i < 4; ++i) o[i] = __half2float(cv.h[i]);
}

// ---------------- CSR build ----------------
__global__ void k_count(const int* __restrict__ ei, int* __restrict__ deg) {
    int e = blockIdx.x * blockDim.x + threadIdx.x;
    if (e >= E_EDGES) return;
    atomicAdd(&deg[ei[E_EDGES + e]], 1);
}

__global__ void k_scan1(const int* __restrict__ deg, int* __restrict__ bsum) {
    __shared__ int sd[256];
    int b = blockIdx.x, t = threadIdx.x;
    int lo = b * SCAN_CHUNK;
    int s = 0;
    for (int i = t; i < SCAN_CHUNK; i += 256) s += deg[lo + i];
    sd[t] = s;
    __syncthreads();
    for (int off = 128; off; off >>= 1) {
        if (t < off) sd[t] += sd[t + off];
        __syncthreads();
    }
    if (t == 0) bsum[b] = sd[0];
}

__global__ void k_scan2(int* __restrict__ bsum) {
    __shared__ int sd[256];
    int t = threadIdx.x;
    int v = (t < SCAN_BLOCKS) ? bsum[t] : 0;
    sd[t] = v;
    __syncthreads();
    for (int off = 1; off < 256; off <<= 1) {
        int u = (t >= off) ? sd[t - off] : 0;
        __syncthreads();
        sd[t] += u;
        __syncthreads();
    }
    if (t < SCAN_BLOCKS) bsum[t] = sd[t] - v;   // exclusive
}

__global__ void k_scan3(const int* __restrict__ deg, const int* __restrict__ bsum,
                        int* __restrict__ row_ptr) {
    __shared__ int sd[256];
    int b = blockIdx.x, t = threadIdx.x;
    int lo = b * SCAN_CHUNK;
    int v = (t < SCAN_CHUNK) ? deg[lo + t] : 0;
    sd[t] = v;
    __syncthreads();
    for (int off = 1; off < 256; off <<= 1) {
        int u = (t >= off) ? sd[t - off] : 0;
        __syncthreads();
        sd[t] += u;
        __syncthreads();
    }
    if (t < SCAN_CHUNK) row_ptr[lo + t] = bsum[b] + sd[t] - v;
    if (b == 0 && t == 0) row_ptr[N_NODES] = E_EDGES;
}

__global__ void k_scatter(const int* __restrict__ ei, const int* __restrict__ row_ptr,
                          int* __restrict__ pos, int* __restrict__ csr_src) {
    int e = blockIdx.x * blockDim.x + threadIdx.x;
    if (e >= E_EDGES) return;
    int src = ei[e], dst = ei[E_EDGES + e];
    int p = atomicAdd(&pos[dst], 1);
    csr_src[row_ptr[dst] + p] = src;
}

// ---------------- fold attention vectors through W1 ----------------
__global__ void k_fold(const float* __restrict__ W1, const float* __restrict__ a_src,
                       const float* __restrict__ a_dst, float* __restrict__ wes,
                       float* __restrict__ wed) {
    int t = threadIdx.x;
    if (t >= 168) return;
    int which = t / 84;
    int idx = t % 84;
    int k = idx >> 2, h = idx & 3;
    const float* a = which ? a_dst : a_src;
    float s = 0.f;
    for (int c = 0; c < 128; ++c)
        s += W1[k * 512 + h * 128 + c] * a[h * 128 + c];
    (which ? wed : wes)[idx] = s;
}

// ---------------- layer-1 coefficients ----------------
__global__ void k_l1_coef(const float* __restrict__ x, const float* __restrict__ wes,
                          const float* __restrict__ wed, float* __restrict__ es,
                          float* __restrict__ ed) {
    int node = blockIdx.x * blockDim.x + threadIdx.x;
    if (node >= N_NODES) return;
    const float* xr = x + (size_t)node * 21;
    float e1[4] = {0.f, 0.f, 0.f, 0.f}, e2[4] = {0.f, 0.f, 0.f, 0.f};
    #pragma unroll
    for (int k = 0; k < 21; ++k) {
        float xv = xr[k];
        float4 a = *(const float4*)&wes[k * 4];
        float4 b = *(const float4*)&wed[k * 4];
        e1[0] += xv * a.x; e1[1] += xv * a.y; e1[2] += xv * a.z; e1[3] += xv * a.w;
        e2[0] += xv * b.x; e2[1] += xv * b.y; e2[2] += xv * b.z; e2[3] += xv * b.w;
    }
    *(float4*)&es[node * 4] = make_float4(e1[0], e1[1], e1[2], e1[3]);
    *(float4*)&ed[node * 4] = make_float4(e2[0], e2[1], e2[2], e2[3]);
}

// ---------------- layer-1 edge phase on RAW x -> y16 (fp16, K-padded) ----------------
// y16 layout: [node][head*32 + k], k in 0..31 (21..31 zero)
__global__ void k_edge_l1x(const int* __restrict__ row_ptr, const int* __restrict__ csr_src,
                           const float* __restrict__ x, const float* __restrict__ es,
                           const float* __restrict__ ed, __half* __restrict__ y16) {
    int wid = (blockIdx.x * blockDim.x + threadIdx.x) >> 6;
    int l = threadIdx.x & 63;
    if (wid >= N_NODES) return;
    const int dst = wid;
    const int hh = l >> 4, sub = l & 15;
    const int beg = row_ptr[dst], end = row_ptr[dst + 1];
    const float eddg = ed[dst * 4 + hh];
    const float self_v = lrelu(es[dst * 4 + hh] + eddg);

    // pass 1: per-head max
    float m = self_v;
    for (int k = beg + sub; k < end; k += 16)
        m = fmaxf(m, lrelu(es[csr_src[k] * 4 + hh] + eddg));
    #pragma unroll
    for (int off = 1; off < 16; off <<= 1) m = fmaxf(m, __shfl_xor(m, off, 64));

    // pass 2: per-head sum of exp
    float s = 0.f;
    for (int k = beg + sub; k < end; k += 16)
        s += __expf(lrelu(es[csr_src[k] * 4 + hh] + eddg) - m);
    #pragma unroll
    for (int off = 1; off < 16; off <<= 1) s += __shfl_xor(s, off, 64);
    float p_self = __expf(self_v - m);
    s += p_self;
    float inv_s = 1.f / s;

    // broadcast per-head stats to all lanes
    float mh[4], ih[4], eh[4], ph[4];
    #pragma unroll
    for (int h = 0; h < 4; ++h) {
        mh[h] = __shfl(m, h * 16, 64);
        ih[h] = __shfl(inv_s, h * 16, 64);
        eh[h] = __shfl(eddg, h * 16, 64);
        ph[h] = __shfl(p_self, h * 16, 64);
    }

    // aggregation: lane l<63: group g=l/21 walks edges beg+g, beg+g+3, ...
    const int g = l / 21;
    const int c = l - g * 21;
    const bool act = (l < 63);

    float xdv = (act && g == 0) ? x[(size_t)dst * 21 + c] : 0.f;
    float acc[4];
    #pragma unroll
    for (int h = 0; h < 4; ++h) acc[h] = ph[h] * ih[h] * xdv;

    if (act) {
        int k = beg + g;
        for (; k + 3 < end; k += 6) {
            int s0 = csr_src[k], s1 = csr_src[k + 3];
            float4 e0 = *(const float4*)&es[s0 * 4];
            float4 e1 = *(const float4*)&es[s1 * 4];
            float x0 = x[(size_t)s0 * 21 + c];
            float x1 = x[(size_t)s1 * 21 + c];
            #pragma unroll
            for (int h = 0; h < 4; ++h) {
                float a0 = __expf(lrelu((&e0.x)[h] + eh[h]) - mh[h]) * ih[h];
                float a1 = __expf(lrelu((&e1.x)[h] + eh[h]) - mh[h]) * ih[h];
                acc[h] += a0 * x0 + a1 * x1;
            }
        }
        if (k < end) {
            int s0 = csr_src[k];
            float4 e0 = *(const float4*)&es[s0 * 4];
            float x0 = x[(size_t)s0 * 21 + c];
            #pragma unroll
            for (int h = 0; h < 4; ++h) {
                float a0 = __expf(lrelu((&e0.x)[h] + eh[h]) - mh[h]) * ih[h];
                acc[h] += a0 * x0;
            }
        }
    }

    // 3-way reduce across edge-groups; lanes 0..20 hold the result, 21..31 write pad
    #pragma unroll
    for (int h = 0; h < 4; ++h) {
        float a1 = __shfl(acc[h], (l + 21) & 63, 64);
        float a2 = __shfl(acc[h], (l + 42) & 63, 64);
        acc[h] += a1 + a2;
    }
    if (l < 32) {
        #pragma unroll
        for (int h = 0; h < 4; ++h) {
            float v = (l < 21) ? acc[h] : 0.f;
            y16[(size_t)dst * 128 + h * 32 + l] = __float2half_rn(v);
        }
    }
}

// ---------------- weight transposes to fp16 (one launch) ----------------
// W1t[n][k] = W1[k][n], k padded to 32; W2t[n][k] = W2[k][n]
__global__ void k_wt(const float* __restrict__ W1, const float* __restrict__ W2,
                     __half* __restrict__ W1t, __half* __restrict__ W2t) {
    int idx = blockIdx.x * blockDim.x + threadIdx.x;
    if (idx < 512 * 32) {
        int n = idx >> 5, k = idx & 31;
        W1t[idx] = (k < 21) ? __float2half_rn(W1[k * 512 + n]) : __half(0.f);
    } else {
        int j = idx - 512 * 32;
        if (j < 512 * 64) {
            int k = j >> 6, n = j & 63;
            W2t[(size_t)n * 512 + k] = __float2half_rn(W2[j]);
        }
    }
}

// ---------------- fused layers 1-post + 2-GEMM via MFMA ----------------
// block = 4 waves, 32 rows. Phase 1: wave wv computes out1 tile rows x cols [wv*128,+128)
// (= round-14 k_post_mfma), stores ELU'd fp16 to LDS As[32][520]. Phase 2: wave wv computes
// h2 cols [wv*16,+16) over K=512 from LDS A-frags (= round-12 k_l2_mfma); es/ed via
// per-wave 16-lane reduce + cross-wave LDS sum.
__global__ void k_l12_fused(const __half* __restrict__ y16, const __half* __restrict__ W1t,
                            const float* __restrict__ b1, const __half* __restrict__ W2t,
                            const float* __restrict__ a_src, const float* __restrict__ a_dst,
                            __half* __restrict__ C16, float* __restrict__ es, float* __restrict__ ed) {
    __shared__ _Float16 As[32][520];   // 512 + 8 pad halves (16B-aligned rows)
    __shared__ float p1s[32][4];
    __shared__ float p2s[32][4];

    const int t = threadIdx.x;
    const int l = t & 63;
    const int wv = t >> 6;            // wave index: head (phase 1) / col-quarter (phase 2)
    const int row0 = blockIdx.x * 32;
    const int lr = l & 15;
    const int kg = l >> 4;

    const _Float16* Y = (const _Float16*)y16;
    const _Float16* B1 = (const _Float16*)W1t;

    int ra0 = row0 + lr;       ra0 = ra0 < N_NODES ? ra0 : N_NODES - 1;
    int ra1 = row0 + 16 + lr;  ra1 = ra1 < N_NODES ? ra1 : N_NODES - 1;

    // ---- phase 1: out1 tile in C-frags, head = wv ----
    f32x4 acc1[2][8];
    #pragma unroll
    for (int m = 0; m < 2; ++m)
        #pragma unroll
        for (int n = 0; n < 8; ++n) acc1[m][n] = (f32x4){0.f, 0.f, 0.f, 0.f};

    f16x8 a0 = *(const f16x8*)(Y + (size_t)ra0 * 128 + wv * 32 + kg * 8);
    f16x8 a1 = *(const f16x8*)(Y + (size_t)ra1 * 128 + wv * 32 + kg * 8);

    #pragma unroll
    for (int nt = 0; nt < 8; ++nt) {
        f16x8 bf = *(const f16x8*)(B1 + (size_t)(wv * 128 + nt * 16 + lr) * 32 + kg * 8);
        acc1[0][nt] = __builtin_amdgcn_mfma_f32_16x16x32_f16(a0, bf, acc1[0][nt], 0, 0, 0);
        acc1[1][nt] = __builtin_amdgcn_mfma_f32_16x16x32_f16(a1, bf, acc1[1][nt], 0, 0, 0);
    }

    float bb[8];
    #pragma unroll
    for (int nt = 0; nt < 8; ++nt) bb[nt] = b1[wv * 128 + nt * 16 + lr];

    #pragma unroll
    for (int m = 0; m < 2; ++m) {
        #pragma unroll
        for (int r = 0; r < 4; ++r) {
            int rl = m * 16 + kg * 4 + r;
            #pragma unroll
            for (int nt = 0; nt < 8; ++nt) {
                float v = acc1[m][nt][r] + bb[nt];
                v = v > 0.f ? v : __expf(v) - 1.f;
                As[rl][wv * 128 + nt * 16 + lr] = (_Float16)v;
            }
        }
    }
    __syncthreads();

    // ---- phase 2: h2 cols [wv*16, wv*16+16), K=512 from LDS ----
    const _Float16* B2 = (const _Float16*)W2t;
    const int n_g = wv * 16 + lr;
    f32x4 acc2[2];
    acc2[0] = (f32x4){0.f, 0.f, 0.f, 0.f};
    acc2[1] = (f32x4){0.f, 0.f, 0.f, 0.f};

    for (int kb = 0; kb < 512; kb += 32) {
        f16x8 fa0 = *(const f16x8*)&As[lr][kb + kg * 8];
        f16x8 fa1 = *(const f16x8*)&As[16 + lr][kb + kg * 8];
        f16x8 bf = *(const f16x8*)(B2 + (size_t)n_g * 512 + kb + kg * 8);
        acc2[0] = __builtin_amdgcn_mfma_f32_16x16x32_f16(fa0, bf, acc2[0], 0, 0, 0);
        acc2[1] = __builtin_amdgcn_mfma_f32_16x16x32_f16(fa1, bf, acc2[1], 0, 0, 0);
    }

    const float asv = a_src[n_g];
    const float adv = a_dst[n_g];

    #pragma unroll
    for (int m = 0; m < 2; ++m) {
        #pragma unroll
        for (int r = 0; r < 4; ++r) {
            int rl = m * 16 + kg * 4 + r;
            int grow = row0 + rl;
            float cv = acc2[m][r];
            float p1 = cv * asv, p2 = cv * adv;
            #pragma unroll
            for (int off = 1; off < 16; off <<= 1) {
                p1 += __shfl_xor(p1, off, 64);
                p2 += __shfl_xor(p2, off, 64);
            }
            if (grow < N_NODES)
                C16[(size_t)grow * 64 + n_g] = __float2half_rn(cv);
            if (lr == 0) { p1s[rl][wv] = p1; p2s[rl][wv] = p2; }
        }
    }
    __syncthreads();

    if (t < 32) {
        int grow = row0 + t;
        if (grow < N_NODES) {
            es[grow] = p1s[t][0] + p1s[t][1] + p1s[t][2] + p1s[t][3];
            ed[grow] = p2s[t][0] + p2s[t][1] + p2s[t][2] + p2s[t][3];
        }
    }
}

// ---------------- Layer 3: wave-per-node dot + es/ed ----------------
__global__ void k_l3_gemm_coef(const float* __restrict__ A, const float* __restrict__ W3,
                               const float* __restrict__ a_src, const float* __restrict__ a_dst,
                               float* __restrict__ h3, float* __restrict__ es, float* __restrict__ ed) {
    int gid = blockIdx.x * blockDim.x + threadIdx.x;
    int node = gid >> 6, lane = gid & 63;
    if (node >= N_NODES) return;
    float v = A[(size_t)node * 64 + lane] * W3[lane];
    v = wave_red_sum64(v);
    if (lane == 0) {
        h3[node] = v;
        es[node] = v * a_src[0];
        ed[node] = v * a_dst[0];
    }
}

// ---------------- Layer 2 edge phase ----------------
__global__ void k_gat_edge_l2(const int* __restrict__ row_ptr, const int* __restrict__ csr_src,
                              const __half* __restrict__ h16, const float* __restrict__ es,
                              const float* __restrict__ ed, const float* __restrict__ b,
                              float* __restrict__ out) {
    int wid = (blockIdx.x * blockDim.x + threadIdx.x) >> 6;
    int lane = threadIdx.x & 63;
    if (wid >= N_NODES) return;
    const int dst = wid;
    const int g = lane >> 4, sub = lane & 15;
    const int beg = row_ptr[dst], end = row_ptr[dst + 1];
    const float edd = ed[dst];
    const float self_v = lrelu(es[dst] + edd);

    float m = self_v;
    for (int k = beg + lane; k < end; k += 64)
        m = fmaxf(m, lrelu(es[csr_src[k]] + edd));
    #pragma unroll
    for (int off = 32; off; off >>= 1) m = fmaxf(m, __shfl_xor(m, off, 64));

    float s = 0.f;
    for (int k = beg + lane; k < end; k += 64)
        s += __expf(lrelu(es[csr_src[k]] + edd) - m);
    #pragma unroll
    for (int off = 32; off; off >>= 1) s += __shfl_xor(s, off, 64);
    float p_self = __expf(self_v - m);
    s += p_self;
    const float inv_s = 1.f / s;

    float acc[4] = {0.f, 0.f, 0.f, 0.f};
    if (g == 0) {
        uint2 r = *(const uint2*)(h16 + (size_t)dst * 64 + sub * 4);
        float hv[4]; h4_to_f4(r, hv);
        float a_self = p_self * inv_s;
        #pragma unroll
        for (int j = 0; j < 4; ++j) acc[j] = a_self * hv[j];
    }
    for (int k0 = beg; k0 < end; k0 += 4) {
        int k = k0 + g;
        if (k < end) {
            int src = csr_src[k];
            float alpha = __expf(lrelu(es[src] + edd) - m) * inv_s;
            uint2 r = *(const uint2*)(h16 + (size_t)src * 64 + sub * 4);
            float hv[4]; h4_to_f4(r, hv);
            #pragma unroll
            for (int j = 0; j < 4; ++j) acc[j] += alpha * hv[j];
        }
    }
    #pragma unroll
    for (int off = 16; off < 64; off <<= 1) {
        #pragma unroll
        for (int j = 0; j < 4; ++j) acc[j] += __shfl_xor(acc[j], off, 64);
    }
    if (g == 0) {
        float4 bv = *(const float4*)&b[sub * 4];
        float o[4] = {acc[0] + bv.x, acc[1] + bv.y, acc[2] + bv.z, acc[3] + bv.w};
        #pragma unroll
        for (int j = 0; j < 4; ++j) o[j] = o[j] > 0.f ? o[j] : expm1f(o[j]);
        *(float4*)&out[(size_t)dst * 64 + sub * 4] = make_float4(o[0], o[1], o[2], o[3]);
    }
}

// ---------------- layer 3 edge phase (H=1, C=1) ----------------
__global__ void k_gat_edge_c1(const int* __restrict__ row_ptr, const int* __restrict__ csr_src,
                              const float* __restrict__ h, const float* __restrict__ es,
                              const float* __restrict__ ed, float* __restrict__ out) {
    int dst = blockIdx.x * blockDim.x + threadIdx.x;
    if (dst >= N_NODES) return;
    int beg = row_ptr[dst], end = row_ptr[dst + 1];
    float edd = ed[dst];
    float self_v = lrelu(es[dst] + edd);
    float m = self_v;
    for (int k = beg; k < end; ++k) m = fmaxf(m, lrelu(es[csr_src[k]] + edd));
    float p = __expf(self_v - m);
    float s = p;
    float acc = p * h[dst];
    for (int k = beg; k < end; ++k) {
        int src = csr_src[k];
        float pv = __expf(lrelu(es[src] + edd) - m);
        s += pv;
        acc += pv * h[src];
    }
    out[dst] = acc / s;
}

// ---------------- final mean + b3 ----------------
__global__ void k_mean(const float* __restrict__ v, const float* __restrict__ b3,
                       float* __restrict__ out, int n) {
    __shared__ float sdata[256];
    float local = 0.f;
    for (int i = blockIdx.x * blockDim.x + threadIdx.x; i < n; i += gridDim.x * blockDim.x)
        local += v[i];
    sdata[threadIdx.x] = local;
    __syncthreads();
    for (int sft = 128; sft > 0; sft >>= 1) {
        if (threadIdx.x < sft) sdata[threadIdx.x] += sdata[threadIdx.x + sft];
        __syncthreads();
    }
    if (threadIdx.x == 0) {
        float add = sdata[0] / (float)n;
        if (blockIdx.x == 0) add += b3[0];
        atomicAdd(out, add);
    }
}

extern "C" void kernel_launch(void* const* d_in, const int* in_sizes, int n_in,
                              void* d_out, int out_size, void* d_ws, size_t ws_size,
                              hipStream_t stream) {
    const float* x      = (const float*)d_in[0];
    const float* W1     = (const float*)d_in[1];
    const float* a_src1 = (const float*)d_in[2];
    const float* a_dst1 = (const float*)d_in[3];
    const float* b1     = (const float*)d_in[4];
    const float* W2     = (const float*)d_in[5];
    const float* a_src2 = (const float*)d_in[6];
    const float* a_dst2 = (const float*)d_in[7];
    const float* b2     = (const float*)d_in[8];
    const float* W3     = (const float*)d_in[9];
    const float* a_src3 = (const float*)d_in[10];
    const float* a_dst3 = (const float*)d_in[11];
    const float* b3     = (const float*)d_in[12];
    const int*   ei     = (const int*)d_in[13];
    float* out = (float*)d_out;

    const int BS = 256;
    const size_t N = N_NODES;

    // workspace layout (float units)
    float*  ws      = (float*)d_ws;
    __half* y16     = (__half*)ws;                 // N*128 halves = N*64 floats
    __half* h2_16   = (__half*)(ws + N * 64);      // N*64 halves = N*32 floats
    float*  out2    = ws + N * 96;                 // N*64
    float*  h3raw   = out2 + N * 64;               // N
    float*  out3    = h3raw + N;                   // N
    float*  es_buf  = out3 + N;                    // N*4
    float*  ed_buf  = es_buf + N * 4;              // N*4
    float*  wes     = ed_buf + N * 4;              // 88
    float*  wed     = wes + 88;                    // 88
    __half* W1t     = (__half*)(wed + 88);         // 512*32 halves = 8192 floats
    __half* W2t     = (__half*)(wed + 88 + 8192);  // 64*512 halves = 16384 floats
    int*    deg     = (int*)(wed + 88 + 8192 + 16384); // N
    int*    row_ptr = deg + N;                     // N+1
    int*    csr_src = row_ptr + N + 1;             // E_EDGES
    int*    bsum    = csr_src + E_EDGES;           // 256

    // CSR build (shared by all 3 layers)
    hipMemsetAsync(deg, 0, N * sizeof(int), stream);
    k_count<<<cdiv(E_EDGES, BS), BS, 0, stream>>>(ei, deg);
    k_scan1<<<SCAN_BLOCKS, 256, 0, stream>>>(deg, bsum);
    k_scan2<<<1, 256, 0, stream>>>(bsum);
    k_scan3<<<SCAN_BLOCKS, 256, 0, stream>>>(deg, bsum, row_ptr);
    hipMemsetAsync(deg, 0, N * sizeof(int), stream);
    k_scatter<<<cdiv(E_EDGES, BS), BS, 0, stream>>>(ei, row_ptr, deg, csr_src);

    // Layer 1: H=4, C=128 — aggregate raw x (y16 fp16)
    k_fold<<<1, 256, 0, stream>>>(W1, a_src1, a_dst1, wes, wed);
    k_l1_coef<<<cdiv((long)N, BS), BS, 0, stream>>>(x, wes, wed, es_buf, ed_buf);
    k_edge_l1x<<<cdiv((long)N * 64, BS), BS, 0, stream>>>(row_ptr, csr_src, x, es_buf, ed_buf, y16);

    // Fused: out1 = ELU(y@W1+b1) (LDS-resident) then h2 = out1@W2 + es/ed
    k_wt<<<cdiv(512 * 32 + 512 * 64, BS), BS, 0, stream>>>(W1, W2, W1t, W2t);
    k_l12_fused<<<cdiv(N_NODES, 32), 256, 0, stream>>>(y16, W1t, b1, W2t, a_src2, a_dst2, h2_16, es_buf, ed_buf);

    // Layer 2 edge phase
    k_gat_edge_l2<<<cdiv((long)N * 64, BS), BS, 0, stream>>>(row_ptr, csr_src, h2_16, es_buf, ed_buf, b2, out2);

    // Layer 3: H=1, C=1
    k_l3_gemm_coef<<<cdiv((long)N * 64, BS), BS, 0, stream>>>(out2, W3, a_src3, a_dst3, h3raw, es_buf, ed_buf);
    k_gat_edge_c1<<<cdiv((long)N, BS), BS, 0, stream>>>(row_ptr, csr_src, h3raw, es_buf, ed_buf, out3);

    hipMemsetAsync(out, 0, sizeof(float), stream);
    k_mean<<<256, 256, 0, stream>>>(out3, b3, out, N_NODES);
}

// Round 16
// 165.931 us; speedup vs baseline: 2.5860x; 1.1601x over previous
//
#include <hip/hip_runtime.h>
#include <hip/hip_fp16.h>
#include <math.h>

#define N_NODES 50000
#define E_EDGES 400000
#define NEG_SLOPE 0.2f
#define SCAN_BLOCKS 250
#define SCAN_CHUNK 200

typedef _Float16 f16x8 __attribute__((ext_vector_type(8)));
typedef float f32x4 __attribute__((ext_vector_type(4)));

static inline int cdiv(long a, int b) { return (int)((a + b - 1) / b); }

__device__ __forceinline__ float lrelu(float v) {
    return v > 0.f ? v : NEG_SLOPE * v;
}

__device__ __forceinline__ void h4_to_f4(uint2 u, float o[4]) {
    union { uint2 u2; __half h[4]; } cv;
    cv.u2 = u;
    #pragma unroll
    for (int i = 0; i < 4; ++i) o[i] = __half2float(cv.h[i]);
}

// ---------------- CSR build ----------------
__global__ void k_count(const int* __restrict__ ei, int* __restrict__ deg) {
    int e = blockIdx.x * blockDim.x + threadIdx.x;
    if (e >= E_EDGES) return;
    atomicAdd(&deg[ei[E_EDGES + e]], 1);
}

__global__ void k_scan1(const int* __restrict__ deg, int* __restrict__ bsum) {
    __shared__ int sd[256];
    int b = blockIdx.x, t = threadIdx.x;
    int lo = b * SCAN_CHUNK;
    int s = 0;
    for (int i = t; i < SCAN_CHUNK; i += 256) s += deg[lo + i];
    sd[t] = s;
    __syncthreads();
    for (int off = 128; off; off >>= 1) {
        if (t < off) sd[t] += sd[t + off];
        __syncthreads();
    }
    if (t == 0) bsum[b] = sd[0];
}

__global__ void k_scan2(int* __restrict__ bsum) {
    __shared__ int sd[256];
    int t = threadIdx.x;
    int v = (t < SCAN_BLOCKS) ? bsum[t] : 0;
    sd[t] = v;
    __syncthreads();
    for (int off = 1; off < 256; off <<= 1) {
        int u = (t >= off) ? sd[t - off] : 0;
        __syncthreads();
        sd[t] += u;
        __syncthreads();
    }
    if (t < SCAN_BLOCKS) bsum[t] = sd[t] - v;   // exclusive
}

__global__ void k_scan3(const int* __restrict__ deg, const int* __restrict__ bsum,
                        int* __restrict__ row_ptr) {
    __shared__ int sd[256];
    int b = blockIdx.x, t = threadIdx.x;
    int lo = b * SCAN_CHUNK;
    int v = (t < SCAN_CHUNK) ? deg[lo + t] : 0;
    sd[t] = v;
    __syncthreads();
    for (int off = 1; off < 256; off <<= 1) {
        int u = (t >= off) ? sd[t - off] : 0;
        __syncthreads();
        sd[t] += u;
        __syncthreads();
    }
    if (t < SCAN_CHUNK) row_ptr[lo + t] = bsum[b] + sd[t] - v;
    if (b == 0 && t == 0) row_ptr[N_NODES] = E_EDGES;
}

__global__ void k_scatter(const int* __restrict__ ei, const int* __restrict__ row_ptr,
                          int* __restrict__ pos, int* __restrict__ csr_src) {
    int e = blockIdx.x * blockDim.x + threadIdx.x;
    if (e >= E_EDGES) return;
    int src = ei[e], dst = ei[E_EDGES + e];
    int p = atomicAdd(&pos[dst], 1);
    csr_src[row_ptr[dst] + p] = src;
}

// ---------------- layer-1 coefficients (fold fused into LDS) ----------------
__global__ void k_l1_coef(const float* __restrict__ x, const float* __restrict__ W1,
                          const float* __restrict__ a_src, const float* __restrict__ a_dst,
                          float* __restrict__ es, float* __restrict__ ed) {
    __shared__ float wesS[88], wedS[88];
    const int t = threadIdx.x;
    if (t < 168) {
        int which = t / 84;
        int idx = t % 84;
        int k = idx >> 2, h = idx & 3;
        const float* a = which ? a_dst : a_src;
        float s = 0.f;
        for (int c = 0; c < 128; ++c)
            s += W1[k * 512 + h * 128 + c] * a[h * 128 + c];
        (which ? wedS : wesS)[idx] = s;
    }
    __syncthreads();

    int node = blockIdx.x * blockDim.x + t;
    if (node >= N_NODES) return;
    const float* xr = x + (size_t)node * 21;
    float e1[4] = {0.f, 0.f, 0.f, 0.f}, e2[4] = {0.f, 0.f, 0.f, 0.f};
    #pragma unroll
    for (int k = 0; k < 21; ++k) {
        float xv = xr[k];
        float4 a = *(const float4*)&wesS[k * 4];
        float4 b = *(const float4*)&wedS[k * 4];
        e1[0] += xv * a.x; e1[1] += xv * a.y; e1[2] += xv * a.z; e1[3] += xv * a.w;
        e2[0] += xv * b.x; e2[1] += xv * b.y; e2[2] += xv * b.z; e2[3] += xv * b.w;
    }
    *(float4*)&es[node * 4] = make_float4(e1[0], e1[1], e1[2], e1[3]);
    *(float4*)&ed[node * 4] = make_float4(e2[0], e2[1], e2[2], e2[3]);
}

// ---------------- layer-1 edge phase on RAW x -> y16 (skip-max softmax) ----------------
// y16 layout: [node][head*32 + k], k in 0..31 (21..31 zero)
__global__ void k_edge_l1x(const int* __restrict__ row_ptr, const int* __restrict__ csr_src,
                           const float* __restrict__ x, const float* __restrict__ es,
                           const float* __restrict__ ed, __half* __restrict__ y16) {
    int wid = (blockIdx.x * blockDim.x + threadIdx.x) >> 6;
    int l = threadIdx.x & 63;
    if (wid >= N_NODES) return;
    const int dst = wid;
    const int hh = l >> 4, sub = l & 15;
    const int beg = row_ptr[dst], end = row_ptr[dst + 1];
    const float eddg = ed[dst * 4 + hh];
    const float self_v = lrelu(es[dst * 4 + hh] + eddg);

    // single pass: sum of exp (softmax is shift-invariant; |v| small, no overflow)
    float s = 0.f;
    for (int k = beg + sub; k < end; k += 16)
        s += __expf(lrelu(es[csr_src[k] * 4 + hh] + eddg));
    #pragma unroll
    for (int off = 1; off < 16; off <<= 1) s += __shfl_xor(s, off, 64);
    float p_self = __expf(self_v);
    s += p_self;
    float inv_s = 1.f / s;

    // broadcast per-head stats to all lanes
    float ih[4], eh[4], ph[4];
    #pragma unroll
    for (int h = 0; h < 4; ++h) {
        ih[h] = __shfl(inv_s, h * 16, 64);
        eh[h] = __shfl(eddg, h * 16, 64);
        ph[h] = __shfl(p_self, h * 16, 64);
    }

    // aggregation: lane l<63: group g=l/21 walks edges beg+g, beg+g+3, ...
    const int g = l / 21;
    const int c = l - g * 21;
    const bool act = (l < 63);

    float xdv = (act && g == 0) ? x[(size_t)dst * 21 + c] : 0.f;
    float acc[4];
    #pragma unroll
    for (int h = 0; h < 4; ++h) acc[h] = ph[h] * ih[h] * xdv;

    if (act) {
        int k = beg + g;
        for (; k + 3 < end; k += 6) {
            int s0 = csr_src[k], s1 = csr_src[k + 3];
            float4 e0 = *(const float4*)&es[s0 * 4];
            float4 e1 = *(const float4*)&es[s1 * 4];
            float x0 = x[(size_t)s0 * 21 + c];
            float x1 = x[(size_t)s1 * 21 + c];
            #pragma unroll
            for (int h = 0; h < 4; ++h) {
                float a0 = __expf(lrelu((&e0.x)[h] + eh[h])) * ih[h];
                float a1 = __expf(lrelu((&e1.x)[h] + eh[h])) * ih[h];
                acc[h] += a0 * x0 + a1 * x1;
            }
        }
        if (k < end) {
            int s0 = csr_src[k];
            float4 e0 = *(const float4*)&es[s0 * 4];
            float x0 = x[(size_t)s0 * 21 + c];
            #pragma unroll
            for (int h = 0; h < 4; ++h) {
                float a0 = __expf(lrelu((&e0.x)[h] + eh[h])) * ih[h];
                acc[h] += a0 * x0;
            }
        }
    }

    // 3-way reduce across edge-groups; lanes 0..20 hold result, 21..31 write pad
    #pragma unroll
    for (int h = 0; h < 4; ++h) {
        float a1 = __shfl(acc[h], (l + 21) & 63, 64);
        float a2 = __shfl(acc[h], (l + 42) & 63, 64);
        acc[h] += a1 + a2;
    }
    if (l < 32) {
        #pragma unroll
        for (int h = 0; h < 4; ++h) {
            float v = (l < 21) ? acc[h] : 0.f;
            y16[(size_t)dst * 128 + h * 32 + l] = __float2half_rn(v);
        }
    }
}

// ---------------- weight transposes to fp16 ----------------
__global__ void k_wt(const float* __restrict__ W1, const float* __restrict__ W2,
                     __half* __restrict__ W1t, __half* __restrict__ W2t) {
    int idx = blockIdx.x * blockDim.x + threadIdx.x;
    if (idx < 512 * 32) {
        int n = idx >> 5, k = idx & 31;
        W1t[idx] = (k < 21) ? __float2half_rn(W1[k * 512 + n]) : __half(0.f);
    } else {
        int j = idx - 512 * 32;
        if (j < 512 * 64) {
            int k = j >> 6, n = j & 63;
            W2t[(size_t)n * 512 + k] = __float2half_rn(W2[j]);
        }
    }
}

// ---------------- fused layers 1-post + 2-GEMM via MFMA ----------------
__global__ void k_l12_fused(const __half* __restrict__ y16, const __half* __restrict__ W1t,
                            const float* __restrict__ b1, const __half* __restrict__ W2t,
                            const float* __restrict__ a_src, const float* __restrict__ a_dst,
                            __half* __restrict__ C16, float* __restrict__ es, float* __restrict__ ed) {
    __shared__ _Float16 As[32][520];
    __shared__ float p1s[32][4];
    __shared__ float p2s[32][4];

    const int t = threadIdx.x;
    const int l = t & 63;
    const int wv = t >> 6;
    const int row0 = blockIdx.x * 32;
    const int lr = l & 15;
    const int kg = l >> 4;

    const _Float16* Y = (const _Float16*)y16;
    const _Float16* B1 = (const _Float16*)W1t;

    int ra0 = row0 + lr;       ra0 = ra0 < N_NODES ? ra0 : N_NODES - 1;
    int ra1 = row0 + 16 + lr;  ra1 = ra1 < N_NODES ? ra1 : N_NODES - 1;

    // phase 1: out1 tile, head = wv
    f32x4 acc1[2][8];
    #pragma unroll
    for (int m = 0; m < 2; ++m)
        #pragma unroll
        for (int n = 0; n < 8; ++n) acc1[m][n] = (f32x4){0.f, 0.f, 0.f, 0.f};

    f16x8 a0 = *(const f16x8*)(Y + (size_t)ra0 * 128 + wv * 32 + kg * 8);
    f16x8 a1 = *(const f16x8*)(Y + (size_t)ra1 * 128 + wv * 32 + kg * 8);

    #pragma unroll
    for (int nt = 0; nt < 8; ++nt) {
        f16x8 bf = *(const f16x8*)(B1 + (size_t)(wv * 128 + nt * 16 + lr) * 32 + kg * 8);
        acc1[0][nt] = __builtin_amdgcn_mfma_f32_16x16x32_f16(a0, bf, acc1[0][nt], 0, 0, 0);
        acc1[1][nt] = __builtin_amdgcn_mfma_f32_16x16x32_f16(a1, bf, acc1[1][nt], 0, 0, 0);
    }

    float bb[8];
    #pragma unroll
    for (int nt = 0; nt < 8; ++nt) bb[nt] = b1[wv * 128 + nt * 16 + lr];

    #pragma unroll
    for (int m = 0; m < 2; ++m) {
        #pragma unroll
        for (int r = 0; r < 4; ++r) {
            int rl = m * 16 + kg * 4 + r;
            #pragma unroll
            for (int nt = 0; nt < 8; ++nt) {
                float v = acc1[m][nt][r] + bb[nt];
                v = v > 0.f ? v : __expf(v) - 1.f;
                As[rl][wv * 128 + nt * 16 + lr] = (_Float16)v;
            }
        }
    }
    __syncthreads();

    // phase 2: h2 cols [wv*16,+16), K=512 from LDS
    const _Float16* B2 = (const _Float16*)W2t;
    const int n_g = wv * 16 + lr;
    f32x4 acc2[2];
    acc2[0] = (f32x4){0.f, 0.f, 0.f, 0.f};
    acc2[1] = (f32x4){0.f, 0.f, 0.f, 0.f};

    for (int kb = 0; kb < 512; kb += 32) {
        f16x8 fa0 = *(const f16x8*)&As[lr][kb + kg * 8];
        f16x8 fa1 = *(const f16x8*)&As[16 + lr][kb + kg * 8];
        f16x8 bf = *(const f16x8*)(B2 + (size_t)n_g * 512 + kb + kg * 8);
        acc2[0] = __builtin_amdgcn_mfma_f32_16x16x32_f16(fa0, bf, acc2[0], 0, 0, 0);
        acc2[1] = __builtin_amdgcn_mfma_f32_16x16x32_f16(fa1, bf, acc2[1], 0, 0, 0);
    }

    const float asv = a_src[n_g];
    const float adv = a_dst[n_g];

    #pragma unroll
    for (int m = 0; m < 2; ++m) {
        #pragma unroll
        for (int r = 0; r < 4; ++r) {
            int rl = m * 16 + kg * 4 + r;
            int grow = row0 + rl;
            float cv = acc2[m][r];
            float p1 = cv * asv, p2 = cv * adv;
            #pragma unroll
            for (int off = 1; off < 16; off <<= 1) {
                p1 += __shfl_xor(p1, off, 64);
                p2 += __shfl_xor(p2, off, 64);
            }
            if (grow < N_NODES)
                C16[(size_t)grow * 64 + n_g] = __float2half_rn(cv);
            if (lr == 0) { p1s[rl][wv] = p1; p2s[rl][wv] = p2; }
        }
    }
    __syncthreads();

    if (t < 32) {
        int grow = row0 + t;
        if (grow < N_NODES) {
            es[grow] = p1s[t][0] + p1s[t][1] + p1s[t][2] + p1s[t][3];
            ed[grow] = p2s[t][0] + p2s[t][1] + p2s[t][2] + p2s[t][3];
        }
    }
}

// ---------------- Layer 2 edge phase + fused layer-3 GEMM/coef ----------------
// skip-max softmax; epilogue computes h3 = ELU(agg+b2)@W3 and es3/ed3 directly (out2 never stored)
__global__ void k_gat_edge_l2_l3(const int* __restrict__ row_ptr, const int* __restrict__ csr_src,
                                 const __half* __restrict__ h16, const float* __restrict__ es,
                                 const float* __restrict__ ed, const float* __restrict__ b,
                                 const float* __restrict__ W3, const float* __restrict__ a_src3,
                                 const float* __restrict__ a_dst3, float* __restrict__ h3,
                                 float* __restrict__ es3, float* __restrict__ ed3) {
    int wid = (blockIdx.x * blockDim.x + threadIdx.x) >> 6;
    int lane = threadIdx.x & 63;
    if (wid >= N_NODES) return;
    const int dst = wid;
    const int g = lane >> 4, sub = lane & 15;
    const int beg = row_ptr[dst], end = row_ptr[dst + 1];
    const float edd = ed[dst];
    const float self_v = lrelu(es[dst] + edd);

    // single-pass sum of exp (shift-invariant softmax)
    float s = 0.f;
    for (int k = beg + lane; k < end; k += 64)
        s += __expf(lrelu(es[csr_src[k]] + edd));
    #pragma unroll
    for (int off = 32; off; off >>= 1) s += __shfl_xor(s, off, 64);
    float p_self = __expf(self_v);
    s += p_self;
    const float inv_s = 1.f / s;

    float acc[4] = {0.f, 0.f, 0.f, 0.f};
    if (g == 0) {
        uint2 r = *(const uint2*)(h16 + (size_t)dst * 64 + sub * 4);
        float hv[4]; h4_to_f4(r, hv);
        float a_self = p_self * inv_s;
        #pragma unroll
        for (int j = 0; j < 4; ++j) acc[j] = a_self * hv[j];
    }
    for (int k0 = beg; k0 < end; k0 += 4) {
        int k = k0 + g;
        if (k < end) {
            int src = csr_src[k];
            float alpha = __expf(lrelu(es[src] + edd)) * inv_s;
            uint2 r = *(const uint2*)(h16 + (size_t)src * 64 + sub * 4);
            float hv[4]; h4_to_f4(r, hv);
            #pragma unroll
            for (int j = 0; j < 4; ++j) acc[j] += alpha * hv[j];
        }
    }
    #pragma unroll
    for (int off = 16; off < 64; off <<= 1) {
        #pragma unroll
        for (int j = 0; j < 4; ++j) acc[j] += __shfl_xor(acc[j], off, 64);
    }

    // epilogue: o = ELU(acc + b2); pp = o . W3[sub*4..+3]; reduce over sub; write h3/es3/ed3
    float4 bv = *(const float4*)&b[sub * 4];
    float4 w3 = *(const float4*)&W3[sub * 4];
    float o0 = acc[0] + bv.x, o1 = acc[1] + bv.y, o2 = acc[2] + bv.z, o3 = acc[3] + bv.w;
    o0 = o0 > 0.f ? o0 : expm1f(o0);
    o1 = o1 > 0.f ? o1 : expm1f(o1);
    o2 = o2 > 0.f ? o2 : expm1f(o2);
    o3 = o3 > 0.f ? o3 : expm1f(o3);
    float pp = o0 * w3.x + o1 * w3.y + o2 * w3.z + o3 * w3.w;
    #pragma unroll
    for (int off = 1; off < 16; off <<= 1) pp += __shfl_xor(pp, off, 64);

    if (lane == 0) {
        h3[dst] = pp;
        es3[dst] = pp * a_src3[0];
        ed3[dst] = pp * a_dst3[0];
    }
}

// ---------------- layer 3 edge phase + mean (fused) ----------------
__global__ void k_gat_edge_c1_mean(const int* __restrict__ row_ptr, const int* __restrict__ csr_src,
                                   const float* __restrict__ h, const float* __restrict__ es,
                                   const float* __restrict__ ed, const float* __restrict__ b3,
                                   float* __restrict__ out) {
    __shared__ float sdata[256];
    int dst = blockIdx.x * blockDim.x + threadIdx.x;
    float val = 0.f;
    if (dst < N_NODES) {
        int beg = row_ptr[dst], end = row_ptr[dst + 1];
        float edd = ed[dst];
        float self_v = lrelu(es[dst] + edd);
        float p = __expf(self_v);
        float s = p;
        float acc = p * h[dst];
        for (int k = beg; k < end; ++k) {
            int src = csr_src[k];
            float pv = __expf(lrelu(es[src] + edd));
            s += pv;
            acc += pv * h[src];
        }
        val = acc / s;
    }
    sdata[threadIdx.x] = val;
    __syncthreads();
    for (int sft = 128; sft > 0; sft >>= 1) {
        if (threadIdx.x < sft) sdata[threadIdx.x] += sdata[threadIdx.x + sft];
        __syncthreads();
    }
    if (threadIdx.x == 0) {
        float add = sdata[0] / (float)N_NODES;
        if (blockIdx.x == 0) add += b3[0];
        atomicAdd(out, add);
    }
}

extern "C" void kernel_launch(void* const* d_in, const int* in_sizes, int n_in,
                              void* d_out, int out_size, void* d_ws, size_t ws_size,
                              hipStream_t stream) {
    const float* x      = (const float*)d_in[0];
    const float* W1     = (const float*)d_in[1];
    const float* a_src1 = (const float*)d_in[2];
    const float* a_dst1 = (const float*)d_in[3];
    const float* b1     = (const float*)d_in[4];
    const float* W2     = (const float*)d_in[5];
    const float* a_src2 = (const float*)d_in[6];
    const float* a_dst2 = (const float*)d_in[7];
    const float* b2     = (const float*)d_in[8];
    const float* W3     = (const float*)d_in[9];
    const float* a_src3 = (const float*)d_in[10];
    const float* a_dst3 = (const float*)d_in[11];
    const float* b3     = (const float*)d_in[12];
    const int*   ei     = (const int*)d_in[13];
    float* out = (float*)d_out;

    const int BS = 256;
    const size_t N = N_NODES;

    // workspace layout (float units)
    float*  ws      = (float*)d_ws;
    __half* y16     = (__half*)ws;                 // N*128 halves = N*64 floats
    __half* h2_16   = (__half*)(ws + N * 64);      // N*64 halves = N*32 floats
    float*  h3raw   = ws + N * 96;                 // N
    float*  es3     = h3raw + N;                   // N
    float*  ed3     = es3 + N;                     // N
    float*  es_buf  = ed3 + N;                     // N*4
    float*  ed_buf  = es_buf + N * 4;              // N*4
    __half* W1t     = (__half*)(ed_buf + N * 4);   // 512*32 halves = 8192 floats
    __half* W2t     = (__half*)(ed_buf + N * 4 + 8192); // 64*512 halves = 16384 floats
    int*    deg     = (int*)(ed_buf + N * 4 + 8192 + 16384); // N
    int*    row_ptr = deg + N;                     // N+1
    int*    csr_src = row_ptr + N + 1;             // E_EDGES
    int*    bsum    = csr_src + E_EDGES;           // 256

    // CSR build (shared by all 3 layers)
    hipMemsetAsync(deg, 0, N * sizeof(int), stream);
    k_count<<<cdiv(E_EDGES, BS), BS, 0, stream>>>(ei, deg);
    k_scan1<<<SCAN_BLOCKS, 256, 0, stream>>>(deg, bsum);
    k_scan2<<<1, 256, 0, stream>>>(bsum);
    k_scan3<<<SCAN_BLOCKS, 256, 0, stream>>>(deg, bsum, row_ptr);
    hipMemsetAsync(deg, 0, N * sizeof(int), stream);
    k_scatter<<<cdiv(E_EDGES, BS), BS, 0, stream>>>(ei, row_ptr, deg, csr_src);

    // Layer 1: coefficients (fold fused) + edge aggregation on raw x
    k_l1_coef<<<cdiv((long)N, BS), BS, 0, stream>>>(x, W1, a_src1, a_dst1, es_buf, ed_buf);
    k_edge_l1x<<<cdiv((long)N * 64, BS), BS, 0, stream>>>(row_ptr, csr_src, x, es_buf, ed_buf, y16);

    // Fused: out1 = ELU(y@W1+b1) (LDS) then h2 = out1@W2 + es/ed
    k_wt<<<cdiv(512 * 32 + 512 * 64, BS), BS, 0, stream>>>(W1, W2, W1t, W2t);
    k_l12_fused<<<cdiv(N_NODES, 32), 256, 0, stream>>>(y16, W1t, b1, W2t, a_src2, a_dst2, h2_16, es_buf, ed_buf);

    // Layer 2 edge phase with fused layer-3 GEMM + coefficients (out2 never materialized)
    k_gat_edge_l2_l3<<<cdiv((long)N * 64, BS), BS, 0, stream>>>(row_ptr, csr_src, h2_16, es_buf, ed_buf,
                                                                b2, W3, a_src3, a_dst3, h3raw, es3, ed3);

    // Layer 3 edge phase + mean (fused)
    hipMemsetAsync(out, 0, sizeof(float), stream);
    k_gat_edge_c1_mean<<<cdiv((long)N, BS), BS, 0, stream>>>(row_ptr, csr_src, h3raw, es3, ed3, b3, out);
}